// Round 4
// baseline (1255.874 us; speedup 1.0000x reference)
//
#include <hip/hip_runtime.h>

#define NN 100000
#define NE 3200000
#define IC 128
#define HD 64
#define BN_EPS 1e-5f
#define CHUNK 98      // ceil(NN / 1024) for the 1-block prefix
#define NBUK 196      // ceil(NN / 512) buckets of 512 nodes (dst >> 9)
#define MSB 16        // edges per thread in multisplit (batch = 4096/block)

// ---------------------------------------------------------------------------
// Input projection + fused BN-stats partials.
// 16 rows/block, 256 threads; wave w handles rows 4w..4w+3 (col = lane).
__global__ __launch_bounds__(256) void k_gemm_in(
    const float* __restrict__ x, const float* __restrict__ Wp,
    const float* __restrict__ bp, float* __restrict__ pre,
    float* __restrict__ stats) {
  __shared__ float sW[IC * HD];    // 32 KB  [k][c]
  __shared__ float sXT[IC * 16];   // 8 KB   [k][r]
  int tid = threadIdx.x;
  for (int i = tid; i < IC * HD; i += 256) sW[i] = Wp[i];
  int row0 = blockIdx.x * 16;
  for (int i = tid; i < 16 * IC; i += 256) {
    int r = i >> 7, k = i & 127;
    sXT[k * 16 + r] = x[(size_t)(row0 + r) * IC + k];
  }
  __syncthreads();
  int w = tid >> 6, c = tid & 63;
  float bc = bp[c];
  float a0 = bc, a1 = bc, a2 = bc, a3 = bc;
#pragma unroll 4
  for (int k = 0; k < IC; ++k) {
    float wv = sW[k * HD + c];
    const float4 xv = *(const float4*)&sXT[k * 16 + w * 4];
    a0 = fmaf(xv.x, wv, a0);
    a1 = fmaf(xv.y, wv, a1);
    a2 = fmaf(xv.z, wv, a2);
    a3 = fmaf(xv.w, wv, a3);
  }
  size_t base = (size_t)(row0 + w * 4) * HD + c;
  pre[base] = a0;
  pre[base + HD] = a1;
  pre[base + 2 * HD] = a2;
  pre[base + 3 * HD] = a3;
  // fused BN stats: per-block per-channel partial sums -> global atomics
  __syncthreads();  // all sXT reads done; reuse as scratch
  float* ss = sXT;          // [4][64]
  float* sq = sXT + 256;    // [4][64]
  ss[w * 64 + c] = a0 + a1 + a2 + a3;
  sq[w * 64 + c] = a0 * a0 + a1 * a1 + a2 * a2 + a3 * a3;
  __syncthreads();
  if (tid < 64) {
    float S = ss[tid] + ss[64 + tid] + ss[128 + tid] + ss[192 + tid];
    float Q = sq[tid] + sq[64 + tid] + sq[128 + tid] + sq[192 + tid];
    atomicAdd(&stats[tid], S);
    atomicAdd(&stats[64 + tid], Q);
  }
}

// ---------------------------------------------------------------------------
// BN normalize + ReLU (materializing variant, no residual).
__global__ __launch_bounds__(256) void k_bn_relu(
    const float* __restrict__ pre, const float* __restrict__ stats,
    const float* __restrict__ g, const float* __restrict__ b,
    float* __restrict__ out) {
  size_t i = (size_t)blockIdx.x * 256 + threadIdx.x;
  int c = threadIdx.x & 63;
  const float invN = 1.0f / NN;
  float m = stats[c] * invN;
  float v = stats[64 + c] * invN - m * m;
  float sc = g[c] * rsqrtf(v + BN_EPS);
  float val = (pre[i] - m) * sc + b[c];
  out[i] = fmaxf(val, 0.f);
}

// ---------------------------------------------------------------------------
// Sort 1: per-node degree histogram.
__global__ __launch_bounds__(256) void k_hist(const int* __restrict__ dst,
                                              unsigned int* __restrict__ cnt) {
  int i0 = blockIdx.x * 256 + threadIdx.x;
  int stride = gridDim.x * 256;
  for (int e = i0; e < NE; e += stride) atomicAdd(&cnt[dst[e]], 1u);
}

// ---------------------------------------------------------------------------
// Sort 2: exclusive prefix over 100k degrees (one 1024-thread block).
// Writes nstart[0..NN] (immutable), ncur[] (phase-B cursors) and gcur[]
// (bucket cursors for the multisplit).
__global__ __launch_bounds__(1024) void k_prefix(
    const unsigned int* __restrict__ cnt, unsigned int* __restrict__ nstart,
    unsigned int* __restrict__ ncur, unsigned int* __restrict__ gcur) {
  __shared__ unsigned int s[1024];
  int t = threadIdx.x;
  int base = t * CHUNK;
  unsigned int sum = 0;
  for (int i = 0; i < CHUNK; ++i) {
    int idx = base + i;
    if (idx < NN) sum += cnt[idx];
  }
  s[t] = sum;
  __syncthreads();
  for (int off = 1; off < 1024; off <<= 1) {
    unsigned int v = (t >= off) ? s[t - off] : 0u;
    __syncthreads();
    s[t] += v;
    __syncthreads();
  }
  unsigned int run = s[t] - sum;  // exclusive prefix of this chunk
  for (int i = 0; i < CHUNK; ++i) {
    int idx = base + i;
    if (idx < NN) {
      nstart[idx] = run;
      ncur[idx] = run;
      run += cnt[idx];
    }
  }
  if (t == 1023) nstart[NN] = s[1023];
  __syncthreads();  // global writes above visible to block
  for (int bkt = t; bkt < NBUK; bkt += 1024) gcur[bkt] = nstart[bkt * 512];
}

// ---------------------------------------------------------------------------
// Sort 3a: multisplit into 512-node buckets. Packed word = src | (dloc<<17).
// Per-batch bucket runs are contiguous -> L2 lines fill -> ~no write amp.
__global__ __launch_bounds__(256) void k_msplit(
    const int* __restrict__ src, const int* __restrict__ dst,
    unsigned int* __restrict__ gcur, unsigned int* __restrict__ staging) {
  __shared__ unsigned int hist[NBUK];
  __shared__ unsigned int gbase[NBUK];
  int tid = threadIdx.x;
  for (int i = tid; i < NBUK; i += 256) hist[i] = 0u;
  __syncthreads();
  int e0 = blockIdx.x * (256 * MSB);
  unsigned int pk[MSB], rk[MSB], bk[MSB];
#pragma unroll
  for (int i = 0; i < MSB; ++i) {
    int e = e0 + i * 256 + tid;
    if (e < NE) {
      int d = dst[e];
      unsigned int b = (unsigned int)(d >> 9);
      rk[i] = atomicAdd(&hist[b], 1u);
      pk[i] = (unsigned int)src[e] | ((unsigned int)(d & 511) << 17);
      bk[i] = b;
    } else {
      bk[i] = 0xFFFFFFFFu;
    }
  }
  __syncthreads();
  for (int i = tid; i < NBUK; i += 256)
    if (hist[i]) gbase[i] = atomicAdd(&gcur[i], hist[i]);
  __syncthreads();
#pragma unroll
  for (int i = 0; i < MSB; ++i)
    if (bk[i] != 0xFFFFFFFFu) staging[gbase[bk[i]] + rk[i]] = pk[i];
}

// ---------------------------------------------------------------------------
// Sort 3b: within-bucket scatter to exact node order (4 blocks per bucket;
// writes confined to a ~65 KB L2-resident window).
__global__ __launch_bounds__(256) void k_bscatter(
    const unsigned int* __restrict__ staging,
    const unsigned int* __restrict__ nstart, unsigned int* __restrict__ ncur,
    unsigned int* __restrict__ sorted_src) {
  int b = blockIdx.x >> 2, part = blockIdx.x & 3;
  int lo = (int)nstart[b * 512];
  int nend = (b + 1) * 512;
  if (nend > NN) nend = NN;
  int hi = (int)nstart[nend];
  for (int e = lo + part * 256 + threadIdx.x; e < hi; e += 1024) {
    unsigned int u = staging[e];
    unsigned int s = u & 0x1FFFFu;
    int node = (b << 9) + (int)(u >> 17);
    unsigned int pos = atomicAdd(&ncur[node], 1u);
    sorted_src[pos] = s;
  }
}

// ---------------------------------------------------------------------------
// Aggregation over sorted edges: one wave per node, lane = channel, mean
// fused, no atomics. Segments from immutable nstart.
__global__ __launch_bounds__(256) void k_aggr_sorted(
    const unsigned int* __restrict__ sorted_src,
    const unsigned int* __restrict__ nstart, const float* __restrict__ h,
    float* __restrict__ aggr) {
  int lane = threadIdx.x & 63;
  int n = (int)((blockIdx.x * 256 + threadIdx.x) >> 6);
  if (n >= NN) return;
  int e0 = (int)nstart[n];
  int e1 = (int)nstart[n + 1];
  float a0 = 0.f, a1 = 0.f, a2 = 0.f, a3 = 0.f;
  float a4 = 0.f, a5 = 0.f, a6 = 0.f, a7 = 0.f;
  int e = e0;
  for (; e + 8 <= e1; e += 8) {
    unsigned int s0 = sorted_src[e], s1 = sorted_src[e + 1];
    unsigned int s2 = sorted_src[e + 2], s3 = sorted_src[e + 3];
    unsigned int s4 = sorted_src[e + 4], s5 = sorted_src[e + 5];
    unsigned int s6 = sorted_src[e + 6], s7 = sorted_src[e + 7];
    a0 += h[(size_t)s0 * HD + lane];
    a1 += h[(size_t)s1 * HD + lane];
    a2 += h[(size_t)s2 * HD + lane];
    a3 += h[(size_t)s3 * HD + lane];
    a4 += h[(size_t)s4 * HD + lane];
    a5 += h[(size_t)s5 * HD + lane];
    a6 += h[(size_t)s6 * HD + lane];
    a7 += h[(size_t)s7 * HD + lane];
  }
  for (; e < e1; ++e) a0 += h[(size_t)sorted_src[e] * HD + lane];
  float acc = ((a0 + a1) + (a2 + a3)) + ((a4 + a5) + (a6 + a7));
  float cntf = (float)(e1 - e0);
  float inv = (cntf > 0.f) ? 1.0f / cntf : 0.f;
  aggr[(size_t)n * HD + lane] = acc * inv;
}

// ---------------------------------------------------------------------------
// SAGE combine + fused BN-stats partials. 32 rows/block, 512 threads.
// Safe with pre == aggr (block stages its own rows before overwriting).
__global__ __launch_bounds__(512) void k_combine(
    const float* __restrict__ aggr, const float* __restrict__ h,
    const float* __restrict__ Wl, const float* __restrict__ bl,
    const float* __restrict__ Wr, float* __restrict__ pre,
    float* __restrict__ stats) {
  __shared__ float sWl[HD * HD], sWr[HD * HD];  // 32 KB
  __shared__ float sAT[HD * 32], sHT[HD * 32];  // 16 KB  [k][r]
  int tid = threadIdx.x;
  for (int i = tid; i < HD * HD; i += 512) {
    sWl[i] = Wl[i];
    sWr[i] = Wr[i];
  }
  int row0 = blockIdx.x * 32;
  for (int i = tid; i < 32 * HD; i += 512) {
    int r = i >> 6, k = i & 63;
    sAT[k * 32 + r] = aggr[(size_t)(row0 + r) * HD + k];
    sHT[k * 32 + r] = h[(size_t)(row0 + r) * HD + k];
  }
  __syncthreads();
  int w = tid >> 6, c = tid & 63;  // wave w -> rows 4w..4w+3
  float bc = bl[c];
  float a0 = bc, a1 = bc, a2 = bc, a3 = bc;
#pragma unroll 4
  for (int k = 0; k < HD; ++k) {
    float wl = sWl[k * HD + c], wr = sWr[k * HD + c];
    const float4 av = *(const float4*)&sAT[k * 32 + w * 4];
    const float4 hv = *(const float4*)&sHT[k * 32 + w * 4];
    a0 = fmaf(av.x, wl, a0);
    a1 = fmaf(av.y, wl, a1);
    a2 = fmaf(av.z, wl, a2);
    a3 = fmaf(av.w, wl, a3);
    a0 = fmaf(hv.x, wr, a0);
    a1 = fmaf(hv.y, wr, a1);
    a2 = fmaf(hv.z, wr, a2);
    a3 = fmaf(hv.w, wr, a3);
  }
  size_t base = (size_t)(row0 + w * 4) * HD + c;
  pre[base] = a0;
  pre[base + HD] = a1;
  pre[base + 2 * HD] = a2;
  pre[base + 3 * HD] = a3;
  // fused BN stats partials
  __syncthreads();  // sAT reads done; reuse as scratch
  float* ss = sAT;          // [8][64]
  float* sq = sAT + 512;    // [8][64]
  ss[w * 64 + c] = a0 + a1 + a2 + a3;
  sq[w * 64 + c] = a0 * a0 + a1 * a1 + a2 * a2 + a3 * a3;
  __syncthreads();
  if (tid < 64) {
    float S = 0.f, Q = 0.f;
#pragma unroll
    for (int j = 0; j < 8; ++j) {
      S += ss[j * 64 + tid];
      Q += sq[j * 64 + tid];
    }
    atomicAdd(&stats[tid], S);
    atomicAdd(&stats[64 + tid], Q);
  }
}

// ---------------------------------------------------------------------------
// Final fused: BN + ReLU + residual + output head. h2 never materialized.
__global__ __launch_bounds__(256) void k_bn_relu_head(
    const float* __restrict__ pre, const float* __restrict__ stats,
    const float* __restrict__ g, const float* __restrict__ b,
    const float* __restrict__ resid, const float* __restrict__ Wo,
    const float* __restrict__ bo, float* __restrict__ out) {
  int lane = threadIdx.x & 63;
  int wid = (int)((blockIdx.x * blockDim.x + threadIdx.x) >> 6);
  int nw = (int)((gridDim.x * blockDim.x) >> 6);
  const float invN = 1.0f / NN;
  float m = stats[lane] * invN;
  float v = stats[64 + lane] * invN - m * m;
  float sc = g[lane] * rsqrtf(v + BN_EPS);
  float bb = b[lane];
  float w0 = Wo[lane * 2], w1 = Wo[lane * 2 + 1];
  float b0 = bo[0], b1 = bo[1];
  for (int row = wid; row < NN; row += nw) {
    size_t i = (size_t)row * HD + lane;
    float val = (pre[i] - m) * sc + bb;
    val = fmaxf(val, 0.f) + resid[i];
    float a0 = val * w0, a1 = val * w1;
#pragma unroll
    for (int off = 32; off > 0; off >>= 1) {
      a0 += __shfl_down(a0, off);
      a1 += __shfl_down(a1, off);
    }
    if (lane == 0) {
      out[(size_t)row * 2] = a0 + b0;
      out[(size_t)row * 2 + 1] = a1 + b1;
    }
  }
}

// ---------------------------------------------------------------------------
extern "C" void kernel_launch(void* const* d_in, const int* in_sizes, int n_in,
                              void* d_out, int out_size, void* d_ws,
                              size_t ws_size, hipStream_t stream) {
  const float* x = (const float*)d_in[0];
  const int* ei = (const int*)d_in[1];
  const float* Wp = (const float*)d_in[2];
  const float* bp = (const float*)d_in[3];
  const float* g_in = (const float*)d_in[4];
  const float* b_in = (const float*)d_in[5];
  const float* Wl0 = (const float*)d_in[6];
  const float* bl0 = (const float*)d_in[7];
  const float* Wr0 = (const float*)d_in[8];
  const float* g0 = (const float*)d_in[9];
  const float* b0 = (const float*)d_in[10];
  const float* Wl1 = (const float*)d_in[11];
  const float* bl1 = (const float*)d_in[12];
  const float* Wr1 = (const float*)d_in[13];
  const float* g1 = (const float*)d_in[14];
  const float* b1 = (const float*)d_in[15];
  const float* Wo = (const float*)d_in[16];
  const float* bo = (const float*)d_in[17];
  float* out = (float*)d_out;

  const int* src = ei;
  const int* dst = ei + NE;

  float* ws = (float*)d_ws;
  float* h0 = ws;                          // [NN*HD]
  float* h1 = ws + (size_t)NN * HD;        // [NN*HD]
  float* pre = ws + (size_t)2 * NN * HD;   // [NN*HD]  (also aggr buffer)
  unsigned int* staging = (unsigned int*)(ws + (size_t)3 * NN * HD);  // [NE]
  unsigned int* sorted_src = staging + NE;  // [NE]
  unsigned int* cnt = sorted_src + NE;      // [NN]
  unsigned int* nstart = cnt + NN;          // [NN+1]
  unsigned int* ncur = nstart + NN + 1;     // [NN]
  unsigned int* gcur = ncur + NN;           // [NBUK]
  float* stats0 = (float*)(gcur + NBUK);    // [128]
  float* stats1 = stats0 + 128;             // [128]
  float* stats2 = stats1 + 128;             // [128]

  const int ELEM_BLOCKS = (NN * HD) / 256;  // 25000
  const int AGGR_BLOCKS = 25000;            // 100k waves, 4/block
  const int MS_BLOCKS = (NE + 256 * MSB - 1) / (256 * MSB);  // 782

  hipMemsetAsync(stats0, 0, 3 * 128 * sizeof(float), stream);
  hipMemsetAsync(cnt, 0, NN * sizeof(unsigned int), stream);

  // ---- input projection (+stats) + BN/ReLU -> h0
  k_gemm_in<<<NN / 16, 256, 0, stream>>>(x, Wp, bp, pre, stats0);
  k_bn_relu<<<ELEM_BLOCKS, 256, 0, stream>>>(pre, stats0, g_in, b_in, h0);

  // ---- counting-sort edges by dst (two-phase binned; shared by both layers)
  k_hist<<<2048, 256, 0, stream>>>(dst, cnt);
  k_prefix<<<1, 1024, 0, stream>>>(cnt, nstart, ncur, gcur);
  k_msplit<<<MS_BLOCKS, 256, 0, stream>>>(src, dst, gcur, staging);
  k_bscatter<<<NBUK * 4, 256, 0, stream>>>(staging, nstart, ncur, sorted_src);

  // ---- layer 0
  k_aggr_sorted<<<AGGR_BLOCKS, 256, 0, stream>>>(sorted_src, nstart, h0, pre);
  k_combine<<<NN / 32, 512, 0, stream>>>(pre, h0, Wl0, bl0, Wr0, pre, stats1);
  k_bn_relu<<<ELEM_BLOCKS, 256, 0, stream>>>(pre, stats1, g0, b0, h1);

  // ---- layer 1 + fused BN/ReLU/residual/head
  k_aggr_sorted<<<AGGR_BLOCKS, 256, 0, stream>>>(sorted_src, nstart, h1, pre);
  k_combine<<<NN / 32, 512, 0, stream>>>(pre, h1, Wl1, bl1, Wr1, pre, stats2);
  k_bn_relu_head<<<1024, 256, 0, stream>>>(pre, stats2, g1, b1, h0, Wo, bo,
                                           out);
}

// Round 5
// 1013.402 us; speedup vs baseline: 1.2393x; 1.2393x over previous
//
#include <hip/hip_runtime.h>

#define NN 100000
#define NE 3200000
#define IC 128
#define HD 64
#define BN_EPS 1e-5f
#define NBUK 196      // ceil(NN / 512) buckets of 512 nodes (dst >> 9)
#define MSB 16        // edges per thread in multisplit (batch = 4096/block)
#define SCAN_BLKS 391 // ceil(NN / 256)

// ---------------------------------------------------------------------------
// Input projection + fused BN-stats partials.
// 16 rows/block, 256 threads; wave w handles rows 4w..4w+3 (col = lane).
__global__ __launch_bounds__(256) void k_gemm_in(
    const float* __restrict__ x, const float* __restrict__ Wp,
    const float* __restrict__ bp, float* __restrict__ pre,
    float* __restrict__ stats) {
  __shared__ float sW[IC * HD];    // 32 KB  [k][c]
  __shared__ float sXT[IC * 16];   // 8 KB   [k][r]
  int tid = threadIdx.x;
  for (int i = tid; i < IC * HD; i += 256) sW[i] = Wp[i];
  int row0 = blockIdx.x * 16;
  for (int i = tid; i < 16 * IC; i += 256) {
    int r = i >> 7, k = i & 127;
    sXT[k * 16 + r] = x[(size_t)(row0 + r) * IC + k];
  }
  __syncthreads();
  int w = tid >> 6, c = tid & 63;
  float bc = bp[c];
  float a0 = bc, a1 = bc, a2 = bc, a3 = bc;
#pragma unroll 4
  for (int k = 0; k < IC; ++k) {
    float wv = sW[k * HD + c];
    const float4 xv = *(const float4*)&sXT[k * 16 + w * 4];
    a0 = fmaf(xv.x, wv, a0);
    a1 = fmaf(xv.y, wv, a1);
    a2 = fmaf(xv.z, wv, a2);
    a3 = fmaf(xv.w, wv, a3);
  }
  size_t base = (size_t)(row0 + w * 4) * HD + c;
  pre[base] = a0;
  pre[base + HD] = a1;
  pre[base + 2 * HD] = a2;
  pre[base + 3 * HD] = a3;
  // fused BN stats: per-block per-channel partial sums -> global atomics
  __syncthreads();  // all sXT reads done; reuse as scratch
  float* ss = sXT;          // [4][64]
  float* sq = sXT + 256;    // [4][64]
  ss[w * 64 + c] = a0 + a1 + a2 + a3;
  sq[w * 64 + c] = a0 * a0 + a1 * a1 + a2 * a2 + a3 * a3;
  __syncthreads();
  if (tid < 64) {
    float S = ss[tid] + ss[64 + tid] + ss[128 + tid] + ss[192 + tid];
    float Q = sq[tid] + sq[64 + tid] + sq[128 + tid] + sq[192 + tid];
    atomicAdd(&stats[tid], S);
    atomicAdd(&stats[64 + tid], Q);
  }
}

// ---------------------------------------------------------------------------
// BN normalize + ReLU (materializing variant, no residual).
__global__ __launch_bounds__(256) void k_bn_relu(
    const float* __restrict__ pre, const float* __restrict__ stats,
    const float* __restrict__ g, const float* __restrict__ b,
    float* __restrict__ out) {
  size_t i = (size_t)blockIdx.x * 256 + threadIdx.x;
  int c = threadIdx.x & 63;
  const float invN = 1.0f / NN;
  float m = stats[c] * invN;
  float v = stats[64 + c] * invN - m * m;
  float sc = g[c] * rsqrtf(v + BN_EPS);
  float val = (pre[i] - m) * sc + b[c];
  out[i] = fmaxf(val, 0.f);
}

// ---------------------------------------------------------------------------
// Sort 1: per-node degree histogram.
__global__ __launch_bounds__(256) void k_hist(const int* __restrict__ dst,
                                              unsigned int* __restrict__ cnt) {
  int i0 = blockIdx.x * 256 + threadIdx.x;
  int stride = gridDim.x * 256;
  for (int e = i0; e < NE; e += stride) atomicAdd(&cnt[dst[e]], 1u);
}

// ---------------------------------------------------------------------------
// Sort 2 (scan phase 1): block partial sums of cnt.
__global__ __launch_bounds__(256) void k_scan1(
    const unsigned int* __restrict__ cnt, unsigned int* __restrict__ bsum) {
  __shared__ unsigned int s[256];
  int t = threadIdx.x;
  int i = blockIdx.x * 256 + t;
  s[t] = (i < NN) ? cnt[i] : 0u;
  __syncthreads();
  for (int off = 128; off > 0; off >>= 1) {
    if (t < off) s[t] += s[t + off];
    __syncthreads();
  }
  if (t == 0) bsum[blockIdx.x] = s[0];
}

// ---------------------------------------------------------------------------
// Sort 2 (scan phase 2): exclusive scan of the 391 block sums (one block).
__global__ __launch_bounds__(512) void k_scan2(
    const unsigned int* __restrict__ bsum, unsigned int* __restrict__ boff) {
  __shared__ unsigned int s[512];
  int t = threadIdx.x;
  unsigned int my = (t < SCAN_BLKS) ? bsum[t] : 0u;
  s[t] = my;
  __syncthreads();
  for (int off = 1; off < 512; off <<= 1) {
    unsigned int v = (t >= off) ? s[t - off] : 0u;
    __syncthreads();
    s[t] += v;
    __syncthreads();
  }
  if (t < SCAN_BLKS) boff[t] = s[t] - my;  // exclusive
}

// ---------------------------------------------------------------------------
// Sort 2 (scan phase 3): in-block exclusive scan + block offset.
// Writes nstart[i], ncur[i], nstart[NN], and gcur[] bucket cursors.
__global__ __launch_bounds__(256) void k_scan3(
    const unsigned int* __restrict__ cnt, const unsigned int* __restrict__ boff,
    unsigned int* __restrict__ nstart, unsigned int* __restrict__ ncur,
    unsigned int* __restrict__ gcur) {
  __shared__ unsigned int s[256];
  int t = threadIdx.x;
  int i = blockIdx.x * 256 + t;
  unsigned int my = (i < NN) ? cnt[i] : 0u;
  s[t] = my;
  __syncthreads();
  for (int off = 1; off < 256; off <<= 1) {
    unsigned int v = (t >= off) ? s[t - off] : 0u;
    __syncthreads();
    s[t] += v;
    __syncthreads();
  }
  if (i < NN) {
    unsigned int st = boff[blockIdx.x] + s[t] - my;  // exclusive global
    nstart[i] = st;
    ncur[i] = st;
    if ((i & 511) == 0) gcur[i >> 9] = st;
    if (i == NN - 1) nstart[NN] = st + my;  // == NE
  }
}

// ---------------------------------------------------------------------------
// Sort 3a: multisplit into 512-node buckets. Packed word = src | (dloc<<17).
// Per-batch bucket runs are contiguous -> L2 lines fill -> ~no write amp.
__global__ __launch_bounds__(256) void k_msplit(
    const int* __restrict__ src, const int* __restrict__ dst,
    unsigned int* __restrict__ gcur, unsigned int* __restrict__ staging) {
  __shared__ unsigned int hist[NBUK];
  __shared__ unsigned int gbase[NBUK];
  int tid = threadIdx.x;
  for (int i = tid; i < NBUK; i += 256) hist[i] = 0u;
  __syncthreads();
  int e0 = blockIdx.x * (256 * MSB);
  unsigned int pk[MSB], rk[MSB], bk[MSB];
#pragma unroll
  for (int i = 0; i < MSB; ++i) {
    int e = e0 + i * 256 + tid;
    if (e < NE) {
      int d = dst[e];
      unsigned int b = (unsigned int)(d >> 9);
      rk[i] = atomicAdd(&hist[b], 1u);
      pk[i] = (unsigned int)src[e] | ((unsigned int)(d & 511) << 17);
      bk[i] = b;
    } else {
      bk[i] = 0xFFFFFFFFu;
    }
  }
  __syncthreads();
  for (int i = tid; i < NBUK; i += 256)
    if (hist[i]) gbase[i] = atomicAdd(&gcur[i], hist[i]);
  __syncthreads();
#pragma unroll
  for (int i = 0; i < MSB; ++i)
    if (bk[i] != 0xFFFFFFFFu) staging[gbase[bk[i]] + rk[i]] = pk[i];
}

// ---------------------------------------------------------------------------
// Sort 3b: within-bucket scatter to exact node order (4 blocks per bucket;
// writes confined to a ~65 KB L2-resident window).
__global__ __launch_bounds__(256) void k_bscatter(
    const unsigned int* __restrict__ staging,
    const unsigned int* __restrict__ nstart, unsigned int* __restrict__ ncur,
    unsigned int* __restrict__ sorted_src) {
  int b = blockIdx.x >> 2, part = blockIdx.x & 3;
  int lo = (int)nstart[b * 512];
  int nend = (b + 1) * 512;
  if (nend > NN) nend = NN;
  int hi = (int)nstart[nend];
  for (int e = lo + part * 256 + threadIdx.x; e < hi; e += 1024) {
    unsigned int u = staging[e];
    unsigned int s = u & 0x1FFFFu;
    int node = (b << 9) + (int)(u >> 17);
    unsigned int pos = atomicAdd(&ncur[node], 1u);
    sorted_src[pos] = s;
  }
}

// ---------------------------------------------------------------------------
// Aggregation over sorted edges: one wave per node, lane = channel, mean
// fused, no atomics. Segments from immutable nstart.
__global__ __launch_bounds__(256) void k_aggr_sorted(
    const unsigned int* __restrict__ sorted_src,
    const unsigned int* __restrict__ nstart, const float* __restrict__ h,
    float* __restrict__ aggr) {
  int lane = threadIdx.x & 63;
  int n = (int)((blockIdx.x * 256 + threadIdx.x) >> 6);
  if (n >= NN) return;
  int e0 = (int)nstart[n];
  int e1 = (int)nstart[n + 1];
  float a0 = 0.f, a1 = 0.f, a2 = 0.f, a3 = 0.f;
  float a4 = 0.f, a5 = 0.f, a6 = 0.f, a7 = 0.f;
  int e = e0;
  for (; e + 8 <= e1; e += 8) {
    unsigned int s0 = sorted_src[e], s1 = sorted_src[e + 1];
    unsigned int s2 = sorted_src[e + 2], s3 = sorted_src[e + 3];
    unsigned int s4 = sorted_src[e + 4], s5 = sorted_src[e + 5];
    unsigned int s6 = sorted_src[e + 6], s7 = sorted_src[e + 7];
    a0 += h[(size_t)s0 * HD + lane];
    a1 += h[(size_t)s1 * HD + lane];
    a2 += h[(size_t)s2 * HD + lane];
    a3 += h[(size_t)s3 * HD + lane];
    a4 += h[(size_t)s4 * HD + lane];
    a5 += h[(size_t)s5 * HD + lane];
    a6 += h[(size_t)s6 * HD + lane];
    a7 += h[(size_t)s7 * HD + lane];
  }
  for (; e < e1; ++e) a0 += h[(size_t)sorted_src[e] * HD + lane];
  float acc = ((a0 + a1) + (a2 + a3)) + ((a4 + a5) + (a6 + a7));
  float cntf = (float)(e1 - e0);
  float inv = (cntf > 0.f) ? 1.0f / cntf : 0.f;
  aggr[(size_t)n * HD + lane] = acc * inv;
}

// ---------------------------------------------------------------------------
// SAGE combine + fused BN-stats partials. 32 rows/block, 512 threads.
// Safe with pre == aggr (block stages its own rows before overwriting).
__global__ __launch_bounds__(512) void k_combine(
    const float* __restrict__ aggr, const float* __restrict__ h,
    const float* __restrict__ Wl, const float* __restrict__ bl,
    const float* __restrict__ Wr, float* __restrict__ pre,
    float* __restrict__ stats) {
  __shared__ float sWl[HD * HD], sWr[HD * HD];  // 32 KB
  __shared__ float sAT[HD * 32], sHT[HD * 32];  // 16 KB  [k][r]
  int tid = threadIdx.x;
  for (int i = tid; i < HD * HD; i += 512) {
    sWl[i] = Wl[i];
    sWr[i] = Wr[i];
  }
  int row0 = blockIdx.x * 32;
  for (int i = tid; i < 32 * HD; i += 512) {
    int r = i >> 6, k = i & 63;
    sAT[k * 32 + r] = aggr[(size_t)(row0 + r) * HD + k];
    sHT[k * 32 + r] = h[(size_t)(row0 + r) * HD + k];
  }
  __syncthreads();
  int w = tid >> 6, c = tid & 63;  // wave w -> rows 4w..4w+3
  float bc = bl[c];
  float a0 = bc, a1 = bc, a2 = bc, a3 = bc;
#pragma unroll 4
  for (int k = 0; k < HD; ++k) {
    float wl = sWl[k * HD + c], wr = sWr[k * HD + c];
    const float4 av = *(const float4*)&sAT[k * 32 + w * 4];
    const float4 hv = *(const float4*)&sHT[k * 32 + w * 4];
    a0 = fmaf(av.x, wl, a0);
    a1 = fmaf(av.y, wl, a1);
    a2 = fmaf(av.z, wl, a2);
    a3 = fmaf(av.w, wl, a3);
    a0 = fmaf(hv.x, wr, a0);
    a1 = fmaf(hv.y, wr, a1);
    a2 = fmaf(hv.z, wr, a2);
    a3 = fmaf(hv.w, wr, a3);
  }
  size_t base = (size_t)(row0 + w * 4) * HD + c;
  pre[base] = a0;
  pre[base + HD] = a1;
  pre[base + 2 * HD] = a2;
  pre[base + 3 * HD] = a3;
  // fused BN stats partials
  __syncthreads();  // sAT reads done; reuse as scratch
  float* ss = sAT;          // [8][64]
  float* sq = sAT + 512;    // [8][64]
  ss[w * 64 + c] = a0 + a1 + a2 + a3;
  sq[w * 64 + c] = a0 * a0 + a1 * a1 + a2 * a2 + a3 * a3;
  __syncthreads();
  if (tid < 64) {
    float S = 0.f, Q = 0.f;
#pragma unroll
    for (int j = 0; j < 8; ++j) {
      S += ss[j * 64 + tid];
      Q += sq[j * 64 + tid];
    }
    atomicAdd(&stats[tid], S);
    atomicAdd(&stats[64 + tid], Q);
  }
}

// ---------------------------------------------------------------------------
// Final fused: BN + ReLU + residual + output head. h2 never materialized.
__global__ __launch_bounds__(256) void k_bn_relu_head(
    const float* __restrict__ pre, const float* __restrict__ stats,
    const float* __restrict__ g, const float* __restrict__ b,
    const float* __restrict__ resid, const float* __restrict__ Wo,
    const float* __restrict__ bo, float* __restrict__ out) {
  int lane = threadIdx.x & 63;
  int wid = (int)((blockIdx.x * blockDim.x + threadIdx.x) >> 6);
  int nw = (int)((gridDim.x * blockDim.x) >> 6);
  const float invN = 1.0f / NN;
  float m = stats[lane] * invN;
  float v = stats[64 + lane] * invN - m * m;
  float sc = g[lane] * rsqrtf(v + BN_EPS);
  float bb = b[lane];
  float w0 = Wo[lane * 2], w1 = Wo[lane * 2 + 1];
  float b0 = bo[0], b1 = bo[1];
  for (int row = wid; row < NN; row += nw) {
    size_t i = (size_t)row * HD + lane;
    float val = (pre[i] - m) * sc + bb;
    val = fmaxf(val, 0.f) + resid[i];
    float a0 = val * w0, a1 = val * w1;
#pragma unroll
    for (int off = 32; off > 0; off >>= 1) {
      a0 += __shfl_down(a0, off);
      a1 += __shfl_down(a1, off);
    }
    if (lane == 0) {
      out[(size_t)row * 2] = a0 + b0;
      out[(size_t)row * 2 + 1] = a1 + b1;
    }
  }
}

// ---------------------------------------------------------------------------
extern "C" void kernel_launch(void* const* d_in, const int* in_sizes, int n_in,
                              void* d_out, int out_size, void* d_ws,
                              size_t ws_size, hipStream_t stream) {
  const float* x = (const float*)d_in[0];
  const int* ei = (const int*)d_in[1];
  const float* Wp = (const float*)d_in[2];
  const float* bp = (const float*)d_in[3];
  const float* g_in = (const float*)d_in[4];
  const float* b_in = (const float*)d_in[5];
  const float* Wl0 = (const float*)d_in[6];
  const float* bl0 = (const float*)d_in[7];
  const float* Wr0 = (const float*)d_in[8];
  const float* g0 = (const float*)d_in[9];
  const float* b0 = (const float*)d_in[10];
  const float* Wl1 = (const float*)d_in[11];
  const float* bl1 = (const float*)d_in[12];
  const float* Wr1 = (const float*)d_in[13];
  const float* g1 = (const float*)d_in[14];
  const float* b1 = (const float*)d_in[15];
  const float* Wo = (const float*)d_in[16];
  const float* bo = (const float*)d_in[17];
  float* out = (float*)d_out;

  const int* src = ei;
  const int* dst = ei + NE;

  float* ws = (float*)d_ws;
  float* h0 = ws;                          // [NN*HD]
  float* h1 = ws + (size_t)NN * HD;        // [NN*HD]
  float* pre = ws + (size_t)2 * NN * HD;   // [NN*HD]  (also aggr buffer)
  unsigned int* staging = (unsigned int*)(ws + (size_t)3 * NN * HD);  // [NE]
  unsigned int* sorted_src = staging + NE;  // [NE]
  unsigned int* cnt = sorted_src + NE;      // [NN]
  unsigned int* nstart = cnt + NN;          // [NN+1]
  unsigned int* ncur = nstart + NN + 1;     // [NN]
  unsigned int* gcur = ncur + NN;           // [NBUK]
  unsigned int* bsum = gcur + NBUK;         // [SCAN_BLKS]
  unsigned int* boff = bsum + SCAN_BLKS;    // [SCAN_BLKS]
  float* stats0 = (float*)(boff + SCAN_BLKS);  // [128]
  float* stats1 = stats0 + 128;             // [128]
  float* stats2 = stats1 + 128;             // [128]

  const int ELEM_BLOCKS = (NN * HD) / 256;  // 25000
  const int AGGR_BLOCKS = 25000;            // 100k waves, 4/block
  const int MS_BLOCKS = (NE + 256 * MSB - 1) / (256 * MSB);  // 782

  hipMemsetAsync(stats0, 0, 3 * 128 * sizeof(float), stream);
  hipMemsetAsync(cnt, 0, NN * sizeof(unsigned int), stream);

  // ---- input projection (+stats) + BN/ReLU -> h0
  k_gemm_in<<<NN / 16, 256, 0, stream>>>(x, Wp, bp, pre, stats0);
  k_bn_relu<<<ELEM_BLOCKS, 256, 0, stream>>>(pre, stats0, g_in, b_in, h0);

  // ---- counting-sort edges by dst (two-phase binned; shared by both layers)
  k_hist<<<2048, 256, 0, stream>>>(dst, cnt);
  k_scan1<<<SCAN_BLKS, 256, 0, stream>>>(cnt, bsum);
  k_scan2<<<1, 512, 0, stream>>>(bsum, boff);
  k_scan3<<<SCAN_BLKS, 256, 0, stream>>>(cnt, boff, nstart, ncur, gcur);
  k_msplit<<<MS_BLOCKS, 256, 0, stream>>>(src, dst, gcur, staging);
  k_bscatter<<<NBUK * 4, 256, 0, stream>>>(staging, nstart, ncur, sorted_src);

  // ---- layer 0
  k_aggr_sorted<<<AGGR_BLOCKS, 256, 0, stream>>>(sorted_src, nstart, h0, pre);
  k_combine<<<NN / 32, 512, 0, stream>>>(pre, h0, Wl0, bl0, Wr0, pre, stats1);
  k_bn_relu<<<ELEM_BLOCKS, 256, 0, stream>>>(pre, stats1, g0, b0, h1);

  // ---- layer 1 + fused BN/ReLU/residual/head
  k_aggr_sorted<<<AGGR_BLOCKS, 256, 0, stream>>>(sorted_src, nstart, h1, pre);
  k_combine<<<NN / 32, 512, 0, stream>>>(pre, h1, Wl1, bl1, Wr1, pre, stats2);
  k_bn_relu_head<<<1024, 256, 0, stream>>>(pre, stats2, g1, b1, h0, Wo, bo,
                                           out);
}

// Round 6
// 965.370 us; speedup vs baseline: 1.3009x; 1.0498x over previous
//
#include <hip/hip_runtime.h>

#define NN 100000
#define NE 3200000
#define IC 128
#define HD 64
#define BN_EPS 1e-5f
#define NBUK 196      // ceil(NN / 512) buckets of 512 nodes (dst >> 9)
#define MSB 16        // edges per thread in multisplit (batch = 4096/block)
#define SCAN_BLKS 391 // ceil(NN / 256)

// ---------------------------------------------------------------------------
// Input projection + fused BN-stats partials. Register-tiled:
// 256 thr = 4 waves; wave w owns rows row0+8w..+7; lane = col c.
// Wp in LDS [k][c] (conflict-free); x rows read as lane-uniform float4
// broadcasts straight from global (each element touched once per wave).
__global__ __launch_bounds__(256) void k_gemm_in(
    const float* __restrict__ x, const float* __restrict__ Wp,
    const float* __restrict__ bp, float* __restrict__ pre,
    float* __restrict__ stats) {
  __shared__ float sW[IC * HD];          // 32 KB
  __shared__ float ss[256], sq[256];     // 2 KB stats scratch
  int tid = threadIdx.x;
  for (int i = tid; i < IC * HD; i += 256) sW[i] = Wp[i];
  __syncthreads();
  int w = tid >> 6, c = tid & 63;
  int row0 = blockIdx.x * 32 + w * 8;
  const float* xr = x + (size_t)row0 * IC;
  float bc = bp[c];
  float acc[8];
#pragma unroll
  for (int r = 0; r < 8; ++r) acc[r] = bc;
  for (int kg = 0; kg < IC; kg += 4) {
    float xreg[8][4];
#pragma unroll
    for (int r = 0; r < 8; ++r)
      *(float4*)&xreg[r][0] = *(const float4*)&xr[(size_t)r * IC + kg];
#pragma unroll
    for (int j = 0; j < 4; ++j) {
      float wv = sW[(kg + j) * HD + c];
#pragma unroll
      for (int r = 0; r < 8; ++r) acc[r] = fmaf(xreg[r][j], wv, acc[r]);
    }
  }
  float S = 0.f, Q = 0.f;
#pragma unroll
  for (int r = 0; r < 8; ++r) {
    pre[(size_t)(row0 + r) * HD + c] = acc[r];
    S += acc[r];
    Q = fmaf(acc[r], acc[r], Q);
  }
  ss[tid] = S;
  sq[tid] = Q;
  __syncthreads();
  if (tid < 64) {
    float Ts = ss[tid] + ss[64 + tid] + ss[128 + tid] + ss[192 + tid];
    float Tq = sq[tid] + sq[64 + tid] + sq[128 + tid] + sq[192 + tid];
    atomicAdd(&stats[tid], Ts);
    atomicAdd(&stats[64 + tid], Tq);
  }
}

// ---------------------------------------------------------------------------
// BN normalize + ReLU (materializing variant, no residual).
__global__ __launch_bounds__(256) void k_bn_relu(
    const float* __restrict__ pre, const float* __restrict__ stats,
    const float* __restrict__ g, const float* __restrict__ b,
    float* __restrict__ out) {
  size_t i = (size_t)blockIdx.x * 256 + threadIdx.x;
  int c = threadIdx.x & 63;
  const float invN = 1.0f / NN;
  float m = stats[c] * invN;
  float v = stats[64 + c] * invN - m * m;
  float sc = g[c] * rsqrtf(v + BN_EPS);
  float val = (pre[i] - m) * sc + b[c];
  out[i] = fmaxf(val, 0.f);
}

// ---------------------------------------------------------------------------
// Sort 1: per-node degree histogram.
__global__ __launch_bounds__(256) void k_hist(const int* __restrict__ dst,
                                              unsigned int* __restrict__ cnt) {
  int i0 = blockIdx.x * 256 + threadIdx.x;
  int stride = gridDim.x * 256;
  for (int e = i0; e < NE; e += stride) atomicAdd(&cnt[dst[e]], 1u);
}

// ---------------------------------------------------------------------------
// Sort 2 (scan phase 1): block partial sums of cnt.
__global__ __launch_bounds__(256) void k_scan1(
    const unsigned int* __restrict__ cnt, unsigned int* __restrict__ bsum) {
  __shared__ unsigned int s[256];
  int t = threadIdx.x;
  int i = blockIdx.x * 256 + t;
  s[t] = (i < NN) ? cnt[i] : 0u;
  __syncthreads();
  for (int off = 128; off > 0; off >>= 1) {
    if (t < off) s[t] += s[t + off];
    __syncthreads();
  }
  if (t == 0) bsum[blockIdx.x] = s[0];
}

// ---------------------------------------------------------------------------
// Sort 2 (scan phase 2): exclusive scan of the 391 block sums (one block).
__global__ __launch_bounds__(512) void k_scan2(
    const unsigned int* __restrict__ bsum, unsigned int* __restrict__ boff) {
  __shared__ unsigned int s[512];
  int t = threadIdx.x;
  unsigned int my = (t < SCAN_BLKS) ? bsum[t] : 0u;
  s[t] = my;
  __syncthreads();
  for (int off = 1; off < 512; off <<= 1) {
    unsigned int v = (t >= off) ? s[t - off] : 0u;
    __syncthreads();
    s[t] += v;
    __syncthreads();
  }
  if (t < SCAN_BLKS) boff[t] = s[t] - my;  // exclusive
}

// ---------------------------------------------------------------------------
// Sort 2 (scan phase 3): in-block exclusive scan + block offset.
// Writes nstart[i], ncur[i], nstart[NN], and gcur[] bucket cursors.
__global__ __launch_bounds__(256) void k_scan3(
    const unsigned int* __restrict__ cnt, const unsigned int* __restrict__ boff,
    unsigned int* __restrict__ nstart, unsigned int* __restrict__ ncur,
    unsigned int* __restrict__ gcur) {
  __shared__ unsigned int s[256];
  int t = threadIdx.x;
  int i = blockIdx.x * 256 + t;
  unsigned int my = (i < NN) ? cnt[i] : 0u;
  s[t] = my;
  __syncthreads();
  for (int off = 1; off < 256; off <<= 1) {
    unsigned int v = (t >= off) ? s[t - off] : 0u;
    __syncthreads();
    s[t] += v;
    __syncthreads();
  }
  if (i < NN) {
    unsigned int st = boff[blockIdx.x] + s[t] - my;  // exclusive global
    nstart[i] = st;
    ncur[i] = st;
    if ((i & 511) == 0) gcur[i >> 9] = st;
    if (i == NN - 1) nstart[NN] = st + my;  // == NE
  }
}

// ---------------------------------------------------------------------------
// Sort 3a: multisplit into 512-node buckets. Packed word = src | (dloc<<17).
__global__ __launch_bounds__(256) void k_msplit(
    const int* __restrict__ src, const int* __restrict__ dst,
    unsigned int* __restrict__ gcur, unsigned int* __restrict__ staging) {
  __shared__ unsigned int hist[NBUK];
  __shared__ unsigned int gbase[NBUK];
  int tid = threadIdx.x;
  for (int i = tid; i < NBUK; i += 256) hist[i] = 0u;
  __syncthreads();
  int e0 = blockIdx.x * (256 * MSB);
  unsigned int pk[MSB], rk[MSB], bk[MSB];
#pragma unroll
  for (int i = 0; i < MSB; ++i) {
    int e = e0 + i * 256 + tid;
    if (e < NE) {
      int d = dst[e];
      unsigned int b = (unsigned int)(d >> 9);
      rk[i] = atomicAdd(&hist[b], 1u);
      pk[i] = (unsigned int)src[e] | ((unsigned int)(d & 511) << 17);
      bk[i] = b;
    } else {
      bk[i] = 0xFFFFFFFFu;
    }
  }
  __syncthreads();
  for (int i = tid; i < NBUK; i += 256)
    if (hist[i]) gbase[i] = atomicAdd(&gcur[i], hist[i]);
  __syncthreads();
#pragma unroll
  for (int i = 0; i < MSB; ++i)
    if (bk[i] != 0xFFFFFFFFu) staging[gbase[bk[i]] + rk[i]] = pk[i];
}

// ---------------------------------------------------------------------------
// Sort 3b: within-bucket scatter to exact node order (4 blocks per bucket).
__global__ __launch_bounds__(256) void k_bscatter(
    const unsigned int* __restrict__ staging,
    const unsigned int* __restrict__ nstart, unsigned int* __restrict__ ncur,
    unsigned int* __restrict__ sorted_src) {
  int b = blockIdx.x >> 2, part = blockIdx.x & 3;
  int lo = (int)nstart[b * 512];
  int nend = (b + 1) * 512;
  if (nend > NN) nend = NN;
  int hi = (int)nstart[nend];
  for (int e = lo + part * 256 + threadIdx.x; e < hi; e += 1024) {
    unsigned int u = staging[e];
    unsigned int s = u & 0x1FFFFu;
    int node = (b << 9) + (int)(u >> 17);
    unsigned int pos = atomicAdd(&ncur[node], 1u);
    sorted_src[pos] = s;
  }
}

// ---------------------------------------------------------------------------
// Aggregation over sorted edges: one wave per node, lane = channel, mean
// fused, no atomics.
__global__ __launch_bounds__(256) void k_aggr_sorted(
    const unsigned int* __restrict__ sorted_src,
    const unsigned int* __restrict__ nstart, const float* __restrict__ h,
    float* __restrict__ aggr) {
  int lane = threadIdx.x & 63;
  int n = (int)((blockIdx.x * 256 + threadIdx.x) >> 6);
  if (n >= NN) return;
  int e0 = (int)nstart[n];
  int e1 = (int)nstart[n + 1];
  float a0 = 0.f, a1 = 0.f, a2 = 0.f, a3 = 0.f;
  float a4 = 0.f, a5 = 0.f, a6 = 0.f, a7 = 0.f;
  int e = e0;
  for (; e + 8 <= e1; e += 8) {
    unsigned int s0 = sorted_src[e], s1 = sorted_src[e + 1];
    unsigned int s2 = sorted_src[e + 2], s3 = sorted_src[e + 3];
    unsigned int s4 = sorted_src[e + 4], s5 = sorted_src[e + 5];
    unsigned int s6 = sorted_src[e + 6], s7 = sorted_src[e + 7];
    a0 += h[(size_t)s0 * HD + lane];
    a1 += h[(size_t)s1 * HD + lane];
    a2 += h[(size_t)s2 * HD + lane];
    a3 += h[(size_t)s3 * HD + lane];
    a4 += h[(size_t)s4 * HD + lane];
    a5 += h[(size_t)s5 * HD + lane];
    a6 += h[(size_t)s6 * HD + lane];
    a7 += h[(size_t)s7 * HD + lane];
  }
  for (; e < e1; ++e) a0 += h[(size_t)sorted_src[e] * HD + lane];
  float acc = ((a0 + a1) + (a2 + a3)) + ((a4 + a5) + (a6 + a7));
  float cntf = (float)(e1 - e0);
  float inv = (cntf > 0.f) ? 1.0f / cntf : 0.f;
  aggr[(size_t)n * HD + lane] = acc * inv;
}

// ---------------------------------------------------------------------------
// SAGE combine + fused BN-stats partials. Register-tiled like k_gemm_in:
// 512 thr = 8 waves; wave w owns rows row0+8w..+7; lane = col.
// Wl,Wr in LDS; aggr/h rows read as lane-uniform float4 broadcasts.
// Safe with pre == aggr: all reads of a block's rows happen in the k-loop,
// all writes after; blocks touch disjoint rows.
__global__ __launch_bounds__(512) void k_combine(
    const float* __restrict__ aggr, const float* __restrict__ h,
    const float* __restrict__ Wl, const float* __restrict__ bl,
    const float* __restrict__ Wr, float* __restrict__ pre,
    float* __restrict__ stats) {
  __shared__ float sWl[HD * HD], sWr[HD * HD];  // 32 KB
  __shared__ float ss[512], sq[512];            // 4 KB
  int tid = threadIdx.x;
  for (int i = tid; i < HD * HD; i += 512) {
    sWl[i] = Wl[i];
    sWr[i] = Wr[i];
  }
  __syncthreads();
  int w = tid >> 6, c = tid & 63;
  int row0 = blockIdx.x * 64 + w * 8;
  float bc = bl[c];
  float acc[8];
#pragma unroll
  for (int r = 0; r < 8; ++r) acc[r] = bc;
  for (int kg = 0; kg < HD; kg += 4) {
    float areg[8][4], hreg[8][4];
#pragma unroll
    for (int r = 0; r < 8; ++r) {
      int row = row0 + r;
      size_t rr = (size_t)(row < NN ? row : NN - 1) * HD + kg;
      *(float4*)&areg[r][0] = *(const float4*)&aggr[rr];
      *(float4*)&hreg[r][0] = *(const float4*)&h[rr];
    }
#pragma unroll
    for (int j = 0; j < 4; ++j) {
      float wl = sWl[(kg + j) * HD + c];
      float wr = sWr[(kg + j) * HD + c];
#pragma unroll
      for (int r = 0; r < 8; ++r) {
        acc[r] = fmaf(areg[r][j], wl, acc[r]);
        acc[r] = fmaf(hreg[r][j], wr, acc[r]);
      }
    }
  }
  float S = 0.f, Q = 0.f;
#pragma unroll
  for (int r = 0; r < 8; ++r) {
    int row = row0 + r;
    if (row < NN) {
      pre[(size_t)row * HD + c] = acc[r];
      S += acc[r];
      Q = fmaf(acc[r], acc[r], Q);
    }
  }
  ss[tid] = S;
  sq[tid] = Q;
  __syncthreads();
  if (tid < 64) {
    float Ts = 0.f, Tq = 0.f;
#pragma unroll
    for (int j = 0; j < 8; ++j) {
      Ts += ss[j * 64 + tid];
      Tq += sq[j * 64 + tid];
    }
    atomicAdd(&stats[tid], Ts);
    atomicAdd(&stats[64 + tid], Tq);
  }
}

// ---------------------------------------------------------------------------
// Final fused: BN + ReLU + residual + output head.
__global__ __launch_bounds__(256) void k_bn_relu_head(
    const float* __restrict__ pre, const float* __restrict__ stats,
    const float* __restrict__ g, const float* __restrict__ b,
    const float* __restrict__ resid, const float* __restrict__ Wo,
    const float* __restrict__ bo, float* __restrict__ out) {
  int lane = threadIdx.x & 63;
  int wid = (int)((blockIdx.x * blockDim.x + threadIdx.x) >> 6);
  int nw = (int)((gridDim.x * blockDim.x) >> 6);
  const float invN = 1.0f / NN;
  float m = stats[lane] * invN;
  float v = stats[64 + lane] * invN - m * m;
  float sc = g[lane] * rsqrtf(v + BN_EPS);
  float bb = b[lane];
  float w0 = Wo[lane * 2], w1 = Wo[lane * 2 + 1];
  float b0 = bo[0], b1 = bo[1];
  for (int row = wid; row < NN; row += nw) {
    size_t i = (size_t)row * HD + lane;
    float val = (pre[i] - m) * sc + bb;
    val = fmaxf(val, 0.f) + resid[i];
    float a0 = val * w0, a1 = val * w1;
#pragma unroll
    for (int off = 32; off > 0; off >>= 1) {
      a0 += __shfl_down(a0, off);
      a1 += __shfl_down(a1, off);
    }
    if (lane == 0) {
      out[(size_t)row * 2] = a0 + b0;
      out[(size_t)row * 2 + 1] = a1 + b1;
    }
  }
}

// ---------------------------------------------------------------------------
extern "C" void kernel_launch(void* const* d_in, const int* in_sizes, int n_in,
                              void* d_out, int out_size, void* d_ws,
                              size_t ws_size, hipStream_t stream) {
  const float* x = (const float*)d_in[0];
  const int* ei = (const int*)d_in[1];
  const float* Wp = (const float*)d_in[2];
  const float* bp = (const float*)d_in[3];
  const float* g_in = (const float*)d_in[4];
  const float* b_in = (const float*)d_in[5];
  const float* Wl0 = (const float*)d_in[6];
  const float* bl0 = (const float*)d_in[7];
  const float* Wr0 = (const float*)d_in[8];
  const float* g0 = (const float*)d_in[9];
  const float* b0 = (const float*)d_in[10];
  const float* Wl1 = (const float*)d_in[11];
  const float* bl1 = (const float*)d_in[12];
  const float* Wr1 = (const float*)d_in[13];
  const float* g1 = (const float*)d_in[14];
  const float* b1 = (const float*)d_in[15];
  const float* Wo = (const float*)d_in[16];
  const float* bo = (const float*)d_in[17];
  float* out = (float*)d_out;

  const int* src = ei;
  const int* dst = ei + NE;

  float* ws = (float*)d_ws;
  float* h0 = ws;                          // [NN*HD]
  float* h1 = ws + (size_t)NN * HD;        // [NN*HD]
  float* pre = ws + (size_t)2 * NN * HD;   // [NN*HD]  (also aggr buffer)
  unsigned int* staging = (unsigned int*)(ws + (size_t)3 * NN * HD);  // [NE]
  unsigned int* sorted_src = staging + NE;  // [NE]
  unsigned int* cnt = sorted_src + NE;      // [NN]
  unsigned int* nstart = cnt + NN;          // [NN+1]
  unsigned int* ncur = nstart + NN + 1;     // [NN]
  unsigned int* gcur = ncur + NN;           // [NBUK]
  unsigned int* bsum = gcur + NBUK;         // [SCAN_BLKS]
  unsigned int* boff = bsum + SCAN_BLKS;    // [SCAN_BLKS]
  float* stats0 = (float*)(boff + SCAN_BLKS);  // [128]
  float* stats1 = stats0 + 128;             // [128]
  float* stats2 = stats1 + 128;             // [128]

  const int ELEM_BLOCKS = (NN * HD) / 256;  // 25000
  const int AGGR_BLOCKS = 25000;            // 100k waves, 4/block
  const int MS_BLOCKS = (NE + 256 * MSB - 1) / (256 * MSB);  // 782
  const int COMB_BLOCKS = (NN + 63) / 64;   // 1563

  hipMemsetAsync(stats0, 0, 3 * 128 * sizeof(float), stream);
  hipMemsetAsync(cnt, 0, NN * sizeof(unsigned int), stream);

  // ---- input projection (+stats) + BN/ReLU -> h0
  k_gemm_in<<<NN / 32, 256, 0, stream>>>(x, Wp, bp, pre, stats0);
  k_bn_relu<<<ELEM_BLOCKS, 256, 0, stream>>>(pre, stats0, g_in, b_in, h0);

  // ---- counting-sort edges by dst (shared by both layers)
  k_hist<<<2048, 256, 0, stream>>>(dst, cnt);
  k_scan1<<<SCAN_BLKS, 256, 0, stream>>>(cnt, bsum);
  k_scan2<<<1, 512, 0, stream>>>(bsum, boff);
  k_scan3<<<SCAN_BLKS, 256, 0, stream>>>(cnt, boff, nstart, ncur, gcur);
  k_msplit<<<MS_BLOCKS, 256, 0, stream>>>(src, dst, gcur, staging);
  k_bscatter<<<NBUK * 4, 256, 0, stream>>>(staging, nstart, ncur, sorted_src);

  // ---- layer 0
  k_aggr_sorted<<<AGGR_BLOCKS, 256, 0, stream>>>(sorted_src, nstart, h0, pre);
  k_combine<<<COMB_BLOCKS, 512, 0, stream>>>(pre, h0, Wl0, bl0, Wr0, pre,
                                             stats1);
  k_bn_relu<<<ELEM_BLOCKS, 256, 0, stream>>>(pre, stats1, g0, b0, h1);

  // ---- layer 1 + fused BN/ReLU/residual/head
  k_aggr_sorted<<<AGGR_BLOCKS, 256, 0, stream>>>(sorted_src, nstart, h1, pre);
  k_combine<<<COMB_BLOCKS, 512, 0, stream>>>(pre, h1, Wl1, bl1, Wr1, pre,
                                             stats2);
  k_bn_relu_head<<<1024, 256, 0, stream>>>(pre, stats2, g1, b1, h0, Wo, bo,
                                           out);
}

// Round 7
// 659.350 us; speedup vs baseline: 1.9047x; 1.4641x over previous
//
#include <hip/hip_runtime.h>
#include <hip/hip_bf16.h>

#define NN 100000
#define NE 3200000
#define IC 128
#define HD 64
#define BN_EPS 1e-5f
#define NBUK 196      // ceil(NN / 512) buckets of 512 nodes (dst >> 9)
#define MSB 16        // edges per thread in multisplit (batch = 4096/block)
#define SCAN_BLKS 391 // ceil(NN / 256)
#define GI_TILE 32    // rows per tile, input gemm (NN % 32 == 0)
#define CB_TILE 64    // rows per tile, combine

__device__ __forceinline__ float bf2f(unsigned short u) {
  return __uint_as_float(((unsigned)u) << 16);
}

// ---------------------------------------------------------------------------
// Input projection + fused BN-stats. Persistent blocks, LDS-staged rows.
// 256 thr = 4 waves; wave w owns tile rows w*8..w*8+7; lane = col c.
// Row reads are uniform-address float4 broadcasts from LDS (conflict-free);
// weight reads are per-lane consecutive (conflict-free).
__global__ __launch_bounds__(256) void k_gemm_in(
    const float* __restrict__ x, const float* __restrict__ Wp,
    const float* __restrict__ bp, float* __restrict__ pre,
    float* __restrict__ stats) {
  __shared__ float sW[IC * HD];        // 32 KB
  __shared__ float sX[GI_TILE * IC];   // 16 KB
  __shared__ float ss[256], sq[256];   // 2 KB
  int tid = threadIdx.x;
  for (int i = tid; i < IC * HD; i += 256) sW[i] = Wp[i];
  int w = tid >> 6, c = tid & 63;
  int rb = w * 8;
  float bc = bp[c];
  float S = 0.f, Q = 0.f;
  const int NT = NN / GI_TILE;  // 3125
  for (int t = blockIdx.x; t < NT; t += gridDim.x) {
    int row0 = t * GI_TILE;
    __syncthreads();  // prior compute reads of sX done
    for (int i = tid; i < GI_TILE * IC / 4; i += 256)
      *(float4*)&sX[i * 4] = *(const float4*)&x[(size_t)row0 * IC + i * 4];
    __syncthreads();
    float acc[8];
#pragma unroll
    for (int r = 0; r < 8; ++r) acc[r] = bc;
    for (int kg = 0; kg < IC; kg += 4) {
      float4 xr[8];
#pragma unroll
      for (int r = 0; r < 8; ++r)
        xr[r] = *(const float4*)&sX[(rb + r) * IC + kg];
#pragma unroll
      for (int j = 0; j < 4; ++j) {
        float wv = sW[(kg + j) * HD + c];
#pragma unroll
        for (int r = 0; r < 8; ++r)
          acc[r] = fmaf(((const float*)&xr[r])[j], wv, acc[r]);
      }
    }
#pragma unroll
    for (int r = 0; r < 8; ++r) {
      pre[(size_t)(row0 + rb + r) * HD + c] = acc[r];
      S += acc[r];
      Q = fmaf(acc[r], acc[r], Q);
    }
  }
  ss[tid] = S;
  sq[tid] = Q;
  __syncthreads();
  if (tid < 64) {
    float Ts = ss[tid] + ss[64 + tid] + ss[128 + tid] + ss[192 + tid];
    float Tq = sq[tid] + sq[64 + tid] + sq[128 + tid] + sq[192 + tid];
    atomicAdd(&stats[tid], Ts);
    atomicAdd(&stats[64 + tid], Tq);
  }
}

// ---------------------------------------------------------------------------
// BN normalize + ReLU -> bf16 hidden state.
__global__ __launch_bounds__(256) void k_bn_relu(
    const float* __restrict__ pre, const float* __restrict__ stats,
    const float* __restrict__ g, const float* __restrict__ b,
    __hip_bfloat16* __restrict__ out16) {
  size_t i = (size_t)blockIdx.x * 256 + threadIdx.x;
  int c = threadIdx.x & 63;
  const float invN = 1.0f / NN;
  float m = stats[c] * invN;
  float v = stats[64 + c] * invN - m * m;
  float sc = g[c] * rsqrtf(v + BN_EPS);
  float val = (pre[i] - m) * sc + b[c];
  out16[i] = __float2bfloat16(fmaxf(val, 0.f));
}

// ---------------------------------------------------------------------------
// Sort 1: per-node degree histogram.
__global__ __launch_bounds__(256) void k_hist(const int* __restrict__ dst,
                                              unsigned int* __restrict__ cnt) {
  int i0 = blockIdx.x * 256 + threadIdx.x;
  int stride = gridDim.x * 256;
  for (int e = i0; e < NE; e += stride) atomicAdd(&cnt[dst[e]], 1u);
}

// ---------------------------------------------------------------------------
// Sort 2a: block partial sums of cnt.
__global__ __launch_bounds__(256) void k_scan1(
    const unsigned int* __restrict__ cnt, unsigned int* __restrict__ bsum) {
  __shared__ unsigned int s[256];
  int t = threadIdx.x;
  int i = blockIdx.x * 256 + t;
  s[t] = (i < NN) ? cnt[i] : 0u;
  __syncthreads();
  for (int off = 128; off > 0; off >>= 1) {
    if (t < off) s[t] += s[t + off];
    __syncthreads();
  }
  if (t == 0) bsum[blockIdx.x] = s[0];
}

// ---------------------------------------------------------------------------
// Sort 2b: exclusive scan of the 391 block sums (one block).
__global__ __launch_bounds__(512) void k_scan2(
    const unsigned int* __restrict__ bsum, unsigned int* __restrict__ boff) {
  __shared__ unsigned int s[512];
  int t = threadIdx.x;
  unsigned int my = (t < SCAN_BLKS) ? bsum[t] : 0u;
  s[t] = my;
  __syncthreads();
  for (int off = 1; off < 512; off <<= 1) {
    unsigned int v = (t >= off) ? s[t - off] : 0u;
    __syncthreads();
    s[t] += v;
    __syncthreads();
  }
  if (t < SCAN_BLKS) boff[t] = s[t] - my;  // exclusive
}

// ---------------------------------------------------------------------------
// Sort 2c: in-block exclusive scan + block offset -> nstart/ncur/gcur.
__global__ __launch_bounds__(256) void k_scan3(
    const unsigned int* __restrict__ cnt, const unsigned int* __restrict__ boff,
    unsigned int* __restrict__ nstart, unsigned int* __restrict__ ncur,
    unsigned int* __restrict__ gcur) {
  __shared__ unsigned int s[256];
  int t = threadIdx.x;
  int i = blockIdx.x * 256 + t;
  unsigned int my = (i < NN) ? cnt[i] : 0u;
  s[t] = my;
  __syncthreads();
  for (int off = 1; off < 256; off <<= 1) {
    unsigned int v = (t >= off) ? s[t - off] : 0u;
    __syncthreads();
    s[t] += v;
    __syncthreads();
  }
  if (i < NN) {
    unsigned int st = boff[blockIdx.x] + s[t] - my;  // exclusive global
    nstart[i] = st;
    ncur[i] = st;
    if ((i & 511) == 0) gcur[i >> 9] = st;
    if (i == NN - 1) nstart[NN] = st + my;  // == NE
  }
}

// ---------------------------------------------------------------------------
// Sort 3a: multisplit into 512-node buckets. Packed word = src | (dloc<<17).
__global__ __launch_bounds__(256) void k_msplit(
    const int* __restrict__ src, const int* __restrict__ dst,
    unsigned int* __restrict__ gcur, unsigned int* __restrict__ staging) {
  __shared__ unsigned int hist[NBUK];
  __shared__ unsigned int gbase[NBUK];
  int tid = threadIdx.x;
  for (int i = tid; i < NBUK; i += 256) hist[i] = 0u;
  __syncthreads();
  int e0 = blockIdx.x * (256 * MSB);
  unsigned int pk[MSB], rk[MSB], bk[MSB];
#pragma unroll
  for (int i = 0; i < MSB; ++i) {
    int e = e0 + i * 256 + tid;
    if (e < NE) {
      int d = dst[e];
      unsigned int b = (unsigned int)(d >> 9);
      rk[i] = atomicAdd(&hist[b], 1u);
      pk[i] = (unsigned int)src[e] | ((unsigned int)(d & 511) << 17);
      bk[i] = b;
    } else {
      bk[i] = 0xFFFFFFFFu;
    }
  }
  __syncthreads();
  for (int i = tid; i < NBUK; i += 256)
    if (hist[i]) gbase[i] = atomicAdd(&gcur[i], hist[i]);
  __syncthreads();
#pragma unroll
  for (int i = 0; i < MSB; ++i)
    if (bk[i] != 0xFFFFFFFFu) staging[gbase[bk[i]] + rk[i]] = pk[i];
}

// ---------------------------------------------------------------------------
// Sort 3b: within-bucket scatter to exact node order (4 blocks per bucket).
__global__ __launch_bounds__(256) void k_bscatter(
    const unsigned int* __restrict__ staging,
    const unsigned int* __restrict__ nstart, unsigned int* __restrict__ ncur,
    unsigned int* __restrict__ sorted_src) {
  int b = blockIdx.x >> 2, part = blockIdx.x & 3;
  int lo = (int)nstart[b * 512];
  int nend = (b + 1) * 512;
  if (nend > NN) nend = NN;
  int hi = (int)nstart[nend];
  for (int e = lo + part * 256 + threadIdx.x; e < hi; e += 1024) {
    unsigned int u = staging[e];
    unsigned int s = u & 0x1FFFFu;
    int node = (b << 9) + (int)(u >> 17);
    unsigned int pos = atomicAdd(&ncur[node], 1u);
    sorted_src[pos] = s;
  }
}

// ---------------------------------------------------------------------------
// Aggregation over sorted edges (bf16 gather): one wave per node, lane =
// channel, f32 accumulate, mean fused, no atomics.
__global__ __launch_bounds__(256) void k_aggr_sorted(
    const unsigned int* __restrict__ sorted_src,
    const unsigned int* __restrict__ nstart,
    const unsigned short* __restrict__ h16, float* __restrict__ aggr) {
  int lane = threadIdx.x & 63;
  int n = (int)((blockIdx.x * 256 + threadIdx.x) >> 6);
  if (n >= NN) return;
  int e0 = (int)nstart[n];
  int e1 = (int)nstart[n + 1];
  float a0 = 0.f, a1 = 0.f, a2 = 0.f, a3 = 0.f;
  float a4 = 0.f, a5 = 0.f, a6 = 0.f, a7 = 0.f;
  int e = e0;
  for (; e + 8 <= e1; e += 8) {
    unsigned int s0 = sorted_src[e], s1 = sorted_src[e + 1];
    unsigned int s2 = sorted_src[e + 2], s3 = sorted_src[e + 3];
    unsigned int s4 = sorted_src[e + 4], s5 = sorted_src[e + 5];
    unsigned int s6 = sorted_src[e + 6], s7 = sorted_src[e + 7];
    a0 += bf2f(h16[(size_t)s0 * HD + lane]);
    a1 += bf2f(h16[(size_t)s1 * HD + lane]);
    a2 += bf2f(h16[(size_t)s2 * HD + lane]);
    a3 += bf2f(h16[(size_t)s3 * HD + lane]);
    a4 += bf2f(h16[(size_t)s4 * HD + lane]);
    a5 += bf2f(h16[(size_t)s5 * HD + lane]);
    a6 += bf2f(h16[(size_t)s6 * HD + lane]);
    a7 += bf2f(h16[(size_t)s7 * HD + lane]);
  }
  for (; e < e1; ++e) a0 += bf2f(h16[(size_t)sorted_src[e] * HD + lane]);
  float acc = ((a0 + a1) + (a2 + a3)) + ((a4 + a5) + (a6 + a7));
  float cntf = (float)(e1 - e0);
  float inv = (cntf > 0.f) ? 1.0f / cntf : 0.f;
  aggr[(size_t)n * HD + lane] = acc * inv;
}

// ---------------------------------------------------------------------------
// SAGE combine + fused BN-stats. Persistent blocks, LDS-staged row tiles.
// 512 thr = 8 waves; wave w owns tile rows w*8..w*8+7; lane = col c.
// aggr staged f32; h staged bf16->f32. Safe with pre == aggr (stage, sync,
// then overwrite own rows; blocks own disjoint tiles).
__global__ __launch_bounds__(512) void k_combine(
    const float* __restrict__ aggr, const unsigned short* __restrict__ h16,
    const float* __restrict__ Wl, const float* __restrict__ bl,
    const float* __restrict__ Wr, float* __restrict__ pre,
    float* __restrict__ stats) {
  __shared__ float sWl[HD * HD], sWr[HD * HD];      // 32 KB
  __shared__ float sA[CB_TILE * HD], sH[CB_TILE * HD];  // 32 KB
  __shared__ float ss[512], sq[512];                // 4 KB
  int tid = threadIdx.x;
  for (int i = tid; i < HD * HD; i += 512) {
    sWl[i] = Wl[i];
    sWr[i] = Wr[i];
  }
  int w = tid >> 6, c = tid & 63;
  int rb = w * 8;
  float bc = bl[c];
  float S = 0.f, Q = 0.f;
  const int NT = (NN + CB_TILE - 1) / CB_TILE;  // 1563
  for (int t = blockIdx.x; t < NT; t += gridDim.x) {
    int row0 = t * CB_TILE;
    __syncthreads();  // prior compute reads done
    {
      // stage: 4096 elems per array; thread handles 8 contiguous elems
      int row = row0 + (tid >> 3);
      int rowc = row < NN ? row : NN - 1;
      int col0 = (tid & 7) * 8;
      const float* srcA = &aggr[(size_t)rowc * HD + col0];
      float4 a0 = *(const float4*)srcA;
      float4 a1 = *(const float4*)(srcA + 4);
      uint4 hu = *(const uint4*)&h16[(size_t)rowc * HD + col0];
      float* dA = &sA[(tid >> 3) * HD + col0];
      *(float4*)dA = a0;
      *(float4*)(dA + 4) = a1;
      float* dH = &sH[(tid >> 3) * HD + col0];
      dH[0] = bf2f((unsigned short)(hu.x & 0xFFFFu));
      dH[1] = bf2f((unsigned short)(hu.x >> 16));
      dH[2] = bf2f((unsigned short)(hu.y & 0xFFFFu));
      dH[3] = bf2f((unsigned short)(hu.y >> 16));
      dH[4] = bf2f((unsigned short)(hu.z & 0xFFFFu));
      dH[5] = bf2f((unsigned short)(hu.z >> 16));
      dH[6] = bf2f((unsigned short)(hu.w & 0xFFFFu));
      dH[7] = bf2f((unsigned short)(hu.w >> 16));
    }
    __syncthreads();
    float acc[8];
#pragma unroll
    for (int r = 0; r < 8; ++r) acc[r] = bc;
    for (int kg = 0; kg < HD; kg += 4) {
      float4 a4[8], h4[8];
#pragma unroll
      for (int r = 0; r < 8; ++r) {
        a4[r] = *(const float4*)&sA[(rb + r) * HD + kg];
        h4[r] = *(const float4*)&sH[(rb + r) * HD + kg];
      }
#pragma unroll
      for (int j = 0; j < 4; ++j) {
        float wl = sWl[(kg + j) * HD + c];
        float wr = sWr[(kg + j) * HD + c];
#pragma unroll
        for (int r = 0; r < 8; ++r) {
          acc[r] = fmaf(((const float*)&a4[r])[j], wl, acc[r]);
          acc[r] = fmaf(((const float*)&h4[r])[j], wr, acc[r]);
        }
      }
    }
#pragma unroll
    for (int r = 0; r < 8; ++r) {
      int row = row0 + rb + r;
      if (row < NN) {
        pre[(size_t)row * HD + c] = acc[r];
        S += acc[r];
        Q = fmaf(acc[r], acc[r], Q);
      }
    }
  }
  ss[tid] = S;
  sq[tid] = Q;
  __syncthreads();
  if (tid < 64) {
    float Ts = 0.f, Tq = 0.f;
#pragma unroll
    for (int j = 0; j < 8; ++j) {
      Ts += ss[j * 64 + tid];
      Tq += sq[j * 64 + tid];
    }
    atomicAdd(&stats[tid], Ts);
    atomicAdd(&stats[64 + tid], Tq);
  }
}

// ---------------------------------------------------------------------------
// Final fused: BN + ReLU + residual(bf16) + output head.
__global__ __launch_bounds__(256) void k_bn_relu_head(
    const float* __restrict__ pre, const float* __restrict__ stats,
    const float* __restrict__ g, const float* __restrict__ b,
    const unsigned short* __restrict__ resid16, const float* __restrict__ Wo,
    const float* __restrict__ bo, float* __restrict__ out) {
  int lane = threadIdx.x & 63;
  int wid = (int)((blockIdx.x * blockDim.x + threadIdx.x) >> 6);
  int nw = (int)((gridDim.x * blockDim.x) >> 6);
  const float invN = 1.0f / NN;
  float m = stats[lane] * invN;
  float v = stats[64 + lane] * invN - m * m;
  float sc = g[lane] * rsqrtf(v + BN_EPS);
  float bb = b[lane];
  float w0 = Wo[lane * 2], w1 = Wo[lane * 2 + 1];
  float b0 = bo[0], b1 = bo[1];
  for (int row = wid; row < NN; row += nw) {
    size_t i = (size_t)row * HD + lane;
    float val = (pre[i] - m) * sc + bb;
    val = fmaxf(val, 0.f) + bf2f(resid16[i]);
    float a0 = val * w0, a1 = val * w1;
#pragma unroll
    for (int off = 32; off > 0; off >>= 1) {
      a0 += __shfl_down(a0, off);
      a1 += __shfl_down(a1, off);
    }
    if (lane == 0) {
      out[(size_t)row * 2] = a0 + b0;
      out[(size_t)row * 2 + 1] = a1 + b1;
    }
  }
}

// ---------------------------------------------------------------------------
extern "C" void kernel_launch(void* const* d_in, const int* in_sizes, int n_in,
                              void* d_out, int out_size, void* d_ws,
                              size_t ws_size, hipStream_t stream) {
  const float* x = (const float*)d_in[0];
  const int* ei = (const int*)d_in[1];
  const float* Wp = (const float*)d_in[2];
  const float* bp = (const float*)d_in[3];
  const float* g_in = (const float*)d_in[4];
  const float* b_in = (const float*)d_in[5];
  const float* Wl0 = (const float*)d_in[6];
  const float* bl0 = (const float*)d_in[7];
  const float* Wr0 = (const float*)d_in[8];
  const float* g0 = (const float*)d_in[9];
  const float* b0 = (const float*)d_in[10];
  const float* Wl1 = (const float*)d_in[11];
  const float* bl1 = (const float*)d_in[12];
  const float* Wr1 = (const float*)d_in[13];
  const float* g1 = (const float*)d_in[14];
  const float* b1 = (const float*)d_in[15];
  const float* Wo = (const float*)d_in[16];
  const float* bo = (const float*)d_in[17];
  float* out = (float*)d_out;

  const int* src = ei;
  const int* dst = ei + NE;

  float* ws = (float*)d_ws;
  float* pre = ws;  // [NN*HD] f32 (also aggr buffer)
  __hip_bfloat16* h0b = (__hip_bfloat16*)(ws + (size_t)NN * HD);  // [NN*HD]
  __hip_bfloat16* h1b = h0b + (size_t)NN * HD;                    // [NN*HD]
  unsigned int* staging = (unsigned int*)(h1b + (size_t)NN * HD); // [NE]
  unsigned int* sorted_src = staging + NE;  // [NE]
  unsigned int* cnt = sorted_src + NE;      // [NN]
  unsigned int* nstart = cnt + NN;          // [NN+1]
  unsigned int* ncur = nstart + NN + 1;     // [NN]
  unsigned int* gcur = ncur + NN;           // [NBUK]
  unsigned int* bsum = gcur + NBUK;         // [SCAN_BLKS]
  unsigned int* boff = bsum + SCAN_BLKS;    // [SCAN_BLKS]
  float* stats0 = (float*)(boff + SCAN_BLKS);  // [128]
  float* stats1 = stats0 + 128;             // [128]
  float* stats2 = stats1 + 128;             // [128]

  const int ELEM_BLOCKS = (NN * HD) / 256;  // 25000
  const int AGGR_BLOCKS = 25000;            // 100k waves, 4/block
  const int MS_BLOCKS = (NE + 256 * MSB - 1) / (256 * MSB);  // 782

  hipMemsetAsync(stats0, 0, 3 * 128 * sizeof(float), stream);
  hipMemsetAsync(cnt, 0, NN * sizeof(unsigned int), stream);

  // ---- input projection (+stats) + BN/ReLU -> h0 (bf16)
  k_gemm_in<<<768, 256, 0, stream>>>(x, Wp, bp, pre, stats0);
  k_bn_relu<<<ELEM_BLOCKS, 256, 0, stream>>>(pre, stats0, g_in, b_in, h0b);

  // ---- counting-sort edges by dst (shared by both layers)
  k_hist<<<2048, 256, 0, stream>>>(dst, cnt);
  k_scan1<<<SCAN_BLKS, 256, 0, stream>>>(cnt, bsum);
  k_scan2<<<1, 512, 0, stream>>>(bsum, boff);
  k_scan3<<<SCAN_BLKS, 256, 0, stream>>>(cnt, boff, nstart, ncur, gcur);
  k_msplit<<<MS_BLOCKS, 256, 0, stream>>>(src, dst, gcur, staging);
  k_bscatter<<<NBUK * 4, 256, 0, stream>>>(staging, nstart, ncur, sorted_src);

  // ---- layer 0
  k_aggr_sorted<<<AGGR_BLOCKS, 256, 0, stream>>>(
      sorted_src, nstart, (const unsigned short*)h0b, pre);
  k_combine<<<512, 512, 0, stream>>>(pre, (const unsigned short*)h0b, Wl0,
                                     bl0, Wr0, pre, stats1);
  k_bn_relu<<<ELEM_BLOCKS, 256, 0, stream>>>(pre, stats1, g0, b0, h1b);

  // ---- layer 1 + fused BN/ReLU/residual/head
  k_aggr_sorted<<<AGGR_BLOCKS, 256, 0, stream>>>(
      sorted_src, nstart, (const unsigned short*)h1b, pre);
  k_combine<<<512, 512, 0, stream>>>(pre, (const unsigned short*)h1b, Wl1,
                                     bl1, Wr1, pre, stats2);
  k_bn_relu_head<<<1024, 256, 0, stream>>>(pre, stats2, g1, b1,
                                           (const unsigned short*)h0b, Wo, bo,
                                           out);
}

// Round 8
// 566.875 us; speedup vs baseline: 2.2154x; 1.1631x over previous
//
#include <hip/hip_runtime.h>
#include <hip/hip_bf16.h>

#define NN 100000
#define NE 3200000
#define IC 128
#define HD 64
#define BN_EPS 1e-5f
#define NBUK 196      // ceil(NN / 512) buckets of 512 nodes (dst >> 9)
#define MSB 16        // edges per thread in multisplit (batch = 4096/block)
#define GI_TILE 32    // rows per tile, input gemm
#define CB_TILE 64    // rows per tile, combine

__device__ __forceinline__ float bf2f(unsigned short u) {
  return __uint_as_float(((unsigned)u) << 16);
}

// ---------------------------------------------------------------------------
// Input projection + fused BN-stats. Persistent blocks, LDS-staged rows.
__global__ __launch_bounds__(256) void k_gemm_in(
    const float* __restrict__ x, const float* __restrict__ Wp,
    const float* __restrict__ bp, float* __restrict__ pre,
    float* __restrict__ stats) {
  __shared__ float sW[IC * HD];        // 32 KB
  __shared__ float sX[GI_TILE * IC];   // 16 KB
  __shared__ float ss[256], sq[256];   // 2 KB
  int tid = threadIdx.x;
  for (int i = tid; i < IC * HD; i += 256) sW[i] = Wp[i];
  int w = tid >> 6, c = tid & 63;
  int rb = w * 8;
  float bc = bp[c];
  float S = 0.f, Q = 0.f;
  const int NT = NN / GI_TILE;  // 3125
  for (int t = blockIdx.x; t < NT; t += gridDim.x) {
    int row0 = t * GI_TILE;
    __syncthreads();  // prior compute reads of sX done
    for (int i = tid; i < GI_TILE * IC / 4; i += 256)
      *(float4*)&sX[i * 4] = *(const float4*)&x[(size_t)row0 * IC + i * 4];
    __syncthreads();
    float acc[8];
#pragma unroll
    for (int r = 0; r < 8; ++r) acc[r] = bc;
    for (int kg = 0; kg < IC; kg += 4) {
      float4 xr[8];
#pragma unroll
      for (int r = 0; r < 8; ++r)
        xr[r] = *(const float4*)&sX[(rb + r) * IC + kg];
#pragma unroll
      for (int j = 0; j < 4; ++j) {
        float wv = sW[(kg + j) * HD + c];
#pragma unroll
        for (int r = 0; r < 8; ++r)
          acc[r] = fmaf(((const float*)&xr[r])[j], wv, acc[r]);
      }
    }
#pragma unroll
    for (int r = 0; r < 8; ++r) {
      pre[(size_t)(row0 + rb + r) * HD + c] = acc[r];
      S += acc[r];
      Q = fmaf(acc[r], acc[r], Q);
    }
  }
  ss[tid] = S;
  sq[tid] = Q;
  __syncthreads();
  if (tid < 64) {
    float Ts = ss[tid] + ss[64 + tid] + ss[128 + tid] + ss[192 + tid];
    float Tq = sq[tid] + sq[64 + tid] + sq[128 + tid] + sq[192 + tid];
    atomicAdd(&stats[tid], Ts);
    atomicAdd(&stats[64 + tid], Tq);
  }
}

// ---------------------------------------------------------------------------
// BN normalize + ReLU -> bf16 hidden state.
__global__ __launch_bounds__(256) void k_bn_relu(
    const float* __restrict__ pre, const float* __restrict__ stats,
    const float* __restrict__ g, const float* __restrict__ b,
    __hip_bfloat16* __restrict__ out16) {
  size_t i = (size_t)blockIdx.x * 256 + threadIdx.x;
  int c = threadIdx.x & 63;
  const float invN = 1.0f / NN;
  float m = stats[c] * invN;
  float v = stats[64 + c] * invN - m * m;
  float sc = g[c] * rsqrtf(v + BN_EPS);
  float val = (pre[i] - m) * sc + b[c];
  out16[i] = __float2bfloat16(fmaxf(val, 0.f));
}

// ---------------------------------------------------------------------------
// Sort 1: bucket histogram via LDS (196 bins), block-reduced to global.
__global__ __launch_bounds__(256) void k_bhist(
    const int* __restrict__ dst, unsigned int* __restrict__ bcnt) {
  __shared__ unsigned int h[NBUK];
  for (int i = threadIdx.x; i < NBUK; i += 256) h[i] = 0u;
  __syncthreads();
  int i0 = blockIdx.x * 256 + threadIdx.x;
  int stride = gridDim.x * 256;
  for (int e = i0; e < NE; e += stride)
    atomicAdd(&h[((unsigned)dst[e]) >> 9], 1u);
  __syncthreads();
  for (int i = threadIdx.x; i < NBUK; i += 256)
    if (h[i]) atomicAdd(&bcnt[i], h[i]);
}

// ---------------------------------------------------------------------------
// Sort 2: exclusive scan of 196 bucket counts (one block).
__global__ __launch_bounds__(256) void k_bscan(
    const unsigned int* __restrict__ bcnt, unsigned int* __restrict__ gstart,
    unsigned int* __restrict__ gcur) {
  __shared__ unsigned int s[256];
  int t = threadIdx.x;
  unsigned int my = (t < NBUK) ? bcnt[t] : 0u;
  s[t] = my;
  __syncthreads();
  for (int off = 1; off < 256; off <<= 1) {
    unsigned int v = (t >= off) ? s[t - off] : 0u;
    __syncthreads();
    s[t] += v;
    __syncthreads();
  }
  if (t < NBUK) {
    gstart[t] = s[t] - my;
    gcur[t] = s[t] - my;
  }
  if (t == NBUK - 1) gstart[NBUK] = s[t];
}

// ---------------------------------------------------------------------------
// Sort 3: multisplit into 512-node buckets. Packed word = src | (dloc<<17).
__global__ __launch_bounds__(256) void k_msplit(
    const int* __restrict__ src, const int* __restrict__ dst,
    unsigned int* __restrict__ gcur, unsigned int* __restrict__ staging) {
  __shared__ unsigned int hist[NBUK];
  __shared__ unsigned int gbase[NBUK];
  int tid = threadIdx.x;
  for (int i = tid; i < NBUK; i += 256) hist[i] = 0u;
  __syncthreads();
  int e0 = blockIdx.x * (256 * MSB);
  unsigned int pk[MSB], rk[MSB], bk[MSB];
#pragma unroll
  for (int i = 0; i < MSB; ++i) {
    int e = e0 + i * 256 + tid;
    if (e < NE) {
      int d = dst[e];
      unsigned int b = (unsigned int)(d >> 9);
      rk[i] = atomicAdd(&hist[b], 1u);
      pk[i] = (unsigned int)src[e] | ((unsigned int)(d & 511) << 17);
      bk[i] = b;
    } else {
      bk[i] = 0xFFFFFFFFu;
    }
  }
  __syncthreads();
  for (int i = tid; i < NBUK; i += 256)
    if (hist[i]) gbase[i] = atomicAdd(&gcur[i], hist[i]);
  __syncthreads();
#pragma unroll
  for (int i = 0; i < MSB; ++i)
    if (bk[i] != 0xFFFFFFFFu) staging[gbase[bk[i]] + rk[i]] = pk[i];
}

// ---------------------------------------------------------------------------
// Sort 4: per-bucket node-degree histogram + scan (one block per bucket).
// Reads the bucket's staging segment, LDS-counts the 512 dloc bins,
// block-scans, writes nstart/ncur. No global atomics.
__global__ __launch_bounds__(512) void k_nscan(
    const unsigned int* __restrict__ staging,
    const unsigned int* __restrict__ gstart, unsigned int* __restrict__ nstart,
    unsigned int* __restrict__ ncur) {
  __shared__ unsigned int hist[512];
  __shared__ unsigned int sc[512];
  int b = blockIdx.x, t = threadIdx.x;
  hist[t] = 0u;
  __syncthreads();
  int lo = (int)gstart[b], hi = (int)gstart[b + 1];
  for (int e = lo + t; e < hi; e += 512)
    atomicAdd(&hist[staging[e] >> 17], 1u);
  __syncthreads();
  unsigned int my = hist[t];
  sc[t] = my;
  __syncthreads();
  for (int off = 1; off < 512; off <<= 1) {
    unsigned int v = (t >= off) ? sc[t - off] : 0u;
    __syncthreads();
    sc[t] += v;
    __syncthreads();
  }
  int node = b * 512 + t;
  if (node < NN) {
    unsigned int st = (unsigned int)lo + sc[t] - my;
    nstart[node] = st;
    ncur[node] = st;
    if (node == NN - 1) nstart[NN] = st + my;  // == NE
  }
}

// ---------------------------------------------------------------------------
// Sort 5: within-bucket scatter to exact node order (4 blocks per bucket).
__global__ __launch_bounds__(256) void k_bscatter(
    const unsigned int* __restrict__ staging,
    const unsigned int* __restrict__ nstart, unsigned int* __restrict__ ncur,
    unsigned int* __restrict__ sorted_src) {
  int b = blockIdx.x >> 2, part = blockIdx.x & 3;
  int lo = (int)nstart[b * 512];
  int nend = (b + 1) * 512;
  if (nend > NN) nend = NN;
  int hi = (int)nstart[nend];
  for (int e = lo + part * 256 + threadIdx.x; e < hi; e += 1024) {
    unsigned int u = staging[e];
    unsigned int s = u & 0x1FFFFu;
    int node = (b << 9) + (int)(u >> 17);
    unsigned int pos = atomicAdd(&ncur[node], 1u);
    sorted_src[pos] = s;
  }
}

// ---------------------------------------------------------------------------
// Aggregation over sorted edges (bf16 gather): one wave per node.
__global__ __launch_bounds__(256) void k_aggr_sorted(
    const unsigned int* __restrict__ sorted_src,
    const unsigned int* __restrict__ nstart,
    const unsigned short* __restrict__ h16, float* __restrict__ aggr) {
  int lane = threadIdx.x & 63;
  int n = (int)((blockIdx.x * 256 + threadIdx.x) >> 6);
  if (n >= NN) return;
  int e0 = (int)nstart[n];
  int e1 = (int)nstart[n + 1];
  float a0 = 0.f, a1 = 0.f, a2 = 0.f, a3 = 0.f;
  float a4 = 0.f, a5 = 0.f, a6 = 0.f, a7 = 0.f;
  int e = e0;
  for (; e + 8 <= e1; e += 8) {
    unsigned int s0 = sorted_src[e], s1 = sorted_src[e + 1];
    unsigned int s2 = sorted_src[e + 2], s3 = sorted_src[e + 3];
    unsigned int s4 = sorted_src[e + 4], s5 = sorted_src[e + 5];
    unsigned int s6 = sorted_src[e + 6], s7 = sorted_src[e + 7];
    a0 += bf2f(h16[(size_t)s0 * HD + lane]);
    a1 += bf2f(h16[(size_t)s1 * HD + lane]);
    a2 += bf2f(h16[(size_t)s2 * HD + lane]);
    a3 += bf2f(h16[(size_t)s3 * HD + lane]);
    a4 += bf2f(h16[(size_t)s4 * HD + lane]);
    a5 += bf2f(h16[(size_t)s5 * HD + lane]);
    a6 += bf2f(h16[(size_t)s6 * HD + lane]);
    a7 += bf2f(h16[(size_t)s7 * HD + lane]);
  }
  for (; e < e1; ++e) a0 += bf2f(h16[(size_t)sorted_src[e] * HD + lane]);
  float acc = ((a0 + a1) + (a2 + a3)) + ((a4 + a5) + (a6 + a7));
  float cntf = (float)(e1 - e0);
  float inv = (cntf > 0.f) ? 1.0f / cntf : 0.f;
  aggr[(size_t)n * HD + lane] = acc * inv;
}

// ---------------------------------------------------------------------------
// SAGE combine + fused BN-stats. Persistent blocks, LDS-staged row tiles.
__global__ __launch_bounds__(512) void k_combine(
    const float* __restrict__ aggr, const unsigned short* __restrict__ h16,
    const float* __restrict__ Wl, const float* __restrict__ bl,
    const float* __restrict__ Wr, float* __restrict__ pre,
    float* __restrict__ stats) {
  __shared__ float sWl[HD * HD], sWr[HD * HD];      // 32 KB
  __shared__ float sA[CB_TILE * HD], sH[CB_TILE * HD];  // 32 KB
  __shared__ float ss[512], sq[512];                // 4 KB
  int tid = threadIdx.x;
  for (int i = tid; i < HD * HD; i += 512) {
    sWl[i] = Wl[i];
    sWr[i] = Wr[i];
  }
  int w = tid >> 6, c = tid & 63;
  int rb = w * 8;
  float bc = bl[c];
  float S = 0.f, Q = 0.f;
  const int NT = (NN + CB_TILE - 1) / CB_TILE;  // 1563
  for (int t = blockIdx.x; t < NT; t += gridDim.x) {
    int row0 = t * CB_TILE;
    __syncthreads();  // prior compute reads done
    {
      int row = row0 + (tid >> 3);
      int rowc = row < NN ? row : NN - 1;
      int col0 = (tid & 7) * 8;
      const float* srcA = &aggr[(size_t)rowc * HD + col0];
      float4 a0 = *(const float4*)srcA;
      float4 a1 = *(const float4*)(srcA + 4);
      uint4 hu = *(const uint4*)&h16[(size_t)rowc * HD + col0];
      float* dA = &sA[(tid >> 3) * HD + col0];
      *(float4*)dA = a0;
      *(float4*)(dA + 4) = a1;
      float* dH = &sH[(tid >> 3) * HD + col0];
      dH[0] = bf2f((unsigned short)(hu.x & 0xFFFFu));
      dH[1] = bf2f((unsigned short)(hu.x >> 16));
      dH[2] = bf2f((unsigned short)(hu.y & 0xFFFFu));
      dH[3] = bf2f((unsigned short)(hu.y >> 16));
      dH[4] = bf2f((unsigned short)(hu.z & 0xFFFFu));
      dH[5] = bf2f((unsigned short)(hu.z >> 16));
      dH[6] = bf2f((unsigned short)(hu.w & 0xFFFFu));
      dH[7] = bf2f((unsigned short)(hu.w >> 16));
    }
    __syncthreads();
    float acc[8];
#pragma unroll
    for (int r = 0; r < 8; ++r) acc[r] = bc;
    for (int kg = 0; kg < HD; kg += 4) {
      float4 a4[8], h4[8];
#pragma unroll
      for (int r = 0; r < 8; ++r) {
        a4[r] = *(const float4*)&sA[(rb + r) * HD + kg];
        h4[r] = *(const float4*)&sH[(rb + r) * HD + kg];
      }
#pragma unroll
      for (int j = 0; j < 4; ++j) {
        float wl = sWl[(kg + j) * HD + c];
        float wr = sWr[(kg + j) * HD + c];
#pragma unroll
        for (int r = 0; r < 8; ++r) {
          acc[r] = fmaf(((const float*)&a4[r])[j], wl, acc[r]);
          acc[r] = fmaf(((const float*)&h4[r])[j], wr, acc[r]);
        }
      }
    }
#pragma unroll
    for (int r = 0; r < 8; ++r) {
      int row = row0 + rb + r;
      if (row < NN) {
        pre[(size_t)row * HD + c] = acc[r];
        S += acc[r];
        Q = fmaf(acc[r], acc[r], Q);
      }
    }
  }
  ss[tid] = S;
  sq[tid] = Q;
  __syncthreads();
  if (tid < 64) {
    float Ts = 0.f, Tq = 0.f;
#pragma unroll
    for (int j = 0; j < 8; ++j) {
      Ts += ss[j * 64 + tid];
      Tq += sq[j * 64 + tid];
    }
    atomicAdd(&stats[tid], Ts);
    atomicAdd(&stats[64 + tid], Tq);
  }
}

// ---------------------------------------------------------------------------
// Final fused: BN + ReLU + residual(bf16) + output head.
__global__ __launch_bounds__(256) void k_bn_relu_head(
    const float* __restrict__ pre, const float* __restrict__ stats,
    const float* __restrict__ g, const float* __restrict__ b,
    const unsigned short* __restrict__ resid16, const float* __restrict__ Wo,
    const float* __restrict__ bo, float* __restrict__ out) {
  int lane = threadIdx.x & 63;
  int wid = (int)((blockIdx.x * blockDim.x + threadIdx.x) >> 6);
  int nw = (int)((gridDim.x * blockDim.x) >> 6);
  const float invN = 1.0f / NN;
  float m = stats[lane] * invN;
  float v = stats[64 + lane] * invN - m * m;
  float sc = g[lane] * rsqrtf(v + BN_EPS);
  float bb = b[lane];
  float w0 = Wo[lane * 2], w1 = Wo[lane * 2 + 1];
  float b0 = bo[0], b1 = bo[1];
  for (int row = wid; row < NN; row += nw) {
    size_t i = (size_t)row * HD + lane;
    float val = (pre[i] - m) * sc + bb;
    val = fmaxf(val, 0.f) + bf2f(resid16[i]);
    float a0 = val * w0, a1 = val * w1;
#pragma unroll
    for (int off = 32; off > 0; off >>= 1) {
      a0 += __shfl_down(a0, off);
      a1 += __shfl_down(a1, off);
    }
    if (lane == 0) {
      out[(size_t)row * 2] = a0 + b0;
      out[(size_t)row * 2 + 1] = a1 + b1;
    }
  }
}

// ---------------------------------------------------------------------------
extern "C" void kernel_launch(void* const* d_in, const int* in_sizes, int n_in,
                              void* d_out, int out_size, void* d_ws,
                              size_t ws_size, hipStream_t stream) {
  const float* x = (const float*)d_in[0];
  const int* ei = (const int*)d_in[1];
  const float* Wp = (const float*)d_in[2];
  const float* bp = (const float*)d_in[3];
  const float* g_in = (const float*)d_in[4];
  const float* b_in = (const float*)d_in[5];
  const float* Wl0 = (const float*)d_in[6];
  const float* bl0 = (const float*)d_in[7];
  const float* Wr0 = (const float*)d_in[8];
  const float* g0 = (const float*)d_in[9];
  const float* b0 = (const float*)d_in[10];
  const float* Wl1 = (const float*)d_in[11];
  const float* bl1 = (const float*)d_in[12];
  const float* Wr1 = (const float*)d_in[13];
  const float* g1 = (const float*)d_in[14];
  const float* b1 = (const float*)d_in[15];
  const float* Wo = (const float*)d_in[16];
  const float* bo = (const float*)d_in[17];
  float* out = (float*)d_out;

  const int* src = ei;
  const int* dst = ei + NE;

  float* ws = (float*)d_ws;
  float* pre = ws;  // [NN*HD] f32 (also aggr buffer)
  __hip_bfloat16* h0b = (__hip_bfloat16*)(ws + (size_t)NN * HD);  // [NN*HD]
  __hip_bfloat16* h1b = h0b + (size_t)NN * HD;                    // [NN*HD]
  unsigned int* staging = (unsigned int*)(h1b + (size_t)NN * HD); // [NE]
  unsigned int* sorted_src = staging + NE;   // [NE]
  unsigned int* nstart = sorted_src + NE;    // [NN+1]
  unsigned int* ncur = nstart + NN + 1;      // [NN]
  unsigned int* bcnt = ncur + NN;            // [NBUK]
  unsigned int* gstart = bcnt + NBUK;        // [NBUK+1]
  unsigned int* gcur = gstart + NBUK + 1;    // [NBUK]
  float* stats0 = (float*)(gcur + NBUK);     // [128]
  float* stats1 = stats0 + 128;              // [128]
  float* stats2 = stats1 + 128;              // [128]

  const int ELEM_BLOCKS = (NN * HD) / 256;  // 25000
  const int AGGR_BLOCKS = 25000;            // 100k waves, 4/block
  const int MS_BLOCKS = (NE + 256 * MSB - 1) / (256 * MSB);  // 782

  hipMemsetAsync(stats0, 0, 3 * 128 * sizeof(float), stream);
  hipMemsetAsync(bcnt, 0, NBUK * sizeof(unsigned int), stream);

  // ---- input projection (+stats) + BN/ReLU -> h0 (bf16)
  k_gemm_in<<<768, 256, 0, stream>>>(x, Wp, bp, pre, stats0);
  k_bn_relu<<<ELEM_BLOCKS, 256, 0, stream>>>(pre, stats0, g_in, b_in, h0b);

  // ---- counting-sort edges by dst, bucket-first (no per-node global atomics)
  k_bhist<<<1024, 256, 0, stream>>>(dst, bcnt);
  k_bscan<<<1, 256, 0, stream>>>(bcnt, gstart, gcur);
  k_msplit<<<MS_BLOCKS, 256, 0, stream>>>(src, dst, gcur, staging);
  k_nscan<<<NBUK, 512, 0, stream>>>(staging, gstart, nstart, ncur);
  k_bscatter<<<NBUK * 4, 256, 0, stream>>>(staging, nstart, ncur, sorted_src);

  // ---- layer 0
  k_aggr_sorted<<<AGGR_BLOCKS, 256, 0, stream>>>(
      sorted_src, nstart, (const unsigned short*)h0b, pre);
  k_combine<<<512, 512, 0, stream>>>(pre, (const unsigned short*)h0b, Wl0,
                                     bl0, Wr0, pre, stats1);
  k_bn_relu<<<ELEM_BLOCKS, 256, 0, stream>>>(pre, stats1, g0, b0, h1b);

  // ---- layer 1 + fused BN/ReLU/residual/head
  k_aggr_sorted<<<AGGR_BLOCKS, 256, 0, stream>>>(
      sorted_src, nstart, (const unsigned short*)h1b, pre);
  k_combine<<<512, 512, 0, stream>>>(pre, (const unsigned short*)h1b, Wl1,
                                     bl1, Wr1, pre, stats2);
  k_bn_relu_head<<<1024, 256, 0, stream>>>(pre, stats2, g1, b1,
                                           (const unsigned short*)h0b, Wo, bo,
                                           out);
}

// Round 9
// 490.309 us; speedup vs baseline: 2.5614x; 1.1562x over previous
//
#include <hip/hip_runtime.h>
#include <hip/hip_bf16.h>

#define NN 100000
#define NE 3200000
#define IC 128
#define HD 64
#define BN_EPS 1e-5f
#define NBUK 196      // ceil(NN / 512) buckets of 512 nodes (dst >> 9)
#define MSB 16        // edges per thread in multisplit (batch = 4096/block)
#define GI_TILE 32    // rows per tile, input gemm
#define CB_TILE 64    // rows per tile, combine

__device__ __forceinline__ float bf2f(unsigned short u) {
  return __uint_as_float(((unsigned)u) << 16);
}

// ---------------------------------------------------------------------------
// Input projection + fused BN-stats. Persistent blocks, LDS-staged rows.
__global__ __launch_bounds__(256) void k_gemm_in(
    const float* __restrict__ x, const float* __restrict__ Wp,
    const float* __restrict__ bp, float* __restrict__ pre,
    float* __restrict__ stats) {
  __shared__ float sW[IC * HD];        // 32 KB
  __shared__ float sX[GI_TILE * IC];   // 16 KB
  __shared__ float ss[256], sq[256];   // 2 KB
  int tid = threadIdx.x;
  for (int i = tid; i < IC * HD; i += 256) sW[i] = Wp[i];
  int w = tid >> 6, c = tid & 63;
  int rb = w * 8;
  float bc = bp[c];
  float S = 0.f, Q = 0.f;
  const int NT = NN / GI_TILE;  // 3125
  for (int t = blockIdx.x; t < NT; t += gridDim.x) {
    int row0 = t * GI_TILE;
    __syncthreads();  // prior compute reads of sX done
    for (int i = tid; i < GI_TILE * IC / 4; i += 256)
      *(float4*)&sX[i * 4] = *(const float4*)&x[(size_t)row0 * IC + i * 4];
    __syncthreads();
    float acc[8];
#pragma unroll
    for (int r = 0; r < 8; ++r) acc[r] = bc;
    for (int kg = 0; kg < IC; kg += 4) {
      float4 xr[8];
#pragma unroll
      for (int r = 0; r < 8; ++r)
        xr[r] = *(const float4*)&sX[(rb + r) * IC + kg];
#pragma unroll
      for (int j = 0; j < 4; ++j) {
        float wv = sW[(kg + j) * HD + c];
#pragma unroll
        for (int r = 0; r < 8; ++r)
          acc[r] = fmaf(((const float*)&xr[r])[j], wv, acc[r]);
      }
    }
#pragma unroll
    for (int r = 0; r < 8; ++r) {
      pre[(size_t)(row0 + rb + r) * HD + c] = acc[r];
      S += acc[r];
      Q = fmaf(acc[r], acc[r], Q);
    }
  }
  ss[tid] = S;
  sq[tid] = Q;
  __syncthreads();
  if (tid < 64) {
    float Ts = ss[tid] + ss[64 + tid] + ss[128 + tid] + ss[192 + tid];
    float Tq = sq[tid] + sq[64 + tid] + sq[128 + tid] + sq[192 + tid];
    atomicAdd(&stats[tid], Ts);
    atomicAdd(&stats[64 + tid], Tq);
  }
}

// ---------------------------------------------------------------------------
// BN normalize + ReLU -> bf16 hidden state.
__global__ __launch_bounds__(256) void k_bn_relu(
    const float* __restrict__ pre, const float* __restrict__ stats,
    const float* __restrict__ g, const float* __restrict__ b,
    __hip_bfloat16* __restrict__ out16) {
  size_t i = (size_t)blockIdx.x * 256 + threadIdx.x;
  int c = threadIdx.x & 63;
  const float invN = 1.0f / NN;
  float m = stats[c] * invN;
  float v = stats[64 + c] * invN - m * m;
  float sc = g[c] * rsqrtf(v + BN_EPS);
  float val = (pre[i] - m) * sc + b[c];
  out16[i] = __float2bfloat16(fmaxf(val, 0.f));
}

// ---------------------------------------------------------------------------
// Sort 1: bucket histogram via LDS (196 bins), block-reduced to global.
__global__ __launch_bounds__(256) void k_bhist(
    const int* __restrict__ dst, unsigned int* __restrict__ bcnt) {
  __shared__ unsigned int h[NBUK];
  for (int i = threadIdx.x; i < NBUK; i += 256) h[i] = 0u;
  __syncthreads();
  int i0 = blockIdx.x * 256 + threadIdx.x;
  int stride = gridDim.x * 256;
  for (int e = i0; e < NE; e += stride)
    atomicAdd(&h[((unsigned)dst[e]) >> 9], 1u);
  __syncthreads();
  for (int i = threadIdx.x; i < NBUK; i += 256)
    if (h[i]) atomicAdd(&bcnt[i], h[i]);
}

// ---------------------------------------------------------------------------
// Sort 2: exclusive scan of 196 bucket counts (one block).
__global__ __launch_bounds__(256) void k_bscan(
    const unsigned int* __restrict__ bcnt, unsigned int* __restrict__ gstart,
    unsigned int* __restrict__ gcur) {
  __shared__ unsigned int s[256];
  int t = threadIdx.x;
  unsigned int my = (t < NBUK) ? bcnt[t] : 0u;
  s[t] = my;
  __syncthreads();
  for (int off = 1; off < 256; off <<= 1) {
    unsigned int v = (t >= off) ? s[t - off] : 0u;
    __syncthreads();
    s[t] += v;
    __syncthreads();
  }
  if (t < NBUK) {
    gstart[t] = s[t] - my;
    gcur[t] = s[t] - my;
  }
  if (t == NBUK - 1) gstart[NBUK] = s[t];
}

// ---------------------------------------------------------------------------
// Sort 3: multisplit into 512-node buckets. Packed word = src | (dloc<<17).
__global__ __launch_bounds__(256) void k_msplit(
    const int* __restrict__ src, const int* __restrict__ dst,
    unsigned int* __restrict__ gcur, unsigned int* __restrict__ staging) {
  __shared__ unsigned int hist[NBUK];
  __shared__ unsigned int gbase[NBUK];
  int tid = threadIdx.x;
  for (int i = tid; i < NBUK; i += 256) hist[i] = 0u;
  __syncthreads();
  int e0 = blockIdx.x * (256 * MSB);
  unsigned int pk[MSB], rk[MSB], bk[MSB];
#pragma unroll
  for (int i = 0; i < MSB; ++i) {
    int e = e0 + i * 256 + tid;
    if (e < NE) {
      int d = dst[e];
      unsigned int b = (unsigned int)(d >> 9);
      rk[i] = atomicAdd(&hist[b], 1u);
      pk[i] = (unsigned int)src[e] | ((unsigned int)(d & 511) << 17);
      bk[i] = b;
    } else {
      bk[i] = 0xFFFFFFFFu;
    }
  }
  __syncthreads();
  for (int i = tid; i < NBUK; i += 256)
    if (hist[i]) gbase[i] = atomicAdd(&gcur[i], hist[i]);
  __syncthreads();
#pragma unroll
  for (int i = 0; i < MSB; ++i)
    if (bk[i] != 0xFFFFFFFFu) staging[gbase[bk[i]] + rk[i]] = pk[i];
}

// ---------------------------------------------------------------------------
// Sort 4 (fused): per-bucket node histogram + scan + scatter, ONE block per
// bucket. All writes to the bucket's sorted_src window come from one CU ->
// lines fill in a single XCD L2 and write back once. LDS cursors, no global
// atomics. Also writes nstart.
__global__ __launch_bounds__(512) void k_bucket_sort(
    const unsigned int* __restrict__ staging,
    const unsigned int* __restrict__ gstart, unsigned int* __restrict__ nstart,
    unsigned int* __restrict__ sorted_src) {
  __shared__ unsigned int hist[512];
  __shared__ unsigned int sc[512];
  __shared__ unsigned int cur[512];
  int b = blockIdx.x, t = threadIdx.x;
  hist[t] = 0u;
  __syncthreads();
  int lo = (int)gstart[b], hi = (int)gstart[b + 1];
  for (int e = lo + t; e < hi; e += 512)
    atomicAdd(&hist[staging[e] >> 17], 1u);
  __syncthreads();
  unsigned int my = hist[t];
  sc[t] = my;
  __syncthreads();
  for (int off = 1; off < 512; off <<= 1) {
    unsigned int v = (t >= off) ? sc[t - off] : 0u;
    __syncthreads();
    sc[t] += v;
    __syncthreads();
  }
  unsigned int st = (unsigned int)lo + sc[t] - my;  // exclusive start
  cur[t] = st;
  int node = b * 512 + t;
  if (node < NN) {
    nstart[node] = st;
    if (node == NN - 1) nstart[NN] = st + my;  // == NE
  }
  __syncthreads();
  for (int e = lo + t; e < hi; e += 512) {
    unsigned int u = staging[e];  // L2-hot (just read in pass 1)
    unsigned int pos = atomicAdd(&cur[u >> 17], 1u);
    sorted_src[pos] = u & 0x1FFFFu;
  }
}

// ---------------------------------------------------------------------------
// Aggregation over sorted edges (bf16 gather): one wave per node.
__global__ __launch_bounds__(256) void k_aggr_sorted(
    const unsigned int* __restrict__ sorted_src,
    const unsigned int* __restrict__ nstart,
    const unsigned short* __restrict__ h16, float* __restrict__ aggr) {
  int lane = threadIdx.x & 63;
  int n = (int)((blockIdx.x * 256 + threadIdx.x) >> 6);
  if (n >= NN) return;
  int e0 = (int)nstart[n];
  int e1 = (int)nstart[n + 1];
  float a0 = 0.f, a1 = 0.f, a2 = 0.f, a3 = 0.f;
  float a4 = 0.f, a5 = 0.f, a6 = 0.f, a7 = 0.f;
  int e = e0;
  for (; e + 8 <= e1; e += 8) {
    unsigned int s0 = sorted_src[e], s1 = sorted_src[e + 1];
    unsigned int s2 = sorted_src[e + 2], s3 = sorted_src[e + 3];
    unsigned int s4 = sorted_src[e + 4], s5 = sorted_src[e + 5];
    unsigned int s6 = sorted_src[e + 6], s7 = sorted_src[e + 7];
    a0 += bf2f(h16[(size_t)s0 * HD + lane]);
    a1 += bf2f(h16[(size_t)s1 * HD + lane]);
    a2 += bf2f(h16[(size_t)s2 * HD + lane]);
    a3 += bf2f(h16[(size_t)s3 * HD + lane]);
    a4 += bf2f(h16[(size_t)s4 * HD + lane]);
    a5 += bf2f(h16[(size_t)s5 * HD + lane]);
    a6 += bf2f(h16[(size_t)s6 * HD + lane]);
    a7 += bf2f(h16[(size_t)s7 * HD + lane]);
  }
  for (; e < e1; ++e) a0 += bf2f(h16[(size_t)sorted_src[e] * HD + lane]);
  float acc = ((a0 + a1) + (a2 + a3)) + ((a4 + a5) + (a6 + a7));
  float cntf = (float)(e1 - e0);
  float inv = (cntf > 0.f) ? 1.0f / cntf : 0.f;
  aggr[(size_t)n * HD + lane] = acc * inv;
}

// ---------------------------------------------------------------------------
// SAGE combine + fused BN-stats. Persistent blocks, LDS-staged row tiles.
__global__ __launch_bounds__(512) void k_combine(
    const float* __restrict__ aggr, const unsigned short* __restrict__ h16,
    const float* __restrict__ Wl, const float* __restrict__ bl,
    const float* __restrict__ Wr, float* __restrict__ pre,
    float* __restrict__ stats) {
  __shared__ float sWl[HD * HD], sWr[HD * HD];      // 32 KB
  __shared__ float sA[CB_TILE * HD], sH[CB_TILE * HD];  // 32 KB
  __shared__ float ss[512], sq[512];                // 4 KB
  int tid = threadIdx.x;
  for (int i = tid; i < HD * HD; i += 512) {
    sWl[i] = Wl[i];
    sWr[i] = Wr[i];
  }
  int w = tid >> 6, c = tid & 63;
  int rb = w * 8;
  float bc = bl[c];
  float S = 0.f, Q = 0.f;
  const int NT = (NN + CB_TILE - 1) / CB_TILE;  // 1563
  for (int t = blockIdx.x; t < NT; t += gridDim.x) {
    int row0 = t * CB_TILE;
    __syncthreads();  // prior compute reads done
    {
      int row = row0 + (tid >> 3);
      int rowc = row < NN ? row : NN - 1;
      int col0 = (tid & 7) * 8;
      const float* srcA = &aggr[(size_t)rowc * HD + col0];
      float4 a0 = *(const float4*)srcA;
      float4 a1 = *(const float4*)(srcA + 4);
      uint4 hu = *(const uint4*)&h16[(size_t)rowc * HD + col0];
      float* dA = &sA[(tid >> 3) * HD + col0];
      *(float4*)dA = a0;
      *(float4*)(dA + 4) = a1;
      float* dH = &sH[(tid >> 3) * HD + col0];
      dH[0] = bf2f((unsigned short)(hu.x & 0xFFFFu));
      dH[1] = bf2f((unsigned short)(hu.x >> 16));
      dH[2] = bf2f((unsigned short)(hu.y & 0xFFFFu));
      dH[3] = bf2f((unsigned short)(hu.y >> 16));
      dH[4] = bf2f((unsigned short)(hu.z & 0xFFFFu));
      dH[5] = bf2f((unsigned short)(hu.z >> 16));
      dH[6] = bf2f((unsigned short)(hu.w & 0xFFFFu));
      dH[7] = bf2f((unsigned short)(hu.w >> 16));
    }
    __syncthreads();
    float acc[8];
#pragma unroll
    for (int r = 0; r < 8; ++r) acc[r] = bc;
    for (int kg = 0; kg < HD; kg += 4) {
      float4 a4[8], h4[8];
#pragma unroll
      for (int r = 0; r < 8; ++r) {
        a4[r] = *(const float4*)&sA[(rb + r) * HD + kg];
        h4[r] = *(const float4*)&sH[(rb + r) * HD + kg];
      }
#pragma unroll
      for (int j = 0; j < 4; ++j) {
        float wl = sWl[(kg + j) * HD + c];
        float wr = sWr[(kg + j) * HD + c];
#pragma unroll
        for (int r = 0; r < 8; ++r) {
          acc[r] = fmaf(((const float*)&a4[r])[j], wl, acc[r]);
          acc[r] = fmaf(((const float*)&h4[r])[j], wr, acc[r]);
        }
      }
    }
#pragma unroll
    for (int r = 0; r < 8; ++r) {
      int row = row0 + rb + r;
      if (row < NN) {
        pre[(size_t)row * HD + c] = acc[r];
        S += acc[r];
        Q = fmaf(acc[r], acc[r], Q);
      }
    }
  }
  ss[tid] = S;
  sq[tid] = Q;
  __syncthreads();
  if (tid < 64) {
    float Ts = 0.f, Tq = 0.f;
#pragma unroll
    for (int j = 0; j < 8; ++j) {
      Ts += ss[j * 64 + tid];
      Tq += sq[j * 64 + tid];
    }
    atomicAdd(&stats[tid], Ts);
    atomicAdd(&stats[64 + tid], Tq);
  }
}

// ---------------------------------------------------------------------------
// Final fused: BN + ReLU + residual(bf16) + output head.
__global__ __launch_bounds__(256) void k_bn_relu_head(
    const float* __restrict__ pre, const float* __restrict__ stats,
    const float* __restrict__ g, const float* __restrict__ b,
    const unsigned short* __restrict__ resid16, const float* __restrict__ Wo,
    const float* __restrict__ bo, float* __restrict__ out) {
  int lane = threadIdx.x & 63;
  int wid = (int)((blockIdx.x * blockDim.x + threadIdx.x) >> 6);
  int nw = (int)((gridDim.x * blockDim.x) >> 6);
  const float invN = 1.0f / NN;
  float m = stats[lane] * invN;
  float v = stats[64 + lane] * invN - m * m;
  float sc = g[lane] * rsqrtf(v + BN_EPS);
  float bb = b[lane];
  float w0 = Wo[lane * 2], w1 = Wo[lane * 2 + 1];
  float b0 = bo[0], b1 = bo[1];
  for (int row = wid; row < NN; row += nw) {
    size_t i = (size_t)row * HD + lane;
    float val = (pre[i] - m) * sc + bb;
    val = fmaxf(val, 0.f) + bf2f(resid16[i]);
    float a0 = val * w0, a1 = val * w1;
#pragma unroll
    for (int off = 32; off > 0; off >>= 1) {
      a0 += __shfl_down(a0, off);
      a1 += __shfl_down(a1, off);
    }
    if (lane == 0) {
      out[(size_t)row * 2] = a0 + b0;
      out[(size_t)row * 2 + 1] = a1 + b1;
    }
  }
}

// ---------------------------------------------------------------------------
extern "C" void kernel_launch(void* const* d_in, const int* in_sizes, int n_in,
                              void* d_out, int out_size, void* d_ws,
                              size_t ws_size, hipStream_t stream) {
  const float* x = (const float*)d_in[0];
  const int* ei = (const int*)d_in[1];
  const float* Wp = (const float*)d_in[2];
  const float* bp = (const float*)d_in[3];
  const float* g_in = (const float*)d_in[4];
  const float* b_in = (const float*)d_in[5];
  const float* Wl0 = (const float*)d_in[6];
  const float* bl0 = (const float*)d_in[7];
  const float* Wr0 = (const float*)d_in[8];
  const float* g0 = (const float*)d_in[9];
  const float* b0 = (const float*)d_in[10];
  const float* Wl1 = (const float*)d_in[11];
  const float* bl1 = (const float*)d_in[12];
  const float* Wr1 = (const float*)d_in[13];
  const float* g1 = (const float*)d_in[14];
  const float* b1 = (const float*)d_in[15];
  const float* Wo = (const float*)d_in[16];
  const float* bo = (const float*)d_in[17];
  float* out = (float*)d_out;

  const int* src = ei;
  const int* dst = ei + NE;

  float* ws = (float*)d_ws;
  float* pre = ws;  // [NN*HD] f32 (also aggr buffer)
  __hip_bfloat16* h0b = (__hip_bfloat16*)(ws + (size_t)NN * HD);  // [NN*HD]
  __hip_bfloat16* h1b = h0b + (size_t)NN * HD;                    // [NN*HD]
  unsigned int* staging = (unsigned int*)(h1b + (size_t)NN * HD); // [NE]
  unsigned int* sorted_src = staging + NE;   // [NE]
  unsigned int* nstart = sorted_src + NE;    // [NN+1]
  unsigned int* bcnt = nstart + NN + 1;      // [NBUK]
  unsigned int* gstart = bcnt + NBUK;        // [NBUK+1]
  unsigned int* gcur = gstart + NBUK + 1;    // [NBUK]
  float* stats0 = (float*)(gcur + NBUK);     // [128]
  float* stats1 = stats0 + 128;              // [128]
  float* stats2 = stats1 + 128;              // [128]

  const int ELEM_BLOCKS = (NN * HD) / 256;  // 25000
  const int AGGR_BLOCKS = 25000;            // 100k waves, 4/block
  const int MS_BLOCKS = (NE + 256 * MSB - 1) / (256 * MSB);  // 782

  hipMemsetAsync(stats0, 0, 3 * 128 * sizeof(float), stream);
  hipMemsetAsync(bcnt, 0, NBUK * sizeof(unsigned int), stream);

  // ---- input projection (+stats) + BN/ReLU -> h0 (bf16)
  k_gemm_in<<<768, 256, 0, stream>>>(x, Wp, bp, pre, stats0);
  k_bn_relu<<<ELEM_BLOCKS, 256, 0, stream>>>(pre, stats0, g_in, b_in, h0b);

  // ---- counting-sort edges by dst, bucket-first; scatter is bucket-local
  k_bhist<<<1024, 256, 0, stream>>>(dst, bcnt);
  k_bscan<<<1, 256, 0, stream>>>(bcnt, gstart, gcur);
  k_msplit<<<MS_BLOCKS, 256, 0, stream>>>(src, dst, gcur, staging);
  k_bucket_sort<<<NBUK, 512, 0, stream>>>(staging, gstart, nstart, sorted_src);

  // ---- layer 0
  k_aggr_sorted<<<AGGR_BLOCKS, 256, 0, stream>>>(
      sorted_src, nstart, (const unsigned short*)h0b, pre);
  k_combine<<<512, 512, 0, stream>>>(pre, (const unsigned short*)h0b, Wl0,
                                     bl0, Wr0, pre, stats1);
  k_bn_relu<<<ELEM_BLOCKS, 256, 0, stream>>>(pre, stats1, g0, b0, h1b);

  // ---- layer 1 + fused BN/ReLU/residual/head
  k_aggr_sorted<<<AGGR_BLOCKS, 256, 0, stream>>>(
      sorted_src, nstart, (const unsigned short*)h1b, pre);
  k_combine<<<512, 512, 0, stream>>>(pre, (const unsigned short*)h1b, Wl1,
                                     bl1, Wr1, pre, stats2);
  k_bn_relu_head<<<1024, 256, 0, stream>>>(pre, stats2, g1, b1,
                                           (const unsigned short*)h0b, Wo, bo,
                                           out);
}

// Round 10
// 451.351 us; speedup vs baseline: 2.7825x; 1.0863x over previous
//
#include <hip/hip_runtime.h>
#include <hip/hip_bf16.h>

#define NN 100000
#define NE 3200000
#define IC 128
#define HD 64
#define BN_EPS 1e-5f
#define NBUK 196      // ceil(NN / 512) buckets of 512 nodes (dst >> 9)
#define MSB 16        // edges per thread in multisplit (batch = 4096/block)
#define GI_TILE 32    // rows per tile, input gemm
#define CB_TILE 64    // rows per tile, combine

__device__ __forceinline__ float bf2f(unsigned short u) {
  return __uint_as_float(((unsigned)u) << 16);
}

// ---------------------------------------------------------------------------
// Input projection + fused BN-stats. Persistent blocks, LDS-staged rows.
__global__ __launch_bounds__(256) void k_gemm_in(
    const float* __restrict__ x, const float* __restrict__ Wp,
    const float* __restrict__ bp, float* __restrict__ pre,
    float* __restrict__ stats) {
  __shared__ float sW[IC * HD];        // 32 KB
  __shared__ float sX[GI_TILE * IC];   // 16 KB
  __shared__ float ss[256], sq[256];   // 2 KB
  int tid = threadIdx.x;
  for (int i = tid; i < IC * HD; i += 256) sW[i] = Wp[i];
  int w = tid >> 6, c = tid & 63;
  int rb = w * 8;
  float bc = bp[c];
  float S = 0.f, Q = 0.f;
  const int NT = NN / GI_TILE;  // 3125
  for (int t = blockIdx.x; t < NT; t += gridDim.x) {
    int row0 = t * GI_TILE;
    __syncthreads();  // prior compute reads of sX done
    for (int i = tid; i < GI_TILE * IC / 4; i += 256)
      *(float4*)&sX[i * 4] = *(const float4*)&x[(size_t)row0 * IC + i * 4];
    __syncthreads();
    float acc[8];
#pragma unroll
    for (int r = 0; r < 8; ++r) acc[r] = bc;
    for (int kg = 0; kg < IC; kg += 4) {
      float4 xr[8];
#pragma unroll
      for (int r = 0; r < 8; ++r)
        xr[r] = *(const float4*)&sX[(rb + r) * IC + kg];
#pragma unroll
      for (int j = 0; j < 4; ++j) {
        float wv = sW[(kg + j) * HD + c];
#pragma unroll
        for (int r = 0; r < 8; ++r)
          acc[r] = fmaf(((const float*)&xr[r])[j], wv, acc[r]);
      }
    }
#pragma unroll
    for (int r = 0; r < 8; ++r) {
      pre[(size_t)(row0 + rb + r) * HD + c] = acc[r];
      S += acc[r];
      Q = fmaf(acc[r], acc[r], Q);
    }
  }
  ss[tid] = S;
  sq[tid] = Q;
  __syncthreads();
  if (tid < 64) {
    float Ts = ss[tid] + ss[64 + tid] + ss[128 + tid] + ss[192 + tid];
    float Tq = sq[tid] + sq[64 + tid] + sq[128 + tid] + sq[192 + tid];
    atomicAdd(&stats[tid], Ts);
    atomicAdd(&stats[64 + tid], Tq);
  }
}

// ---------------------------------------------------------------------------
// BN normalize + ReLU -> bf16 hidden state.
__global__ __launch_bounds__(256) void k_bn_relu(
    const float* __restrict__ pre, const float* __restrict__ stats,
    const float* __restrict__ g, const float* __restrict__ b,
    __hip_bfloat16* __restrict__ out16) {
  size_t i = (size_t)blockIdx.x * 256 + threadIdx.x;
  int c = threadIdx.x & 63;
  const float invN = 1.0f / NN;
  float m = stats[c] * invN;
  float v = stats[64 + c] * invN - m * m;
  float sc = g[c] * rsqrtf(v + BN_EPS);
  float val = (pre[i] - m) * sc + b[c];
  out16[i] = __float2bfloat16(fmaxf(val, 0.f));
}

// ---------------------------------------------------------------------------
// Sort 1: bucket histogram via LDS (196 bins), block-reduced to global.
__global__ __launch_bounds__(256) void k_bhist(
    const int* __restrict__ dst, unsigned int* __restrict__ bcnt) {
  __shared__ unsigned int h[NBUK];
  for (int i = threadIdx.x; i < NBUK; i += 256) h[i] = 0u;
  __syncthreads();
  int i0 = blockIdx.x * 256 + threadIdx.x;
  int stride = gridDim.x * 256;
  for (int e = i0; e < NE; e += stride)
    atomicAdd(&h[((unsigned)dst[e]) >> 9], 1u);
  __syncthreads();
  for (int i = threadIdx.x; i < NBUK; i += 256)
    if (h[i]) atomicAdd(&bcnt[i], h[i]);
}

// ---------------------------------------------------------------------------
// Sort 2: exclusive scan of 196 bucket counts (one block).
__global__ __launch_bounds__(256) void k_bscan(
    const unsigned int* __restrict__ bcnt, unsigned int* __restrict__ gstart,
    unsigned int* __restrict__ gcur) {
  __shared__ unsigned int s[256];
  int t = threadIdx.x;
  unsigned int my = (t < NBUK) ? bcnt[t] : 0u;
  s[t] = my;
  __syncthreads();
  for (int off = 1; off < 256; off <<= 1) {
    unsigned int v = (t >= off) ? s[t - off] : 0u;
    __syncthreads();
    s[t] += v;
    __syncthreads();
  }
  if (t < NBUK) {
    gstart[t] = s[t] - my;
    gcur[t] = s[t] - my;
  }
  if (t == NBUK - 1) gstart[NBUK] = s[t];
}

// ---------------------------------------------------------------------------
// Sort 3: multisplit into 512-node buckets. Packed word = src | (dloc<<17).
__global__ __launch_bounds__(256) void k_msplit(
    const int* __restrict__ src, const int* __restrict__ dst,
    unsigned int* __restrict__ gcur, unsigned int* __restrict__ staging) {
  __shared__ unsigned int hist[NBUK];
  __shared__ unsigned int gbase[NBUK];
  int tid = threadIdx.x;
  for (int i = tid; i < NBUK; i += 256) hist[i] = 0u;
  __syncthreads();
  int e0 = blockIdx.x * (256 * MSB);
  unsigned int pk[MSB], rk[MSB], bk[MSB];
#pragma unroll
  for (int i = 0; i < MSB; ++i) {
    int e = e0 + i * 256 + tid;
    if (e < NE) {
      int d = dst[e];
      unsigned int b = (unsigned int)(d >> 9);
      rk[i] = atomicAdd(&hist[b], 1u);
      pk[i] = (unsigned int)src[e] | ((unsigned int)(d & 511) << 17);
      bk[i] = b;
    } else {
      bk[i] = 0xFFFFFFFFu;
    }
  }
  __syncthreads();
  for (int i = tid; i < NBUK; i += 256)
    if (hist[i]) gbase[i] = atomicAdd(&gcur[i], hist[i]);
  __syncthreads();
#pragma unroll
  for (int i = 0; i < MSB; ++i)
    if (bk[i] != 0xFFFFFFFFu) staging[gbase[bk[i]] + rk[i]] = pk[i];
}

// ---------------------------------------------------------------------------
// Sort 4 (fused): per-bucket node histogram + scan + scatter, ONE block per
// bucket. Single-CU-owned output window -> no cross-XCD line bouncing.
__global__ __launch_bounds__(512) void k_bucket_sort(
    const unsigned int* __restrict__ staging,
    const unsigned int* __restrict__ gstart, unsigned int* __restrict__ nstart,
    unsigned int* __restrict__ sorted_src) {
  __shared__ unsigned int hist[512];
  __shared__ unsigned int sc[512];
  __shared__ unsigned int cur[512];
  int b = blockIdx.x, t = threadIdx.x;
  hist[t] = 0u;
  __syncthreads();
  int lo = (int)gstart[b], hi = (int)gstart[b + 1];
  for (int e = lo + t; e < hi; e += 512)
    atomicAdd(&hist[staging[e] >> 17], 1u);
  __syncthreads();
  unsigned int my = hist[t];
  sc[t] = my;
  __syncthreads();
  for (int off = 1; off < 512; off <<= 1) {
    unsigned int v = (t >= off) ? sc[t - off] : 0u;
    __syncthreads();
    sc[t] += v;
    __syncthreads();
  }
  unsigned int st = (unsigned int)lo + sc[t] - my;  // exclusive start
  cur[t] = st;
  int node = b * 512 + t;
  if (node < NN) {
    nstart[node] = st;
    if (node == NN - 1) nstart[NN] = st + my;  // == NE
  }
  __syncthreads();
  for (int e = lo + t; e < hi; e += 512) {
    unsigned int u = staging[e];  // L2-hot (just read in pass 1)
    unsigned int pos = atomicAdd(&cur[u >> 17], 1u);
    sorted_src[pos] = u & 0x1FFFFu;
  }
}

// ---------------------------------------------------------------------------
// Aggregation over sorted edges: one wave per node, 4 edges per wave-instr.
// Lane layout: g = lane>>4 owns edge slot e+g; q = lane&15 owns channels
// 4q..4q+3 (uint2 = 8B gather). 2-deep unroll = 8 edges in flight.
// Cross-group reduce via shfl_xor; lanes g==0 write float4.
__global__ __launch_bounds__(256) void k_aggr_sorted(
    const unsigned int* __restrict__ sorted_src,
    const unsigned int* __restrict__ nstart,
    const unsigned short* __restrict__ h16, float* __restrict__ aggr) {
  int lane = threadIdx.x & 63;
  int n = (int)((blockIdx.x * 256 + threadIdx.x) >> 6);
  if (n >= NN) return;
  int g = lane >> 4;
  int q = lane & 15;
  int e0 = (int)nstart[n];
  int e1 = (int)nstart[n + 1];
  float ax = 0.f, ay = 0.f, az = 0.f, aw = 0.f;
  float bx = 0.f, by = 0.f, bz = 0.f, bw = 0.f;
  int e = e0 + g;
  for (; e + 4 < e1; e += 8) {
    unsigned int s0 = sorted_src[e];
    unsigned int s1 = sorted_src[e + 4];
    uint2 u0 = *(const uint2*)&h16[(size_t)s0 * HD + q * 4];
    uint2 u1 = *(const uint2*)&h16[(size_t)s1 * HD + q * 4];
    ax += __uint_as_float(u0.x << 16);
    ay += __uint_as_float(u0.x & 0xFFFF0000u);
    az += __uint_as_float(u0.y << 16);
    aw += __uint_as_float(u0.y & 0xFFFF0000u);
    bx += __uint_as_float(u1.x << 16);
    by += __uint_as_float(u1.x & 0xFFFF0000u);
    bz += __uint_as_float(u1.y << 16);
    bw += __uint_as_float(u1.y & 0xFFFF0000u);
  }
  if (e < e1) {
    unsigned int s0 = sorted_src[e];
    uint2 u0 = *(const uint2*)&h16[(size_t)s0 * HD + q * 4];
    ax += __uint_as_float(u0.x << 16);
    ay += __uint_as_float(u0.x & 0xFFFF0000u);
    az += __uint_as_float(u0.y << 16);
    aw += __uint_as_float(u0.y & 0xFFFF0000u);
  }
  ax += bx;
  ay += by;
  az += bz;
  aw += bw;
  // reduce across the 4 edge-slot groups (lane xor 16, then xor 32)
  ax += __shfl_xor(ax, 16);
  ay += __shfl_xor(ay, 16);
  az += __shfl_xor(az, 16);
  aw += __shfl_xor(aw, 16);
  ax += __shfl_xor(ax, 32);
  ay += __shfl_xor(ay, 32);
  az += __shfl_xor(az, 32);
  aw += __shfl_xor(aw, 32);
  if (g == 0) {
    float cntf = (float)(e1 - e0);
    float inv = (cntf > 0.f) ? 1.0f / cntf : 0.f;
    float4 o;
    o.x = ax * inv;
    o.y = ay * inv;
    o.z = az * inv;
    o.w = aw * inv;
    *(float4*)&aggr[(size_t)n * HD + q * 4] = o;
  }
}

// ---------------------------------------------------------------------------
// SAGE combine + fused BN-stats. Persistent blocks, LDS-staged row tiles.
__global__ __launch_bounds__(512) void k_combine(
    const float* __restrict__ aggr, const unsigned short* __restrict__ h16,
    const float* __restrict__ Wl, const float* __restrict__ bl,
    const float* __restrict__ Wr, float* __restrict__ pre,
    float* __restrict__ stats) {
  __shared__ float sWl[HD * HD], sWr[HD * HD];      // 32 KB
  __shared__ float sA[CB_TILE * HD], sH[CB_TILE * HD];  // 32 KB
  __shared__ float ss[512], sq[512];                // 4 KB
  int tid = threadIdx.x;
  for (int i = tid; i < HD * HD; i += 512) {
    sWl[i] = Wl[i];
    sWr[i] = Wr[i];
  }
  int w = tid >> 6, c = tid & 63;
  int rb = w * 8;
  float bc = bl[c];
  float S = 0.f, Q = 0.f;
  const int NT = (NN + CB_TILE - 1) / CB_TILE;  // 1563
  for (int t = blockIdx.x; t < NT; t += gridDim.x) {
    int row0 = t * CB_TILE;
    __syncthreads();  // prior compute reads done
    {
      int row = row0 + (tid >> 3);
      int rowc = row < NN ? row : NN - 1;
      int col0 = (tid & 7) * 8;
      const float* srcA = &aggr[(size_t)rowc * HD + col0];
      float4 a0 = *(const float4*)srcA;
      float4 a1 = *(const float4*)(srcA + 4);
      uint4 hu = *(const uint4*)&h16[(size_t)rowc * HD + col0];
      float* dA = &sA[(tid >> 3) * HD + col0];
      *(float4*)dA = a0;
      *(float4*)(dA + 4) = a1;
      float* dH = &sH[(tid >> 3) * HD + col0];
      dH[0] = bf2f((unsigned short)(hu.x & 0xFFFFu));
      dH[1] = bf2f((unsigned short)(hu.x >> 16));
      dH[2] = bf2f((unsigned short)(hu.y & 0xFFFFu));
      dH[3] = bf2f((unsigned short)(hu.y >> 16));
      dH[4] = bf2f((unsigned short)(hu.z & 0xFFFFu));
      dH[5] = bf2f((unsigned short)(hu.z >> 16));
      dH[6] = bf2f((unsigned short)(hu.w & 0xFFFFu));
      dH[7] = bf2f((unsigned short)(hu.w >> 16));
    }
    __syncthreads();
    float acc[8];
#pragma unroll
    for (int r = 0; r < 8; ++r) acc[r] = bc;
    for (int kg = 0; kg < HD; kg += 4) {
      float4 a4[8], h4[8];
#pragma unroll
      for (int r = 0; r < 8; ++r) {
        a4[r] = *(const float4*)&sA[(rb + r) * HD + kg];
        h4[r] = *(const float4*)&sH[(rb + r) * HD + kg];
      }
#pragma unroll
      for (int j = 0; j < 4; ++j) {
        float wl = sWl[(kg + j) * HD + c];
        float wr = sWr[(kg + j) * HD + c];
#pragma unroll
        for (int r = 0; r < 8; ++r) {
          acc[r] = fmaf(((const float*)&a4[r])[j], wl, acc[r]);
          acc[r] = fmaf(((const float*)&h4[r])[j], wr, acc[r]);
        }
      }
    }
#pragma unroll
    for (int r = 0; r < 8; ++r) {
      int row = row0 + rb + r;
      if (row < NN) {
        pre[(size_t)row * HD + c] = acc[r];
        S += acc[r];
        Q = fmaf(acc[r], acc[r], Q);
      }
    }
  }
  ss[tid] = S;
  sq[tid] = Q;
  __syncthreads();
  if (tid < 64) {
    float Ts = 0.f, Tq = 0.f;
#pragma unroll
    for (int j = 0; j < 8; ++j) {
      Ts += ss[j * 64 + tid];
      Tq += sq[j * 64 + tid];
    }
    atomicAdd(&stats[tid], Ts);
    atomicAdd(&stats[64 + tid], Tq);
  }
}

// ---------------------------------------------------------------------------
// Final fused: BN + ReLU + residual(bf16) + output head.
__global__ __launch_bounds__(256) void k_bn_relu_head(
    const float* __restrict__ pre, const float* __restrict__ stats,
    const float* __restrict__ g, const float* __restrict__ b,
    const unsigned short* __restrict__ resid16, const float* __restrict__ Wo,
    const float* __restrict__ bo, float* __restrict__ out) {
  int lane = threadIdx.x & 63;
  int wid = (int)((blockIdx.x * blockDim.x + threadIdx.x) >> 6);
  int nw = (int)((gridDim.x * blockDim.x) >> 6);
  const float invN = 1.0f / NN;
  float m = stats[lane] * invN;
  float v = stats[64 + lane] * invN - m * m;
  float sc = g[lane] * rsqrtf(v + BN_EPS);
  float bb = b[lane];
  float w0 = Wo[lane * 2], w1 = Wo[lane * 2 + 1];
  float b0 = bo[0], b1 = bo[1];
  for (int row = wid; row < NN; row += nw) {
    size_t i = (size_t)row * HD + lane;
    float val = (pre[i] - m) * sc + bb;
    val = fmaxf(val, 0.f) + bf2f(resid16[i]);
    float a0 = val * w0, a1 = val * w1;
#pragma unroll
    for (int off = 32; off > 0; off >>= 1) {
      a0 += __shfl_down(a0, off);
      a1 += __shfl_down(a1, off);
    }
    if (lane == 0) {
      out[(size_t)row * 2] = a0 + b0;
      out[(size_t)row * 2 + 1] = a1 + b1;
    }
  }
}

// ---------------------------------------------------------------------------
extern "C" void kernel_launch(void* const* d_in, const int* in_sizes, int n_in,
                              void* d_out, int out_size, void* d_ws,
                              size_t ws_size, hipStream_t stream) {
  const float* x = (const float*)d_in[0];
  const int* ei = (const int*)d_in[1];
  const float* Wp = (const float*)d_in[2];
  const float* bp = (const float*)d_in[3];
  const float* g_in = (const float*)d_in[4];
  const float* b_in = (const float*)d_in[5];
  const float* Wl0 = (const float*)d_in[6];
  const float* bl0 = (const float*)d_in[7];
  const float* Wr0 = (const float*)d_in[8];
  const float* g0 = (const float*)d_in[9];
  const float* b0 = (const float*)d_in[10];
  const float* Wl1 = (const float*)d_in[11];
  const float* bl1 = (const float*)d_in[12];
  const float* Wr1 = (const float*)d_in[13];
  const float* g1 = (const float*)d_in[14];
  const float* b1 = (const float*)d_in[15];
  const float* Wo = (const float*)d_in[16];
  const float* bo = (const float*)d_in[17];
  float* out = (float*)d_out;

  const int* src = ei;
  const int* dst = ei + NE;

  float* ws = (float*)d_ws;
  float* pre = ws;  // [NN*HD] f32 (also aggr buffer)
  __hip_bfloat16* h0b = (__hip_bfloat16*)(ws + (size_t)NN * HD);  // [NN*HD]
  __hip_bfloat16* h1b = h0b + (size_t)NN * HD;                    // [NN*HD]
  unsigned int* staging = (unsigned int*)(h1b + (size_t)NN * HD); // [NE]
  unsigned int* sorted_src = staging + NE;   // [NE]
  unsigned int* nstart = sorted_src + NE;    // [NN+1]
  unsigned int* bcnt = nstart + NN + 1;      // [NBUK]
  unsigned int* gstart = bcnt + NBUK;        // [NBUK+1]
  unsigned int* gcur = gstart + NBUK + 1;    // [NBUK]
  float* stats0 = (float*)(gcur + NBUK);     // [128]
  float* stats1 = stats0 + 128;              // [128]
  float* stats2 = stats1 + 128;              // [128]

  const int ELEM_BLOCKS = (NN * HD) / 256;  // 25000
  const int AGGR_BLOCKS = 25000;            // 100k waves, 4/block
  const int MS_BLOCKS = (NE + 256 * MSB - 1) / (256 * MSB);  // 782

  hipMemsetAsync(stats0, 0, 3 * 128 * sizeof(float), stream);
  hipMemsetAsync(bcnt, 0, NBUK * sizeof(unsigned int), stream);

  // ---- input projection (+stats) + BN/ReLU -> h0 (bf16)
  k_gemm_in<<<768, 256, 0, stream>>>(x, Wp, bp, pre, stats0);
  k_bn_relu<<<ELEM_BLOCKS, 256, 0, stream>>>(pre, stats0, g_in, b_in, h0b);

  // ---- counting-sort edges by dst, bucket-first; scatter is bucket-local
  k_bhist<<<1024, 256, 0, stream>>>(dst, bcnt);
  k_bscan<<<1, 256, 0, stream>>>(bcnt, gstart, gcur);
  k_msplit<<<MS_BLOCKS, 256, 0, stream>>>(src, dst, gcur, staging);
  k_bucket_sort<<<NBUK, 512, 0, stream>>>(staging, gstart, nstart, sorted_src);

  // ---- layer 0
  k_aggr_sorted<<<AGGR_BLOCKS, 256, 0, stream>>>(
      sorted_src, nstart, (const unsigned short*)h0b, pre);
  k_combine<<<512, 512, 0, stream>>>(pre, (const unsigned short*)h0b, Wl0,
                                     bl0, Wr0, pre, stats1);
  k_bn_relu<<<ELEM_BLOCKS, 256, 0, stream>>>(pre, stats1, g0, b0, h1b);

  // ---- layer 1 + fused BN/ReLU/residual/head
  k_aggr_sorted<<<AGGR_BLOCKS, 256, 0, stream>>>(
      sorted_src, nstart, (const unsigned short*)h1b, pre);
  k_combine<<<512, 512, 0, stream>>>(pre, (const unsigned short*)h1b, Wl1,
                                     bl1, Wr1, pre, stats2);
  k_bn_relu_head<<<1024, 256, 0, stream>>>(pre, stats2, g1, b1,
                                           (const unsigned short*)h0b, Wo, bo,
                                           out);
}

// Round 11
// 425.310 us; speedup vs baseline: 2.9528x; 1.0612x over previous
//
#include <hip/hip_runtime.h>
#include <hip/hip_bf16.h>

#define NN 100000
#define NE 3200000
#define IC 128
#define HD 64
#define BN_EPS 1e-5f
#define NBUK 196      // ceil(NN / 512) buckets of 512 nodes (dst >> 9)
#define MSB 16        // edges per thread in multisplit (batch = 4096/block)

__device__ __forceinline__ float bf2f(unsigned short u) {
  return __uint_as_float(((unsigned)u) << 16);
}

// ---------------------------------------------------------------------------
// Input projection + fused BN-stats. 4x4 register tile per thread.
// 256 thr: cg = tid&15 -> cols cg*4..+3 ; rg = tid>>4 -> rows rg*4..+3.
// Tile = 64 rows x 64 cols. Per 4-k step: 4 x-b128 + 4 w-b128 -> 64 FMA.
__global__ __launch_bounds__(256) void k_gemm_in(
    const float* __restrict__ x, const float* __restrict__ Wp,
    const float* __restrict__ bp, float* __restrict__ pre,
    float* __restrict__ stats) {
  __shared__ float sW[IC * HD];        // 32 KB  [k][c]
  __shared__ float sX[64 * 130];       // 33.3 KB [r][k], pad->bank-spread
  __shared__ float ssS[1024], ssQ[1024];  // 8 KB
  int tid = threadIdx.x;
  for (int i = tid; i < IC * HD / 4; i += 256)
    *(float4*)&sW[i * 4] = *(const float4*)&Wp[i * 4];
  int cg = tid & 15, rg = tid >> 4;
  int c0 = cg * 4;
  float4 bpc = *(const float4*)&bp[c0];
  float S[4] = {0.f, 0.f, 0.f, 0.f}, Q[4] = {0.f, 0.f, 0.f, 0.f};
  const int NT = (NN + 63) / 64;  // 1563
  for (int t = blockIdx.x; t < NT; t += gridDim.x) {
    int row0 = t * 64;
    __syncthreads();  // prior tile's LDS reads done
    for (int i = tid; i < 64 * IC / 4; i += 256) {
      int r = i >> 5, k4 = i & 31;  // 32 float4 per row
      int grow = row0 + r;
      if (grow >= NN) grow = NN - 1;
      *(float4*)&sX[r * 130 + k4 * 4] =
          *(const float4*)&x[(size_t)grow * IC + k4 * 4];
    }
    __syncthreads();
    float acc[4][4];
#pragma unroll
    for (int r = 0; r < 4; ++r)
#pragma unroll
      for (int c = 0; c < 4; ++c) acc[r][c] = ((const float*)&bpc)[c];
    for (int kg = 0; kg < IC; kg += 4) {
      float4 xr[4], wv[4];
#pragma unroll
      for (int r = 0; r < 4; ++r)
        xr[r] = *(const float4*)&sX[(rg * 4 + r) * 130 + kg];
#pragma unroll
      for (int j = 0; j < 4; ++j)
        wv[j] = *(const float4*)&sW[(kg + j) * HD + c0];
#pragma unroll
      for (int j = 0; j < 4; ++j)
#pragma unroll
        for (int r = 0; r < 4; ++r) {
          float xv = ((const float*)&xr[r])[j];
          acc[r][0] = fmaf(xv, ((const float*)&wv[j])[0], acc[r][0]);
          acc[r][1] = fmaf(xv, ((const float*)&wv[j])[1], acc[r][1]);
          acc[r][2] = fmaf(xv, ((const float*)&wv[j])[2], acc[r][2]);
          acc[r][3] = fmaf(xv, ((const float*)&wv[j])[3], acc[r][3]);
        }
    }
#pragma unroll
    for (int r = 0; r < 4; ++r) {
      int row = row0 + rg * 4 + r;
      if (row < NN) {
        *(float4*)&pre[(size_t)row * HD + c0] = *(float4*)&acc[r][0];
#pragma unroll
        for (int c = 0; c < 4; ++c) {
          S[c] += acc[r][c];
          Q[c] = fmaf(acc[r][c], acc[r][c], Q[c]);
        }
      }
    }
  }
#pragma unroll
  for (int c = 0; c < 4; ++c) {
    ssS[tid * 4 + c] = S[c];
    ssQ[tid * 4 + c] = Q[c];
  }
  __syncthreads();
  if (tid < 64) {
    int cgr = tid >> 2, cc = tid & 3;
    float Ts = 0.f, Tq = 0.f;
#pragma unroll
    for (int m = 0; m < 16; ++m) {
      Ts += ssS[(m * 16 + cgr) * 4 + cc];
      Tq += ssQ[(m * 16 + cgr) * 4 + cc];
    }
    atomicAdd(&stats[tid], Ts);
    atomicAdd(&stats[64 + tid], Tq);
  }
}

// ---------------------------------------------------------------------------
// BN normalize + ReLU -> bf16 hidden state.
__global__ __launch_bounds__(256) void k_bn_relu(
    const float* __restrict__ pre, const float* __restrict__ stats,
    const float* __restrict__ g, const float* __restrict__ b,
    __hip_bfloat16* __restrict__ out16) {
  size_t i = (size_t)blockIdx.x * 256 + threadIdx.x;
  int c = threadIdx.x & 63;
  const float invN = 1.0f / NN;
  float m = stats[c] * invN;
  float v = stats[64 + c] * invN - m * m;
  float sc = g[c] * rsqrtf(v + BN_EPS);
  float val = (pre[i] - m) * sc + b[c];
  out16[i] = __float2bfloat16(fmaxf(val, 0.f));
}

// ---------------------------------------------------------------------------
// Sort 1: bucket histogram via LDS (196 bins), block-reduced to global.
__global__ __launch_bounds__(256) void k_bhist(
    const int* __restrict__ dst, unsigned int* __restrict__ bcnt) {
  __shared__ unsigned int h[NBUK];
  for (int i = threadIdx.x; i < NBUK; i += 256) h[i] = 0u;
  __syncthreads();
  int i0 = blockIdx.x * 256 + threadIdx.x;
  int stride = gridDim.x * 256;
  for (int e = i0; e < NE; e += stride)
    atomicAdd(&h[((unsigned)dst[e]) >> 9], 1u);
  __syncthreads();
  for (int i = threadIdx.x; i < NBUK; i += 256)
    if (h[i]) atomicAdd(&bcnt[i], h[i]);
}

// ---------------------------------------------------------------------------
// Sort 2: exclusive scan of 196 bucket counts (one block).
__global__ __launch_bounds__(256) void k_bscan(
    const unsigned int* __restrict__ bcnt, unsigned int* __restrict__ gstart,
    unsigned int* __restrict__ gcur) {
  __shared__ unsigned int s[256];
  int t = threadIdx.x;
  unsigned int my = (t < NBUK) ? bcnt[t] : 0u;
  s[t] = my;
  __syncthreads();
  for (int off = 1; off < 256; off <<= 1) {
    unsigned int v = (t >= off) ? s[t - off] : 0u;
    __syncthreads();
    s[t] += v;
    __syncthreads();
  }
  if (t < NBUK) {
    gstart[t] = s[t] - my;
    gcur[t] = s[t] - my;
  }
  if (t == NBUK - 1) gstart[NBUK] = s[t];
}

// ---------------------------------------------------------------------------
// Sort 3: multisplit into 512-node buckets. Packed word = src | (dloc<<17).
__global__ __launch_bounds__(256) void k_msplit(
    const int* __restrict__ src, const int* __restrict__ dst,
    unsigned int* __restrict__ gcur, unsigned int* __restrict__ staging) {
  __shared__ unsigned int hist[NBUK];
  __shared__ unsigned int gbase[NBUK];
  int tid = threadIdx.x;
  for (int i = tid; i < NBUK; i += 256) hist[i] = 0u;
  __syncthreads();
  int e0 = blockIdx.x * (256 * MSB);
  unsigned int pk[MSB], rk[MSB], bk[MSB];
#pragma unroll
  for (int i = 0; i < MSB; ++i) {
    int e = e0 + i * 256 + tid;
    if (e < NE) {
      int d = dst[e];
      unsigned int b = (unsigned int)(d >> 9);
      rk[i] = atomicAdd(&hist[b], 1u);
      pk[i] = (unsigned int)src[e] | ((unsigned int)(d & 511) << 17);
      bk[i] = b;
    } else {
      bk[i] = 0xFFFFFFFFu;
    }
  }
  __syncthreads();
  for (int i = tid; i < NBUK; i += 256)
    if (hist[i]) gbase[i] = atomicAdd(&gcur[i], hist[i]);
  __syncthreads();
#pragma unroll
  for (int i = 0; i < MSB; ++i)
    if (bk[i] != 0xFFFFFFFFu) staging[gbase[bk[i]] + rk[i]] = pk[i];
}

// ---------------------------------------------------------------------------
// Sort 4 (fused): per-bucket node histogram + scan + scatter, ONE block per
// bucket. Single-CU-owned output window -> no cross-XCD line bouncing.
__global__ __launch_bounds__(512) void k_bucket_sort(
    const unsigned int* __restrict__ staging,
    const unsigned int* __restrict__ gstart, unsigned int* __restrict__ nstart,
    unsigned int* __restrict__ sorted_src) {
  __shared__ unsigned int hist[512];
  __shared__ unsigned int sc[512];
  __shared__ unsigned int cur[512];
  int b = blockIdx.x, t = threadIdx.x;
  hist[t] = 0u;
  __syncthreads();
  int lo = (int)gstart[b], hi = (int)gstart[b + 1];
  for (int e = lo + t; e < hi; e += 512)
    atomicAdd(&hist[staging[e] >> 17], 1u);
  __syncthreads();
  unsigned int my = hist[t];
  sc[t] = my;
  __syncthreads();
  for (int off = 1; off < 512; off <<= 1) {
    unsigned int v = (t >= off) ? sc[t - off] : 0u;
    __syncthreads();
    sc[t] += v;
    __syncthreads();
  }
  unsigned int st = (unsigned int)lo + sc[t] - my;  // exclusive start
  cur[t] = st;
  int node = b * 512 + t;
  if (node < NN) {
    nstart[node] = st;
    if (node == NN - 1) nstart[NN] = st + my;  // == NE
  }
  __syncthreads();
  for (int e = lo + t; e < hi; e += 512) {
    unsigned int u = staging[e];  // L2-hot (just read in pass 1)
    unsigned int pos = atomicAdd(&cur[u >> 17], 1u);
    sorted_src[pos] = u & 0x1FFFFu;
  }
}

// ---------------------------------------------------------------------------
// Aggregation over sorted edges: one wave per node, 4 edges per wave-instr.
__global__ __launch_bounds__(256) void k_aggr_sorted(
    const unsigned int* __restrict__ sorted_src,
    const unsigned int* __restrict__ nstart,
    const unsigned short* __restrict__ h16, float* __restrict__ aggr) {
  int lane = threadIdx.x & 63;
  int n = (int)((blockIdx.x * 256 + threadIdx.x) >> 6);
  if (n >= NN) return;
  int g = lane >> 4;
  int q = lane & 15;
  int e0 = (int)nstart[n];
  int e1 = (int)nstart[n + 1];
  float ax = 0.f, ay = 0.f, az = 0.f, aw = 0.f;
  float bx = 0.f, by = 0.f, bz = 0.f, bw = 0.f;
  int e = e0 + g;
  for (; e + 4 < e1; e += 8) {
    unsigned int s0 = sorted_src[e];
    unsigned int s1 = sorted_src[e + 4];
    uint2 u0 = *(const uint2*)&h16[(size_t)s0 * HD + q * 4];
    uint2 u1 = *(const uint2*)&h16[(size_t)s1 * HD + q * 4];
    ax += __uint_as_float(u0.x << 16);
    ay += __uint_as_float(u0.x & 0xFFFF0000u);
    az += __uint_as_float(u0.y << 16);
    aw += __uint_as_float(u0.y & 0xFFFF0000u);
    bx += __uint_as_float(u1.x << 16);
    by += __uint_as_float(u1.x & 0xFFFF0000u);
    bz += __uint_as_float(u1.y << 16);
    bw += __uint_as_float(u1.y & 0xFFFF0000u);
  }
  if (e < e1) {
    unsigned int s0 = sorted_src[e];
    uint2 u0 = *(const uint2*)&h16[(size_t)s0 * HD + q * 4];
    ax += __uint_as_float(u0.x << 16);
    ay += __uint_as_float(u0.x & 0xFFFF0000u);
    az += __uint_as_float(u0.y << 16);
    aw += __uint_as_float(u0.y & 0xFFFF0000u);
  }
  ax += bx;
  ay += by;
  az += bz;
  aw += bw;
  ax += __shfl_xor(ax, 16);
  ay += __shfl_xor(ay, 16);
  az += __shfl_xor(az, 16);
  aw += __shfl_xor(aw, 16);
  ax += __shfl_xor(ax, 32);
  ay += __shfl_xor(ay, 32);
  az += __shfl_xor(az, 32);
  aw += __shfl_xor(aw, 32);
  if (g == 0) {
    float cntf = (float)(e1 - e0);
    float inv = (cntf > 0.f) ? 1.0f / cntf : 0.f;
    float4 o;
    o.x = ax * inv;
    o.y = ay * inv;
    o.z = az * inv;
    o.w = aw * inv;
    *(float4*)&aggr[(size_t)n * HD + q * 4] = o;
  }
}

// ---------------------------------------------------------------------------
// SAGE combine + fused BN-stats. 4x4 register tile per thread, two GEMMs.
// Per 4-k step: 4 A-b128 + 4 H-b128 + 8 W-b128 -> 128 FMA.
// Safe with pre == aggr (stage, sync, compute, write own tile).
__global__ __launch_bounds__(256) void k_combine(
    const float* __restrict__ aggr, const unsigned short* __restrict__ h16,
    const float* __restrict__ Wl, const float* __restrict__ bl,
    const float* __restrict__ Wr, float* __restrict__ pre,
    float* __restrict__ stats) {
  __shared__ float sWl[HD * HD], sWr[HD * HD];  // 32 KB  [k][c]
  __shared__ float sA[64 * 66], sH[64 * 66];    // 33.8 KB [r][k] padded
  __shared__ float ssS[1024], ssQ[1024];        // 8 KB
  int tid = threadIdx.x;
  for (int i = tid; i < HD * HD / 4; i += 256) {
    *(float4*)&sWl[i * 4] = *(const float4*)&Wl[i * 4];
    *(float4*)&sWr[i * 4] = *(const float4*)&Wr[i * 4];
  }
  int cg = tid & 15, rg = tid >> 4;
  int c0 = cg * 4;
  float4 blc = *(const float4*)&bl[c0];
  float S[4] = {0.f, 0.f, 0.f, 0.f}, Q[4] = {0.f, 0.f, 0.f, 0.f};
  const int NT = (NN + 63) / 64;  // 1563
  for (int t = blockIdx.x; t < NT; t += gridDim.x) {
    int row0 = t * 64;
    __syncthreads();  // prior tile's LDS reads done
    for (int i = tid; i < 1024; i += 256) {
      int r = i >> 4, k4 = i & 15;  // 16 float4 per row
      int grow = row0 + r;
      if (grow >= NN) grow = NN - 1;
      *(float4*)&sA[r * 66 + k4 * 4] =
          *(const float4*)&aggr[(size_t)grow * HD + k4 * 4];
      uint2 hu = *(const uint2*)&h16[(size_t)grow * HD + k4 * 4];
      float* dH = &sH[r * 66 + k4 * 4];
      dH[0] = bf2f((unsigned short)(hu.x & 0xFFFFu));
      dH[1] = bf2f((unsigned short)(hu.x >> 16));
      dH[2] = bf2f((unsigned short)(hu.y & 0xFFFFu));
      dH[3] = bf2f((unsigned short)(hu.y >> 16));
    }
    __syncthreads();
    float acc[4][4];
#pragma unroll
    for (int r = 0; r < 4; ++r)
#pragma unroll
      for (int c = 0; c < 4; ++c) acc[r][c] = ((const float*)&blc)[c];
    for (int kg = 0; kg < HD; kg += 4) {
      float4 ar[4], hr[4], wlv[4], wrv[4];
#pragma unroll
      for (int r = 0; r < 4; ++r) {
        ar[r] = *(const float4*)&sA[(rg * 4 + r) * 66 + kg];
        hr[r] = *(const float4*)&sH[(rg * 4 + r) * 66 + kg];
      }
#pragma unroll
      for (int j = 0; j < 4; ++j) {
        wlv[j] = *(const float4*)&sWl[(kg + j) * HD + c0];
        wrv[j] = *(const float4*)&sWr[(kg + j) * HD + c0];
      }
#pragma unroll
      for (int j = 0; j < 4; ++j)
#pragma unroll
        for (int r = 0; r < 4; ++r) {
          float av = ((const float*)&ar[r])[j];
          float hv = ((const float*)&hr[r])[j];
#pragma unroll
          for (int c = 0; c < 4; ++c) {
            acc[r][c] = fmaf(av, ((const float*)&wlv[j])[c], acc[r][c]);
            acc[r][c] = fmaf(hv, ((const float*)&wrv[j])[c], acc[r][c]);
          }
        }
    }
#pragma unroll
    for (int r = 0; r < 4; ++r) {
      int row = row0 + rg * 4 + r;
      if (row < NN) {
        *(float4*)&pre[(size_t)row * HD + c0] = *(float4*)&acc[r][0];
#pragma unroll
        for (int c = 0; c < 4; ++c) {
          S[c] += acc[r][c];
          Q[c] = fmaf(acc[r][c], acc[r][c], Q[c]);
        }
      }
    }
  }
#pragma unroll
  for (int c = 0; c < 4; ++c) {
    ssS[tid * 4 + c] = S[c];
    ssQ[tid * 4 + c] = Q[c];
  }
  __syncthreads();
  if (tid < 64) {
    int cgr = tid >> 2, cc = tid & 3;
    float Ts = 0.f, Tq = 0.f;
#pragma unroll
    for (int m = 0; m < 16; ++m) {
      Ts += ssS[(m * 16 + cgr) * 4 + cc];
      Tq += ssQ[(m * 16 + cgr) * 4 + cc];
    }
    atomicAdd(&stats[tid], Ts);
    atomicAdd(&stats[64 + tid], Tq);
  }
}

// ---------------------------------------------------------------------------
// Final fused: BN + ReLU + residual(bf16) + output head.
__global__ __launch_bounds__(256) void k_bn_relu_head(
    const float* __restrict__ pre, const float* __restrict__ stats,
    const float* __restrict__ g, const float* __restrict__ b,
    const unsigned short* __restrict__ resid16, const float* __restrict__ Wo,
    const float* __restrict__ bo, float* __restrict__ out) {
  int lane = threadIdx.x & 63;
  int wid = (int)((blockIdx.x * blockDim.x + threadIdx.x) >> 6);
  int nw = (int)((gridDim.x * blockDim.x) >> 6);
  const float invN = 1.0f / NN;
  float m = stats[lane] * invN;
  float v = stats[64 + lane] * invN - m * m;
  float sc = g[lane] * rsqrtf(v + BN_EPS);
  float bb = b[lane];
  float w0 = Wo[lane * 2], w1 = Wo[lane * 2 + 1];
  float b0 = bo[0], b1 = bo[1];
  for (int row = wid; row < NN; row += nw) {
    size_t i = (size_t)row * HD + lane;
    float val = (pre[i] - m) * sc + bb;
    val = fmaxf(val, 0.f) + bf2f(resid16[i]);
    float a0 = val * w0, a1 = val * w1;
#pragma unroll
    for (int off = 32; off > 0; off >>= 1) {
      a0 += __shfl_down(a0, off);
      a1 += __shfl_down(a1, off);
    }
    if (lane == 0) {
      out[(size_t)row * 2] = a0 + b0;
      out[(size_t)row * 2 + 1] = a1 + b1;
    }
  }
}

// ---------------------------------------------------------------------------
extern "C" void kernel_launch(void* const* d_in, const int* in_sizes, int n_in,
                              void* d_out, int out_size, void* d_ws,
                              size_t ws_size, hipStream_t stream) {
  const float* x = (const float*)d_in[0];
  const int* ei = (const int*)d_in[1];
  const float* Wp = (const float*)d_in[2];
  const float* bp = (const float*)d_in[3];
  const float* g_in = (const float*)d_in[4];
  const float* b_in = (const float*)d_in[5];
  const float* Wl0 = (const float*)d_in[6];
  const float* bl0 = (const float*)d_in[7];
  const float* Wr0 = (const float*)d_in[8];
  const float* g0 = (const float*)d_in[9];
  const float* b0 = (const float*)d_in[10];
  const float* Wl1 = (const float*)d_in[11];
  const float* bl1 = (const float*)d_in[12];
  const float* Wr1 = (const float*)d_in[13];
  const float* g1 = (const float*)d_in[14];
  const float* b1 = (const float*)d_in[15];
  const float* Wo = (const float*)d_in[16];
  const float* bo = (const float*)d_in[17];
  float* out = (float*)d_out;

  const int* src = ei;
  const int* dst = ei + NE;

  float* ws = (float*)d_ws;
  float* pre = ws;  // [NN*HD] f32 (also aggr buffer)
  __hip_bfloat16* h0b = (__hip_bfloat16*)(ws + (size_t)NN * HD);  // [NN*HD]
  __hip_bfloat16* h1b = h0b + (size_t)NN * HD;                    // [NN*HD]
  unsigned int* staging = (unsigned int*)(h1b + (size_t)NN * HD); // [NE]
  unsigned int* sorted_src = staging + NE;   // [NE]
  unsigned int* nstart = sorted_src + NE;    // [NN+1]
  unsigned int* bcnt = nstart + NN + 1;      // [NBUK]
  unsigned int* gstart = bcnt + NBUK;        // [NBUK+1]
  unsigned int* gcur = gstart + NBUK + 1;    // [NBUK]
  float* stats0 = (float*)(gcur + NBUK);     // [128]
  float* stats1 = stats0 + 128;              // [128]
  float* stats2 = stats1 + 128;              // [128]

  const int ELEM_BLOCKS = (NN * HD) / 256;  // 25000
  const int AGGR_BLOCKS = 25000;            // 100k waves, 4/block
  const int MS_BLOCKS = (NE + 256 * MSB - 1) / (256 * MSB);  // 782

  hipMemsetAsync(stats0, 0, 3 * 128 * sizeof(float), stream);
  hipMemsetAsync(bcnt, 0, NBUK * sizeof(unsigned int), stream);

  // ---- input projection (+stats) + BN/ReLU -> h0 (bf16)
  k_gemm_in<<<512, 256, 0, stream>>>(x, Wp, bp, pre, stats0);
  k_bn_relu<<<ELEM_BLOCKS, 256, 0, stream>>>(pre, stats0, g_in, b_in, h0b);

  // ---- counting-sort edges by dst, bucket-first; scatter is bucket-local
  k_bhist<<<1024, 256, 0, stream>>>(dst, bcnt);
  k_bscan<<<1, 256, 0, stream>>>(bcnt, gstart, gcur);
  k_msplit<<<MS_BLOCKS, 256, 0, stream>>>(src, dst, gcur, staging);
  k_bucket_sort<<<NBUK, 512, 0, stream>>>(staging, gstart, nstart, sorted_src);

  // ---- layer 0
  k_aggr_sorted<<<AGGR_BLOCKS, 256, 0, stream>>>(
      sorted_src, nstart, (const unsigned short*)h0b, pre);
  k_combine<<<512, 256, 0, stream>>>(pre, (const unsigned short*)h0b, Wl0,
                                     bl0, Wr0, pre, stats1);
  k_bn_relu<<<ELEM_BLOCKS, 256, 0, stream>>>(pre, stats1, g0, b0, h1b);

  // ---- layer 1 + fused BN/ReLU/residual/head
  k_aggr_sorted<<<AGGR_BLOCKS, 256, 0, stream>>>(
      sorted_src, nstart, (const unsigned short*)h1b, pre);
  k_combine<<<512, 256, 0, stream>>>(pre, (const unsigned short*)h1b, Wl1,
                                     bl1, Wr1, pre, stats2);
  k_bn_relu_head<<<1024, 256, 0, stream>>>(pre, stats2, g1, b1,
                                           (const unsigned short*)h0b, Wo, bo,
                                           out);
}

// Round 12
// 399.762 us; speedup vs baseline: 3.1416x; 1.0639x over previous
//
#include <hip/hip_runtime.h>
#include <hip/hip_bf16.h>

#define NN 100000
#define NE 3200000
#define IC 128
#define HD 64
#define BN_EPS 1e-5f
#define NBUK 196      // ceil(NN / 512) buckets of 512 nodes (dst >> 9)
#define MSB 16        // edges per thread in multisplit (batch = 4096/block)

__device__ __forceinline__ float bf2f(unsigned short u) {
  return __uint_as_float(((unsigned)u) << 16);
}
// f32 -> bf16 (RNE), returns low 16 bits
__device__ __forceinline__ unsigned int f2bf(float f) {
  unsigned int u = __float_as_uint(f);
  return (u + 0x7FFFu + ((u >> 16) & 1u)) >> 16;
}

// ---------------------------------------------------------------------------
// Input projection + fused BN-stats. 4x4 register tile per thread.
__global__ __launch_bounds__(256) void k_gemm_in(
    const float* __restrict__ x, const float* __restrict__ Wp,
    const float* __restrict__ bp, float* __restrict__ pre,
    float* __restrict__ stats) {
  __shared__ float sW[IC * HD];        // 32 KB  [k][c]
  __shared__ float sX[64 * 130];       // 33.3 KB [r][k], pad->bank-spread
  __shared__ float ssS[1024], ssQ[1024];  // 8 KB
  int tid = threadIdx.x;
  for (int i = tid; i < IC * HD / 4; i += 256)
    *(float4*)&sW[i * 4] = *(const float4*)&Wp[i * 4];
  int cg = tid & 15, rg = tid >> 4;
  int c0 = cg * 4;
  float4 bpc = *(const float4*)&bp[c0];
  float S[4] = {0.f, 0.f, 0.f, 0.f}, Q[4] = {0.f, 0.f, 0.f, 0.f};
  const int NT = (NN + 63) / 64;  // 1563
  for (int t = blockIdx.x; t < NT; t += gridDim.x) {
    int row0 = t * 64;
    __syncthreads();  // prior tile's LDS reads done
    for (int i = tid; i < 64 * IC / 4; i += 256) {
      int r = i >> 5, k4 = i & 31;  // 32 float4 per row
      int grow = row0 + r;
      if (grow >= NN) grow = NN - 1;
      *(float4*)&sX[r * 130 + k4 * 4] =
          *(const float4*)&x[(size_t)grow * IC + k4 * 4];
    }
    __syncthreads();
    float acc[4][4];
#pragma unroll
    for (int r = 0; r < 4; ++r)
#pragma unroll
      for (int c = 0; c < 4; ++c) acc[r][c] = ((const float*)&bpc)[c];
    for (int kg = 0; kg < IC; kg += 4) {
      float4 xr[4], wv[4];
#pragma unroll
      for (int r = 0; r < 4; ++r)
        xr[r] = *(const float4*)&sX[(rg * 4 + r) * 130 + kg];
#pragma unroll
      for (int j = 0; j < 4; ++j)
        wv[j] = *(const float4*)&sW[(kg + j) * HD + c0];
#pragma unroll
      for (int j = 0; j < 4; ++j)
#pragma unroll
        for (int r = 0; r < 4; ++r) {
          float xv = ((const float*)&xr[r])[j];
          acc[r][0] = fmaf(xv, ((const float*)&wv[j])[0], acc[r][0]);
          acc[r][1] = fmaf(xv, ((const float*)&wv[j])[1], acc[r][1]);
          acc[r][2] = fmaf(xv, ((const float*)&wv[j])[2], acc[r][2]);
          acc[r][3] = fmaf(xv, ((const float*)&wv[j])[3], acc[r][3]);
        }
    }
#pragma unroll
    for (int r = 0; r < 4; ++r) {
      int row = row0 + rg * 4 + r;
      if (row < NN) {
        *(float4*)&pre[(size_t)row * HD + c0] = *(float4*)&acc[r][0];
#pragma unroll
        for (int c = 0; c < 4; ++c) {
          S[c] += acc[r][c];
          Q[c] = fmaf(acc[r][c], acc[r][c], Q[c]);
        }
      }
    }
  }
#pragma unroll
  for (int c = 0; c < 4; ++c) {
    ssS[tid * 4 + c] = S[c];
    ssQ[tid * 4 + c] = Q[c];
  }
  __syncthreads();
  if (tid < 64) {
    int cgr = tid >> 2, cc = tid & 3;
    float Ts = 0.f, Tq = 0.f;
#pragma unroll
    for (int m = 0; m < 16; ++m) {
      Ts += ssS[(m * 16 + cgr) * 4 + cc];
      Tq += ssQ[(m * 16 + cgr) * 4 + cc];
    }
    atomicAdd(&stats[tid], Ts);
    atomicAdd(&stats[64 + tid], Tq);
  }
}

// ---------------------------------------------------------------------------
// BN normalize + ReLU -> bf16 hidden state.
__global__ __launch_bounds__(256) void k_bn_relu(
    const float* __restrict__ pre, const float* __restrict__ stats,
    const float* __restrict__ g, const float* __restrict__ b,
    __hip_bfloat16* __restrict__ out16) {
  size_t i = (size_t)blockIdx.x * 256 + threadIdx.x;
  int c = threadIdx.x & 63;
  const float invN = 1.0f / NN;
  float m = stats[c] * invN;
  float v = stats[64 + c] * invN - m * m;
  float sc = g[c] * rsqrtf(v + BN_EPS);
  float val = (pre[i] - m) * sc + b[c];
  out16[i] = __float2bfloat16(fmaxf(val, 0.f));
}

// ---------------------------------------------------------------------------
// Sort 1: bucket histogram via LDS (196 bins), block-reduced to global.
__global__ __launch_bounds__(256) void k_bhist(
    const int* __restrict__ dst, unsigned int* __restrict__ bcnt) {
  __shared__ unsigned int h[NBUK];
  for (int i = threadIdx.x; i < NBUK; i += 256) h[i] = 0u;
  __syncthreads();
  int i0 = blockIdx.x * 256 + threadIdx.x;
  int stride = gridDim.x * 256;
  for (int e = i0; e < NE; e += stride)
    atomicAdd(&h[((unsigned)dst[e]) >> 9], 1u);
  __syncthreads();
  for (int i = threadIdx.x; i < NBUK; i += 256)
    if (h[i]) atomicAdd(&bcnt[i], h[i]);
}

// ---------------------------------------------------------------------------
// Sort 2: exclusive scan of 196 bucket counts (one block).
__global__ __launch_bounds__(256) void k_bscan(
    const unsigned int* __restrict__ bcnt, unsigned int* __restrict__ gstart,
    unsigned int* __restrict__ gcur) {
  __shared__ unsigned int s[256];
  int t = threadIdx.x;
  unsigned int my = (t < NBUK) ? bcnt[t] : 0u;
  s[t] = my;
  __syncthreads();
  for (int off = 1; off < 256; off <<= 1) {
    unsigned int v = (t >= off) ? s[t - off] : 0u;
    __syncthreads();
    s[t] += v;
    __syncthreads();
  }
  if (t < NBUK) {
    gstart[t] = s[t] - my;
    gcur[t] = s[t] - my;
  }
  if (t == NBUK - 1) gstart[NBUK] = s[t];
}

// ---------------------------------------------------------------------------
// Sort 3: multisplit into 512-node buckets. Packed word = src | (dloc<<17).
__global__ __launch_bounds__(256) void k_msplit(
    const int* __restrict__ src, const int* __restrict__ dst,
    unsigned int* __restrict__ gcur, unsigned int* __restrict__ staging) {
  __shared__ unsigned int hist[NBUK];
  __shared__ unsigned int gbase[NBUK];
  int tid = threadIdx.x;
  for (int i = tid; i < NBUK; i += 256) hist[i] = 0u;
  __syncthreads();
  int e0 = blockIdx.x * (256 * MSB);
  unsigned int pk[MSB], rk[MSB], bk[MSB];
#pragma unroll
  for (int i = 0; i < MSB; ++i) {
    int e = e0 + i * 256 + tid;
    if (e < NE) {
      int d = dst[e];
      unsigned int b = (unsigned int)(d >> 9);
      rk[i] = atomicAdd(&hist[b], 1u);
      pk[i] = (unsigned int)src[e] | ((unsigned int)(d & 511) << 17);
      bk[i] = b;
    } else {
      bk[i] = 0xFFFFFFFFu;
    }
  }
  __syncthreads();
  for (int i = tid; i < NBUK; i += 256)
    if (hist[i]) gbase[i] = atomicAdd(&gcur[i], hist[i]);
  __syncthreads();
#pragma unroll
  for (int i = 0; i < MSB; ++i)
    if (bk[i] != 0xFFFFFFFFu) staging[gbase[bk[i]] + rk[i]] = pk[i];
}

// ---------------------------------------------------------------------------
// Sort 4 (fused): per-bucket node histogram + scan + scatter, ONE block per
// bucket. Output values are PRE-SHIFTED row byte offsets (src << 7).
__global__ __launch_bounds__(512) void k_bucket_sort(
    const unsigned int* __restrict__ staging,
    const unsigned int* __restrict__ gstart, unsigned int* __restrict__ nstart,
    unsigned int* __restrict__ srcoff) {
  __shared__ unsigned int hist[512];
  __shared__ unsigned int sc[512];
  __shared__ unsigned int cur[512];
  int b = blockIdx.x, t = threadIdx.x;
  hist[t] = 0u;
  __syncthreads();
  int lo = (int)gstart[b], hi = (int)gstart[b + 1];
  for (int e = lo + t; e < hi; e += 512)
    atomicAdd(&hist[staging[e] >> 17], 1u);
  __syncthreads();
  unsigned int my = hist[t];
  sc[t] = my;
  __syncthreads();
  for (int off = 1; off < 512; off <<= 1) {
    unsigned int v = (t >= off) ? sc[t - off] : 0u;
    __syncthreads();
    sc[t] += v;
    __syncthreads();
  }
  unsigned int st = (unsigned int)lo + sc[t] - my;  // exclusive start
  cur[t] = st;
  int node = b * 512 + t;
  if (node < NN) {
    nstart[node] = st;
    if (node == NN - 1) nstart[NN] = st + my;  // == NE
  }
  __syncthreads();
  for (int e = lo + t; e < hi; e += 512) {
    unsigned int u = staging[e];  // L2-hot (just read in pass 1)
    unsigned int pos = atomicAdd(&cur[u >> 17], 1u);
    srcoff[pos] = (u & 0x1FFFFu) << 7;  // row byte offset (HD*2 = 128 B)
  }
}

// ---------------------------------------------------------------------------
// Aggregation over sorted edges: one wave per node, 8 edges per wave-instr.
// g = lane>>3 owns edge slots; q = lane&7 owns channels 8q..8q+7 (uint4).
// srcoff holds pre-shifted byte offsets. Output aggr is bf16.
__global__ __launch_bounds__(256) void k_aggr_sorted(
    const unsigned int* __restrict__ srcoff,
    const unsigned int* __restrict__ nstart,
    const unsigned short* __restrict__ h16,
    unsigned short* __restrict__ a16) {
  int lane = threadIdx.x & 63;
  int n = (int)((blockIdx.x * 256 + threadIdx.x) >> 6);
  if (n >= NN) return;
  int g = lane >> 3;
  int q = lane & 7;
  int e0 = (int)nstart[n];
  int e1 = (int)nstart[n + 1];
  const char* hbase = (const char*)h16 + q * 16;
  float a0 = 0.f, a1 = 0.f, a2 = 0.f, a3 = 0.f;
  float a4 = 0.f, a5 = 0.f, a6 = 0.f, a7 = 0.f;
  float b0 = 0.f, b1 = 0.f, b2 = 0.f, b3 = 0.f;
  float b4 = 0.f, b5 = 0.f, b6 = 0.f, b7 = 0.f;
  int e = e0 + g;
  for (; e + 8 < e1; e += 16) {
    unsigned int o0 = srcoff[e];
    unsigned int o1 = srcoff[e + 8];
    uint4 u0 = *(const uint4*)(hbase + o0);
    uint4 u1 = *(const uint4*)(hbase + o1);
    a0 += __uint_as_float(u0.x << 16);
    a1 += __uint_as_float(u0.x & 0xFFFF0000u);
    a2 += __uint_as_float(u0.y << 16);
    a3 += __uint_as_float(u0.y & 0xFFFF0000u);
    a4 += __uint_as_float(u0.z << 16);
    a5 += __uint_as_float(u0.z & 0xFFFF0000u);
    a6 += __uint_as_float(u0.w << 16);
    a7 += __uint_as_float(u0.w & 0xFFFF0000u);
    b0 += __uint_as_float(u1.x << 16);
    b1 += __uint_as_float(u1.x & 0xFFFF0000u);
    b2 += __uint_as_float(u1.y << 16);
    b3 += __uint_as_float(u1.y & 0xFFFF0000u);
    b4 += __uint_as_float(u1.z << 16);
    b5 += __uint_as_float(u1.z & 0xFFFF0000u);
    b6 += __uint_as_float(u1.w << 16);
    b7 += __uint_as_float(u1.w & 0xFFFF0000u);
  }
  if (e < e1) {
    unsigned int o0 = srcoff[e];
    uint4 u0 = *(const uint4*)(hbase + o0);
    a0 += __uint_as_float(u0.x << 16);
    a1 += __uint_as_float(u0.x & 0xFFFF0000u);
    a2 += __uint_as_float(u0.y << 16);
    a3 += __uint_as_float(u0.y & 0xFFFF0000u);
    a4 += __uint_as_float(u0.z << 16);
    a5 += __uint_as_float(u0.z & 0xFFFF0000u);
    a6 += __uint_as_float(u0.w << 16);
    a7 += __uint_as_float(u0.w & 0xFFFF0000u);
  }
  a0 += b0; a1 += b1; a2 += b2; a3 += b3;
  a4 += b4; a5 += b5; a6 += b6; a7 += b7;
  // reduce across the 8 edge-slot groups (xor 8, 16, 32)
#pragma unroll
  for (int off = 8; off <= 32; off <<= 1) {
    a0 += __shfl_xor(a0, off);
    a1 += __shfl_xor(a1, off);
    a2 += __shfl_xor(a2, off);
    a3 += __shfl_xor(a3, off);
    a4 += __shfl_xor(a4, off);
    a5 += __shfl_xor(a5, off);
    a6 += __shfl_xor(a6, off);
    a7 += __shfl_xor(a7, off);
  }
  if (g == 0) {
    float cntf = (float)(e1 - e0);
    float inv = (cntf > 0.f) ? 1.0f / cntf : 0.f;
    uint4 o;
    o.x = f2bf(a0 * inv) | (f2bf(a1 * inv) << 16);
    o.y = f2bf(a2 * inv) | (f2bf(a3 * inv) << 16);
    o.z = f2bf(a4 * inv) | (f2bf(a5 * inv) << 16);
    o.w = f2bf(a6 * inv) | (f2bf(a7 * inv) << 16);
    *(uint4*)((char*)a16 + (size_t)n * 128 + q * 16) = o;
  }
}

// ---------------------------------------------------------------------------
// SAGE combine + fused BN-stats. 4x4 register tile; A and H both bf16 in.
__global__ __launch_bounds__(256) void k_combine(
    const unsigned short* __restrict__ a16,
    const unsigned short* __restrict__ h16, const float* __restrict__ Wl,
    const float* __restrict__ bl, const float* __restrict__ Wr,
    float* __restrict__ pre, float* __restrict__ stats) {
  __shared__ float sWl[HD * HD], sWr[HD * HD];  // 32 KB  [k][c]
  __shared__ float sA[64 * 66], sH[64 * 66];    // 33.8 KB [r][k] padded
  __shared__ float ssS[1024], ssQ[1024];        // 8 KB
  int tid = threadIdx.x;
  for (int i = tid; i < HD * HD / 4; i += 256) {
    *(float4*)&sWl[i * 4] = *(const float4*)&Wl[i * 4];
    *(float4*)&sWr[i * 4] = *(const float4*)&Wr[i * 4];
  }
  int cg = tid & 15, rg = tid >> 4;
  int c0 = cg * 4;
  float4 blc = *(const float4*)&bl[c0];
  float S[4] = {0.f, 0.f, 0.f, 0.f}, Q[4] = {0.f, 0.f, 0.f, 0.f};
  const int NT = (NN + 63) / 64;  // 1563
  for (int t = blockIdx.x; t < NT; t += gridDim.x) {
    int row0 = t * 64;
    __syncthreads();  // prior tile's LDS reads done
    for (int i = tid; i < 1024; i += 256) {
      int r = i >> 4, k4 = i & 15;  // 16 float4 per row
      int grow = row0 + r;
      if (grow >= NN) grow = NN - 1;
      uint2 au = *(const uint2*)&a16[(size_t)grow * HD + k4 * 4];
      float* dA = &sA[r * 66 + k4 * 4];
      dA[0] = bf2f((unsigned short)(au.x & 0xFFFFu));
      dA[1] = bf2f((unsigned short)(au.x >> 16));
      dA[2] = bf2f((unsigned short)(au.y & 0xFFFFu));
      dA[3] = bf2f((unsigned short)(au.y >> 16));
      uint2 hu = *(const uint2*)&h16[(size_t)grow * HD + k4 * 4];
      float* dH = &sH[r * 66 + k4 * 4];
      dH[0] = bf2f((unsigned short)(hu.x & 0xFFFFu));
      dH[1] = bf2f((unsigned short)(hu.x >> 16));
      dH[2] = bf2f((unsigned short)(hu.y & 0xFFFFu));
      dH[3] = bf2f((unsigned short)(hu.y >> 16));
    }
    __syncthreads();
    float acc[4][4];
#pragma unroll
    for (int r = 0; r < 4; ++r)
#pragma unroll
      for (int c = 0; c < 4; ++c) acc[r][c] = ((const float*)&blc)[c];
    for (int kg = 0; kg < HD; kg += 4) {
      float4 ar[4], hr[4], wlv[4], wrv[4];
#pragma unroll
      for (int r = 0; r < 4; ++r) {
        ar[r] = *(const float4*)&sA[(rg * 4 + r) * 66 + kg];
        hr[r] = *(const float4*)&sH[(rg * 4 + r) * 66 + kg];
      }
#pragma unroll
      for (int j = 0; j < 4; ++j) {
        wlv[j] = *(const float4*)&sWl[(kg + j) * HD + c0];
        wrv[j] = *(const float4*)&sWr[(kg + j) * HD + c0];
      }
#pragma unroll
      for (int j = 0; j < 4; ++j)
#pragma unroll
        for (int r = 0; r < 4; ++r) {
          float av = ((const float*)&ar[r])[j];
          float hv = ((const float*)&hr[r])[j];
#pragma unroll
          for (int c = 0; c < 4; ++c) {
            acc[r][c] = fmaf(av, ((const float*)&wlv[j])[c], acc[r][c]);
            acc[r][c] = fmaf(hv, ((const float*)&wrv[j])[c], acc[r][c]);
          }
        }
    }
#pragma unroll
    for (int r = 0; r < 4; ++r) {
      int row = row0 + rg * 4 + r;
      if (row < NN) {
        *(float4*)&pre[(size_t)row * HD + c0] = *(float4*)&acc[r][0];
#pragma unroll
        for (int c = 0; c < 4; ++c) {
          S[c] += acc[r][c];
          Q[c] = fmaf(acc[r][c], acc[r][c], Q[c]);
        }
      }
    }
  }
#pragma unroll
  for (int c = 0; c < 4; ++c) {
    ssS[tid * 4 + c] = S[c];
    ssQ[tid * 4 + c] = Q[c];
  }
  __syncthreads();
  if (tid < 64) {
    int cgr = tid >> 2, cc = tid & 3;
    float Ts = 0.f, Tq = 0.f;
#pragma unroll
    for (int m = 0; m < 16; ++m) {
      Ts += ssS[(m * 16 + cgr) * 4 + cc];
      Tq += ssQ[(m * 16 + cgr) * 4 + cc];
    }
    atomicAdd(&stats[tid], Ts);
    atomicAdd(&stats[64 + tid], Tq);
  }
}

// ---------------------------------------------------------------------------
// Final fused: BN + ReLU + residual(bf16) + output head.
__global__ __launch_bounds__(256) void k_bn_relu_head(
    const float* __restrict__ pre, const float* __restrict__ stats,
    const float* __restrict__ g, const float* __restrict__ b,
    const unsigned short* __restrict__ resid16, const float* __restrict__ Wo,
    const float* __restrict__ bo, float* __restrict__ out) {
  int lane = threadIdx.x & 63;
  int wid = (int)((blockIdx.x * blockDim.x + threadIdx.x) >> 6);
  int nw = (int)((gridDim.x * blockDim.x) >> 6);
  const float invN = 1.0f / NN;
  float m = stats[lane] * invN;
  float v = stats[64 + lane] * invN - m * m;
  float sc = g[lane] * rsqrtf(v + BN_EPS);
  float bb = b[lane];
  float w0 = Wo[lane * 2], w1 = Wo[lane * 2 + 1];
  float b0 = bo[0], b1 = bo[1];
  for (int row = wid; row < NN; row += nw) {
    size_t i = (size_t)row * HD + lane;
    float val = (pre[i] - m) * sc + bb;
    val = fmaxf(val, 0.f) + bf2f(resid16[i]);
    float a0 = val * w0, a1 = val * w1;
#pragma unroll
    for (int off = 32; off > 0; off >>= 1) {
      a0 += __shfl_down(a0, off);
      a1 += __shfl_down(a1, off);
    }
    if (lane == 0) {
      out[(size_t)row * 2] = a0 + b0;
      out[(size_t)row * 2 + 1] = a1 + b1;
    }
  }
}

// ---------------------------------------------------------------------------
extern "C" void kernel_launch(void* const* d_in, const int* in_sizes, int n_in,
                              void* d_out, int out_size, void* d_ws,
                              size_t ws_size, hipStream_t stream) {
  const float* x = (const float*)d_in[0];
  const int* ei = (const int*)d_in[1];
  const float* Wp = (const float*)d_in[2];
  const float* bp = (const float*)d_in[3];
  const float* g_in = (const float*)d_in[4];
  const float* b_in = (const float*)d_in[5];
  const float* Wl0 = (const float*)d_in[6];
  const float* bl0 = (const float*)d_in[7];
  const float* Wr0 = (const float*)d_in[8];
  const float* g0 = (const float*)d_in[9];
  const float* b0 = (const float*)d_in[10];
  const float* Wl1 = (const float*)d_in[11];
  const float* bl1 = (const float*)d_in[12];
  const float* Wr1 = (const float*)d_in[13];
  const float* g1 = (const float*)d_in[14];
  const float* b1 = (const float*)d_in[15];
  const float* Wo = (const float*)d_in[16];
  const float* bo = (const float*)d_in[17];
  float* out = (float*)d_out;

  const int* src = ei;
  const int* dst = ei + NE;

  float* ws = (float*)d_ws;
  float* pre = ws;                                          // [NN*HD] f32
  __hip_bfloat16* h0b = (__hip_bfloat16*)(ws + (size_t)NN * HD);  // [NN*HD]
  __hip_bfloat16* h1b = h0b + (size_t)NN * HD;              // [NN*HD]
  unsigned short* a16 = (unsigned short*)(h1b + (size_t)NN * HD);  // [NN*HD]
  unsigned int* staging = (unsigned int*)(a16 + (size_t)NN * HD);  // [NE]
  unsigned int* srcoff = staging + NE;       // [NE]
  unsigned int* nstart = srcoff + NE;        // [NN+1]
  unsigned int* bcnt = nstart + NN + 1;      // [NBUK]
  unsigned int* gstart = bcnt + NBUK;        // [NBUK+1]
  unsigned int* gcur = gstart + NBUK + 1;    // [NBUK]
  float* stats0 = (float*)(gcur + NBUK);     // [128]
  float* stats1 = stats0 + 128;              // [128]
  float* stats2 = stats1 + 128;              // [128]

  const int ELEM_BLOCKS = (NN * HD) / 256;  // 25000
  const int AGGR_BLOCKS = 25000;            // 100k waves, 4/block
  const int MS_BLOCKS = (NE + 256 * MSB - 1) / (256 * MSB);  // 782

  hipMemsetAsync(stats0, 0, 3 * 128 * sizeof(float), stream);
  hipMemsetAsync(bcnt, 0, NBUK * sizeof(unsigned int), stream);

  // ---- input projection (+stats) + BN/ReLU -> h0 (bf16)
  k_gemm_in<<<512, 256, 0, stream>>>(x, Wp, bp, pre, stats0);
  k_bn_relu<<<ELEM_BLOCKS, 256, 0, stream>>>(pre, stats0, g_in, b_in, h0b);

  // ---- counting-sort edges by dst, bucket-first; scatter is bucket-local
  k_bhist<<<1024, 256, 0, stream>>>(dst, bcnt);
  k_bscan<<<1, 256, 0, stream>>>(bcnt, gstart, gcur);
  k_msplit<<<MS_BLOCKS, 256, 0, stream>>>(src, dst, gcur, staging);
  k_bucket_sort<<<NBUK, 512, 0, stream>>>(staging, gstart, nstart, srcoff);

  // ---- layer 0
  k_aggr_sorted<<<AGGR_BLOCKS, 256, 0, stream>>>(
      srcoff, nstart, (const unsigned short*)h0b, a16);
  k_combine<<<512, 256, 0, stream>>>(a16, (const unsigned short*)h0b, Wl0,
                                     bl0, Wr0, pre, stats1);
  k_bn_relu<<<ELEM_BLOCKS, 256, 0, stream>>>(pre, stats1, g0, b0, h1b);

  // ---- layer 1 + fused BN/ReLU/residual/head
  k_aggr_sorted<<<AGGR_BLOCKS, 256, 0, stream>>>(
      srcoff, nstart, (const unsigned short*)h1b, a16);
  k_combine<<<512, 256, 0, stream>>>(a16, (const unsigned short*)h1b, Wl1,
                                     bl1, Wr1, pre, stats2);
  k_bn_relu_head<<<1024, 256, 0, stream>>>(pre, stats2, g1, b1,
                                           (const unsigned short*)h0b, Wo, bo,
                                           out);
}

// Round 13
// 395.785 us; speedup vs baseline: 3.1731x; 1.0100x over previous
//
#include <hip/hip_runtime.h>
#include <hip/hip_bf16.h>

#define NN 100000
#define NE 3200000
#define IC 128
#define HD 64
#define BN_EPS 1e-5f
#define NBUK 196      // ceil(NN / 512) buckets of 512 nodes (dst >> 9)
#define MSB 16        // edges per thread in multisplit (batch = 4096/block)

__device__ __forceinline__ float bf2f(unsigned short u) {
  return __uint_as_float(((unsigned)u) << 16);
}
// f32 -> bf16 (RNE), returns low 16 bits
__device__ __forceinline__ unsigned int f2bf(float f) {
  unsigned int u = __float_as_uint(f);
  return (u + 0x7FFFu + ((u >> 16) & 1u)) >> 16;
}
__device__ __forceinline__ unsigned int pack2(float a, float b) {
  return f2bf(a) | (f2bf(b) << 16);
}

// ---------------------------------------------------------------------------
// Input projection + fused BN-stats. 4x4 register tile per thread.
// x staged in LDS as packed bf16 (halves LDS + read bytes); W stays f32.
// pre written as packed bf16; stats from exact f32 accumulators.
__global__ __launch_bounds__(256) void k_gemm_in(
    const float* __restrict__ x, const float* __restrict__ Wp,
    const float* __restrict__ bp, unsigned int* __restrict__ pre16,
    float* __restrict__ stats) {
  __shared__ float sW[IC * HD];           // 32 KB  [k][c]
  __shared__ unsigned int sXu[64 * 68];   // 17.4 KB [r][k/2] bf16-pairs
  __shared__ float sStS[256], sStQ[256];  // 2 KB
  int tid = threadIdx.x;
  for (int i = tid; i < IC * HD / 4; i += 256)
    *(float4*)&sW[i * 4] = *(const float4*)&Wp[i * 4];
  int cg = tid & 15, rg = tid >> 4;
  int c0 = cg * 4;
  float4 bpc = *(const float4*)&bp[c0];
  float S[4] = {0.f, 0.f, 0.f, 0.f}, Q[4] = {0.f, 0.f, 0.f, 0.f};
  const int NT = (NN + 63) / 64;  // 1563
  for (int t = blockIdx.x; t < NT; t += gridDim.x) {
    int row0 = t * 64;
    __syncthreads();  // prior tile's LDS reads done
    for (int i = tid; i < 1024; i += 256) {  // 8 floats per i
      int r = i >> 4, k8 = i & 15;
      int grow = row0 + r;
      if (grow >= NN) grow = NN - 1;
      const float* xs = &x[(size_t)grow * IC + k8 * 8];
      float4 f0 = *(const float4*)xs;
      float4 f1 = *(const float4*)(xs + 4);
      uint4 p;
      p.x = pack2(f0.x, f0.y);
      p.y = pack2(f0.z, f0.w);
      p.z = pack2(f1.x, f1.y);
      p.w = pack2(f1.z, f1.w);
      *(uint4*)&sXu[r * 68 + k8 * 4] = p;
    }
    __syncthreads();
    float acc[4][4];
#pragma unroll
    for (int r = 0; r < 4; ++r)
#pragma unroll
      for (int c = 0; c < 4; ++c) acc[r][c] = ((const float*)&bpc)[c];
    for (int kg = 0; kg < IC; kg += 4) {
      uint2 xu[4];
      float4 wv[4];
#pragma unroll
      for (int r = 0; r < 4; ++r)
        xu[r] = *(const uint2*)&sXu[(rg * 4 + r) * 68 + (kg >> 1)];
#pragma unroll
      for (int j = 0; j < 4; ++j)
        wv[j] = *(const float4*)&sW[(kg + j) * HD + c0];
#pragma unroll
      for (int r = 0; r < 4; ++r) {
        float xv[4];
        xv[0] = __uint_as_float(xu[r].x << 16);
        xv[1] = __uint_as_float(xu[r].x & 0xFFFF0000u);
        xv[2] = __uint_as_float(xu[r].y << 16);
        xv[3] = __uint_as_float(xu[r].y & 0xFFFF0000u);
#pragma unroll
        for (int j = 0; j < 4; ++j) {
#pragma unroll
          for (int c = 0; c < 4; ++c)
            acc[r][c] = fmaf(xv[j], ((const float*)&wv[j])[c], acc[r][c]);
        }
      }
    }
#pragma unroll
    for (int r = 0; r < 4; ++r) {
      int row = row0 + rg * 4 + r;
      if (row < NN) {
        uint2 o;
        o.x = pack2(acc[r][0], acc[r][1]);
        o.y = pack2(acc[r][2], acc[r][3]);
        *(uint2*)&pre16[(size_t)row * 32 + cg * 2] = o;
#pragma unroll
        for (int c = 0; c < 4; ++c) {
          S[c] += acc[r][c];
          Q[c] = fmaf(acc[r][c], acc[r][c], Q[c]);
        }
      }
    }
  }
  // wave-level reduce across rg groups (lanes cg, cg+16, cg+32, cg+48)
#pragma unroll
  for (int c = 0; c < 4; ++c) {
    S[c] += __shfl_xor(S[c], 16);
    S[c] += __shfl_xor(S[c], 32);
    Q[c] += __shfl_xor(Q[c], 16);
    Q[c] += __shfl_xor(Q[c], 32);
  }
  int wave = tid >> 6, lane = tid & 63;
  if (lane < 16) {
#pragma unroll
    for (int c = 0; c < 4; ++c) {
      sStS[wave * 64 + lane * 4 + c] = S[c];
      sStQ[wave * 64 + lane * 4 + c] = Q[c];
    }
  }
  __syncthreads();
  if (tid < 64) {
    float Ts = sStS[tid] + sStS[64 + tid] + sStS[128 + tid] + sStS[192 + tid];
    float Tq = sStQ[tid] + sStQ[64 + tid] + sStQ[128 + tid] + sStQ[192 + tid];
    atomicAdd(&stats[tid], Ts);
    atomicAdd(&stats[64 + tid], Tq);
  }
}

// ---------------------------------------------------------------------------
// BN normalize + ReLU: bf16-packed pre in -> bf16-packed h out. 4 ch/thread.
__global__ __launch_bounds__(256) void k_bn_relu(
    const unsigned int* __restrict__ pre16, const float* __restrict__ stats,
    const float* __restrict__ g, const float* __restrict__ b,
    unsigned int* __restrict__ h16u) {
  size_t i = (size_t)blockIdx.x * 256 + threadIdx.x;  // uint2 unit = 4 ch
  int c0 = ((int)(i & 15)) * 4;
  const float invN = 1.0f / NN;
  uint2 p = *(const uint2*)&pre16[i * 2];
  float v[4];
  v[0] = __uint_as_float(p.x << 16);
  v[1] = __uint_as_float(p.x & 0xFFFF0000u);
  v[2] = __uint_as_float(p.y << 16);
  v[3] = __uint_as_float(p.y & 0xFFFF0000u);
#pragma unroll
  for (int c = 0; c < 4; ++c) {
    float m = stats[c0 + c] * invN;
    float var = stats[64 + c0 + c] * invN - m * m;
    float sc = g[c0 + c] * rsqrtf(var + BN_EPS);
    v[c] = fmaxf((v[c] - m) * sc + b[c0 + c], 0.f);
  }
  uint2 o;
  o.x = pack2(v[0], v[1]);
  o.y = pack2(v[2], v[3]);
  *(uint2*)&h16u[i * 2] = o;
}

// ---------------------------------------------------------------------------
// Sort 1: bucket histogram via LDS (196 bins), block-reduced to global.
__global__ __launch_bounds__(256) void k_bhist(
    const int* __restrict__ dst, unsigned int* __restrict__ bcnt) {
  __shared__ unsigned int h[NBUK];
  for (int i = threadIdx.x; i < NBUK; i += 256) h[i] = 0u;
  __syncthreads();
  int i0 = blockIdx.x * 256 + threadIdx.x;
  int stride = gridDim.x * 256;
  for (int e = i0; e < NE; e += stride)
    atomicAdd(&h[((unsigned)dst[e]) >> 9], 1u);
  __syncthreads();
  for (int i = threadIdx.x; i < NBUK; i += 256)
    if (h[i]) atomicAdd(&bcnt[i], h[i]);
}

// ---------------------------------------------------------------------------
// Sort 2: exclusive scan of 196 bucket counts (one block).
__global__ __launch_bounds__(256) void k_bscan(
    const unsigned int* __restrict__ bcnt, unsigned int* __restrict__ gstart,
    unsigned int* __restrict__ gcur) {
  __shared__ unsigned int s[256];
  int t = threadIdx.x;
  unsigned int my = (t < NBUK) ? bcnt[t] : 0u;
  s[t] = my;
  __syncthreads();
  for (int off = 1; off < 256; off <<= 1) {
    unsigned int v = (t >= off) ? s[t - off] : 0u;
    __syncthreads();
    s[t] += v;
    __syncthreads();
  }
  if (t < NBUK) {
    gstart[t] = s[t] - my;
    gcur[t] = s[t] - my;
  }
  if (t == NBUK - 1) gstart[NBUK] = s[t];
}

// ---------------------------------------------------------------------------
// Sort 3: multisplit into 512-node buckets. Packed word = src | (dloc<<17).
__global__ __launch_bounds__(256) void k_msplit(
    const int* __restrict__ src, const int* __restrict__ dst,
    unsigned int* __restrict__ gcur, unsigned int* __restrict__ staging) {
  __shared__ unsigned int hist[NBUK];
  __shared__ unsigned int gbase[NBUK];
  int tid = threadIdx.x;
  for (int i = tid; i < NBUK; i += 256) hist[i] = 0u;
  __syncthreads();
  int e0 = blockIdx.x * (256 * MSB);
  unsigned int pk[MSB], rk[MSB], bk[MSB];
#pragma unroll
  for (int i = 0; i < MSB; ++i) {
    int e = e0 + i * 256 + tid;
    if (e < NE) {
      int d = dst[e];
      unsigned int b = (unsigned int)(d >> 9);
      rk[i] = atomicAdd(&hist[b], 1u);
      pk[i] = (unsigned int)src[e] | ((unsigned int)(d & 511) << 17);
      bk[i] = b;
    } else {
      bk[i] = 0xFFFFFFFFu;
    }
  }
  __syncthreads();
  for (int i = tid; i < NBUK; i += 256)
    if (hist[i]) gbase[i] = atomicAdd(&gcur[i], hist[i]);
  __syncthreads();
#pragma unroll
  for (int i = 0; i < MSB; ++i)
    if (bk[i] != 0xFFFFFFFFu) staging[gbase[bk[i]] + rk[i]] = pk[i];
}

// ---------------------------------------------------------------------------
// Sort 4 (fused): per-bucket node histogram + scan + scatter, ONE block per
// bucket. Output values are PRE-SHIFTED row byte offsets (src << 7).
__global__ __launch_bounds__(512) void k_bucket_sort(
    const unsigned int* __restrict__ staging,
    const unsigned int* __restrict__ gstart, unsigned int* __restrict__ nstart,
    unsigned int* __restrict__ srcoff) {
  __shared__ unsigned int hist[512];
  __shared__ unsigned int sc[512];
  __shared__ unsigned int cur[512];
  int b = blockIdx.x, t = threadIdx.x;
  hist[t] = 0u;
  __syncthreads();
  int lo = (int)gstart[b], hi = (int)gstart[b + 1];
  for (int e = lo + t; e < hi; e += 512)
    atomicAdd(&hist[staging[e] >> 17], 1u);
  __syncthreads();
  unsigned int my = hist[t];
  sc[t] = my;
  __syncthreads();
  for (int off = 1; off < 512; off <<= 1) {
    unsigned int v = (t >= off) ? sc[t - off] : 0u;
    __syncthreads();
    sc[t] += v;
    __syncthreads();
  }
  unsigned int st = (unsigned int)lo + sc[t] - my;  // exclusive start
  cur[t] = st;
  int node = b * 512 + t;
  if (node < NN) {
    nstart[node] = st;
    if (node == NN - 1) nstart[NN] = st + my;  // == NE
  }
  __syncthreads();
  for (int e = lo + t; e < hi; e += 512) {
    unsigned int u = staging[e];  // L2-hot (just read in pass 1)
    unsigned int pos = atomicAdd(&cur[u >> 17], 1u);
    srcoff[pos] = (u & 0x1FFFFu) << 7;  // row byte offset (HD*2 = 128 B)
  }
}

// ---------------------------------------------------------------------------
// Aggregation over sorted edges: one wave per node, 8 edges per wave-instr.
__global__ __launch_bounds__(256) void k_aggr_sorted(
    const unsigned int* __restrict__ srcoff,
    const unsigned int* __restrict__ nstart,
    const unsigned short* __restrict__ h16,
    unsigned short* __restrict__ a16) {
  int lane = threadIdx.x & 63;
  int n = (int)((blockIdx.x * 256 + threadIdx.x) >> 6);
  if (n >= NN) return;
  int g = lane >> 3;
  int q = lane & 7;
  int e0 = (int)nstart[n];
  int e1 = (int)nstart[n + 1];
  const char* hbase = (const char*)h16 + q * 16;
  float a0 = 0.f, a1 = 0.f, a2 = 0.f, a3 = 0.f;
  float a4 = 0.f, a5 = 0.f, a6 = 0.f, a7 = 0.f;
  float b0 = 0.f, b1 = 0.f, b2 = 0.f, b3 = 0.f;
  float b4 = 0.f, b5 = 0.f, b6 = 0.f, b7 = 0.f;
  int e = e0 + g;
  for (; e + 8 < e1; e += 16) {
    unsigned int o0 = srcoff[e];
    unsigned int o1 = srcoff[e + 8];
    uint4 u0 = *(const uint4*)(hbase + o0);
    uint4 u1 = *(const uint4*)(hbase + o1);
    a0 += __uint_as_float(u0.x << 16);
    a1 += __uint_as_float(u0.x & 0xFFFF0000u);
    a2 += __uint_as_float(u0.y << 16);
    a3 += __uint_as_float(u0.y & 0xFFFF0000u);
    a4 += __uint_as_float(u0.z << 16);
    a5 += __uint_as_float(u0.z & 0xFFFF0000u);
    a6 += __uint_as_float(u0.w << 16);
    a7 += __uint_as_float(u0.w & 0xFFFF0000u);
    b0 += __uint_as_float(u1.x << 16);
    b1 += __uint_as_float(u1.x & 0xFFFF0000u);
    b2 += __uint_as_float(u1.y << 16);
    b3 += __uint_as_float(u1.y & 0xFFFF0000u);
    b4 += __uint_as_float(u1.z << 16);
    b5 += __uint_as_float(u1.z & 0xFFFF0000u);
    b6 += __uint_as_float(u1.w << 16);
    b7 += __uint_as_float(u1.w & 0xFFFF0000u);
  }
  if (e < e1) {
    unsigned int o0 = srcoff[e];
    uint4 u0 = *(const uint4*)(hbase + o0);
    a0 += __uint_as_float(u0.x << 16);
    a1 += __uint_as_float(u0.x & 0xFFFF0000u);
    a2 += __uint_as_float(u0.y << 16);
    a3 += __uint_as_float(u0.y & 0xFFFF0000u);
    a4 += __uint_as_float(u0.z << 16);
    a5 += __uint_as_float(u0.z & 0xFFFF0000u);
    a6 += __uint_as_float(u0.w << 16);
    a7 += __uint_as_float(u0.w & 0xFFFF0000u);
  }
  a0 += b0; a1 += b1; a2 += b2; a3 += b3;
  a4 += b4; a5 += b5; a6 += b6; a7 += b7;
#pragma unroll
  for (int off = 8; off <= 32; off <<= 1) {
    a0 += __shfl_xor(a0, off);
    a1 += __shfl_xor(a1, off);
    a2 += __shfl_xor(a2, off);
    a3 += __shfl_xor(a3, off);
    a4 += __shfl_xor(a4, off);
    a5 += __shfl_xor(a5, off);
    a6 += __shfl_xor(a6, off);
    a7 += __shfl_xor(a7, off);
  }
  if (g == 0) {
    float cntf = (float)(e1 - e0);
    float inv = (cntf > 0.f) ? 1.0f / cntf : 0.f;
    uint4 o;
    o.x = pack2(a0 * inv, a1 * inv);
    o.y = pack2(a2 * inv, a3 * inv);
    o.z = pack2(a4 * inv, a5 * inv);
    o.w = pack2(a6 * inv, a7 * inv);
    *(uint4*)((char*)a16 + (size_t)n * 128 + q * 16) = o;
  }
}

// ---------------------------------------------------------------------------
// SAGE combine + fused BN-stats. 4x4 register tile; A,H bf16-packed in LDS;
// W f32 in LDS; pre out bf16-packed; stats from exact f32 accumulators.
__global__ __launch_bounds__(256) void k_combine(
    const unsigned int* __restrict__ a16u,
    const unsigned int* __restrict__ h16u, const float* __restrict__ Wl,
    const float* __restrict__ bl, const float* __restrict__ Wr,
    unsigned int* __restrict__ pre16, float* __restrict__ stats) {
  __shared__ float sWl[HD * HD], sWr[HD * HD];        // 32 KB  [k][c]
  __shared__ unsigned int sAu[64 * 36], sHu[64 * 36]; // 18.4 KB bf16-pairs
  __shared__ float sStS[256], sStQ[256];              // 2 KB
  int tid = threadIdx.x;
  for (int i = tid; i < HD * HD / 4; i += 256) {
    *(float4*)&sWl[i * 4] = *(const float4*)&Wl[i * 4];
    *(float4*)&sWr[i * 4] = *(const float4*)&Wr[i * 4];
  }
  int cg = tid & 15, rg = tid >> 4;
  int c0 = cg * 4;
  float4 blc = *(const float4*)&bl[c0];
  float S[4] = {0.f, 0.f, 0.f, 0.f}, Q[4] = {0.f, 0.f, 0.f, 0.f};
  const int NT = (NN + 63) / 64;  // 1563
  for (int t = blockIdx.x; t < NT; t += gridDim.x) {
    int row0 = t * 64;
    __syncthreads();  // prior tile's LDS reads done
    for (int i = tid; i < 512; i += 256) {  // uint4 = 8 bf16; 8 per row
      int r = i >> 3, c4 = i & 7;
      int grow = row0 + r;
      if (grow >= NN) grow = NN - 1;
      *(uint4*)&sAu[r * 36 + c4 * 4] =
          *(const uint4*)&a16u[(size_t)grow * 32 + c4 * 4];
      *(uint4*)&sHu[r * 36 + c4 * 4] =
          *(const uint4*)&h16u[(size_t)grow * 32 + c4 * 4];
    }
    __syncthreads();
    float acc[4][4];
#pragma unroll
    for (int r = 0; r < 4; ++r)
#pragma unroll
      for (int c = 0; c < 4; ++c) acc[r][c] = ((const float*)&blc)[c];
    for (int kg = 0; kg < HD; kg += 4) {
      uint2 au[4], hu[4];
      float4 wlv[4], wrv[4];
#pragma unroll
      for (int r = 0; r < 4; ++r) {
        au[r] = *(const uint2*)&sAu[(rg * 4 + r) * 36 + (kg >> 1)];
        hu[r] = *(const uint2*)&sHu[(rg * 4 + r) * 36 + (kg >> 1)];
      }
#pragma unroll
      for (int j = 0; j < 4; ++j) {
        wlv[j] = *(const float4*)&sWl[(kg + j) * HD + c0];
        wrv[j] = *(const float4*)&sWr[(kg + j) * HD + c0];
      }
#pragma unroll
      for (int r = 0; r < 4; ++r) {
        float av[4], hv[4];
        av[0] = __uint_as_float(au[r].x << 16);
        av[1] = __uint_as_float(au[r].x & 0xFFFF0000u);
        av[2] = __uint_as_float(au[r].y << 16);
        av[3] = __uint_as_float(au[r].y & 0xFFFF0000u);
        hv[0] = __uint_as_float(hu[r].x << 16);
        hv[1] = __uint_as_float(hu[r].x & 0xFFFF0000u);
        hv[2] = __uint_as_float(hu[r].y << 16);
        hv[3] = __uint_as_float(hu[r].y & 0xFFFF0000u);
#pragma unroll
        for (int j = 0; j < 4; ++j) {
#pragma unroll
          for (int c = 0; c < 4; ++c) {
            acc[r][c] = fmaf(av[j], ((const float*)&wlv[j])[c], acc[r][c]);
            acc[r][c] = fmaf(hv[j], ((const float*)&wrv[j])[c], acc[r][c]);
          }
        }
      }
    }
#pragma unroll
    for (int r = 0; r < 4; ++r) {
      int row = row0 + rg * 4 + r;
      if (row < NN) {
        uint2 o;
        o.x = pack2(acc[r][0], acc[r][1]);
        o.y = pack2(acc[r][2], acc[r][3]);
        *(uint2*)&pre16[(size_t)row * 32 + cg * 2] = o;
#pragma unroll
        for (int c = 0; c < 4; ++c) {
          S[c] += acc[r][c];
          Q[c] = fmaf(acc[r][c], acc[r][c], Q[c]);
        }
      }
    }
  }
#pragma unroll
  for (int c = 0; c < 4; ++c) {
    S[c] += __shfl_xor(S[c], 16);
    S[c] += __shfl_xor(S[c], 32);
    Q[c] += __shfl_xor(Q[c], 16);
    Q[c] += __shfl_xor(Q[c], 32);
  }
  int wave = tid >> 6, lane = tid & 63;
  if (lane < 16) {
#pragma unroll
    for (int c = 0; c < 4; ++c) {
      sStS[wave * 64 + lane * 4 + c] = S[c];
      sStQ[wave * 64 + lane * 4 + c] = Q[c];
    }
  }
  __syncthreads();
  if (tid < 64) {
    float Ts = sStS[tid] + sStS[64 + tid] + sStS[128 + tid] + sStS[192 + tid];
    float Tq = sStQ[tid] + sStQ[64 + tid] + sStQ[128 + tid] + sStQ[192 + tid];
    atomicAdd(&stats[tid], Ts);
    atomicAdd(&stats[64 + tid], Tq);
  }
}

// ---------------------------------------------------------------------------
// Final fused: BN + ReLU + residual(bf16) + output head (pre is bf16-packed).
__global__ __launch_bounds__(256) void k_bn_relu_head(
    const unsigned short* __restrict__ pre16,
    const float* __restrict__ stats, const float* __restrict__ g,
    const float* __restrict__ b, const unsigned short* __restrict__ resid16,
    const float* __restrict__ Wo, const float* __restrict__ bo,
    float* __restrict__ out) {
  int lane = threadIdx.x & 63;
  int wid = (int)((blockIdx.x * blockDim.x + threadIdx.x) >> 6);
  int nw = (int)((gridDim.x * blockDim.x) >> 6);
  const float invN = 1.0f / NN;
  float m = stats[lane] * invN;
  float v = stats[64 + lane] * invN - m * m;
  float sc = g[lane] * rsqrtf(v + BN_EPS);
  float bb = b[lane];
  float w0 = Wo[lane * 2], w1 = Wo[lane * 2 + 1];
  float b0 = bo[0], b1 = bo[1];
  for (int row = wid; row < NN; row += nw) {
    size_t i = (size_t)row * HD + lane;
    float val = (bf2f(pre16[i]) - m) * sc + bb;
    val = fmaxf(val, 0.f) + bf2f(resid16[i]);
    float a0 = val * w0, a1 = val * w1;
#pragma unroll
    for (int off = 32; off > 0; off >>= 1) {
      a0 += __shfl_down(a0, off);
      a1 += __shfl_down(a1, off);
    }
    if (lane == 0) {
      out[(size_t)row * 2] = a0 + b0;
      out[(size_t)row * 2 + 1] = a1 + b1;
    }
  }
}

// ---------------------------------------------------------------------------
extern "C" void kernel_launch(void* const* d_in, const int* in_sizes, int n_in,
                              void* d_out, int out_size, void* d_ws,
                              size_t ws_size, hipStream_t stream) {
  const float* x = (const float*)d_in[0];
  const int* ei = (const int*)d_in[1];
  const float* Wp = (const float*)d_in[2];
  const float* bp = (const float*)d_in[3];
  const float* g_in = (const float*)d_in[4];
  const float* b_in = (const float*)d_in[5];
  const float* Wl0 = (const float*)d_in[6];
  const float* bl0 = (const float*)d_in[7];
  const float* Wr0 = (const float*)d_in[8];
  const float* g0 = (const float*)d_in[9];
  const float* b0 = (const float*)d_in[10];
  const float* Wl1 = (const float*)d_in[11];
  const float* bl1 = (const float*)d_in[12];
  const float* Wr1 = (const float*)d_in[13];
  const float* g1 = (const float*)d_in[14];
  const float* b1 = (const float*)d_in[15];
  const float* Wo = (const float*)d_in[16];
  const float* bo = (const float*)d_in[17];
  float* out = (float*)d_out;

  const int* src = ei;
  const int* dst = ei + NE;

  unsigned int* pre16 = (unsigned int*)d_ws;                 // [NN*32] u32
  unsigned short* h0 = (unsigned short*)(pre16 + (size_t)NN * 32);  // [NN*64]
  unsigned short* h1 = h0 + (size_t)NN * HD;                 // [NN*64]
  unsigned short* a16 = h1 + (size_t)NN * HD;                // [NN*64]
  unsigned int* staging = (unsigned int*)(a16 + (size_t)NN * HD);  // [NE]
  unsigned int* srcoff = staging + NE;       // [NE]
  unsigned int* nstart = srcoff + NE;        // [NN+1]
  unsigned int* bcnt = nstart + NN + 1;      // [NBUK]
  unsigned int* gstart = bcnt + NBUK;        // [NBUK+1]
  unsigned int* gcur = gstart + NBUK + 1;    // [NBUK]
  float* stats0 = (float*)(gcur + NBUK);     // [128]
  float* stats1 = stats0 + 128;              // [128]
  float* stats2 = stats1 + 128;              // [128]

  const int BNR_BLOCKS = (NN * HD / 4) / 256;  // 6250
  const int AGGR_BLOCKS = 25000;               // 100k waves, 4/block
  const int MS_BLOCKS = (NE + 256 * MSB - 1) / (256 * MSB);  // 782

  hipMemsetAsync(stats0, 0, 3 * 128 * sizeof(float), stream);
  hipMemsetAsync(bcnt, 0, NBUK * sizeof(unsigned int), stream);

  // ---- input projection (+stats) + BN/ReLU -> h0 (bf16)
  k_gemm_in<<<768, 256, 0, stream>>>(x, Wp, bp, pre16, stats0);
  k_bn_relu<<<BNR_BLOCKS, 256, 0, stream>>>(pre16, stats0, g_in, b_in,
                                            (unsigned int*)h0);

  // ---- counting-sort edges by dst, bucket-first; scatter is bucket-local
  k_bhist<<<1024, 256, 0, stream>>>(dst, bcnt);
  k_bscan<<<1, 256, 0, stream>>>(bcnt, gstart, gcur);
  k_msplit<<<MS_BLOCKS, 256, 0, stream>>>(src, dst, gcur, staging);
  k_bucket_sort<<<NBUK, 512, 0, stream>>>(staging, gstart, nstart, srcoff);

  // ---- layer 0
  k_aggr_sorted<<<AGGR_BLOCKS, 256, 0, stream>>>(srcoff, nstart, h0, a16);
  k_combine<<<768, 256, 0, stream>>>((const unsigned int*)a16,
                                     (const unsigned int*)h0, Wl0, bl0, Wr0,
                                     pre16, stats1);
  k_bn_relu<<<BNR_BLOCKS, 256, 0, stream>>>(pre16, stats1, g0, b0,
                                            (unsigned int*)h1);

  // ---- layer 1 + fused BN/ReLU/residual/head
  k_aggr_sorted<<<AGGR_BLOCKS, 256, 0, stream>>>(srcoff, nstart, h1, a16);
  k_combine<<<768, 256, 0, stream>>>((const unsigned int*)a16,
                                     (const unsigned int*)h1, Wl1, bl1, Wr1,
                                     pre16, stats2);
  k_bn_relu_head<<<1024, 256, 0, stream>>>((const unsigned short*)pre16,
                                           stats2, g1, b1, h0, Wo, bo, out);
}